// Round 2
// baseline (19689.899 us; speedup 1.0000x reference)
//
#include <hip/hip_runtime.h>
#include <math.h>

#define CH 24

// ============ all kernels operate on a SINGLE image (pointers pre-offset) ============

// mean over 3 ch + 3x3 Laplacian (zero pad). x: [3][H][W] -> xl: [H][W]
__global__ void k_lap(const float* __restrict__ x, float* __restrict__ xl, int H, int W){
  int idx = blockIdx.x*256 + threadIdx.x;
  int HW = H*W;
  if (idx >= HW) return;
  int px = idx % W, py = idx / W;
#define MEANV(yy,xx) (((yy)>=0&&(yy)<H&&(xx)>=0&&(xx)<W) ? (x[(yy)*W+(xx)]+x[HW+(yy)*W+(xx)]+x[2*HW+(yy)*W+(xx)])*(1.f/3.f) : 0.f)
  float v = 4.f*MEANV(py,px) - MEANV(py-1,px) - MEANV(py+1,px) - MEANV(py,px-1) - MEANV(py,px+1);
#undef MEANV
  xl[idx] = v;
}

// 1x1 conv 1 -> 24
__global__ void k_expand(const float* __restrict__ xl, const float* __restrict__ w,
                         float* __restrict__ out, int HW){
  int idx = blockIdx.x*256 + threadIdx.x;
  if (idx >= CH*HW) return;
  int p = idx % HW;
  int c = idx / HW;
  out[idx] = xl[p] * w[c];
}

// KxK conv, 24->24, pad K/2, stride 1 (LDS-tiled). in/out: [24][H][W]
template<int K>
__launch_bounds__(256)
__global__ void k_conv(const float* __restrict__ in, const float* __restrict__ w,
                       float* __restrict__ out, int H, int W){
  constexpr int T = 16 + K - 1;
  __shared__ float tile[CH*T*T];
  int tx = threadIdx.x & 15, ty = threadIdx.x >> 4;
  int x0 = blockIdx.x*16 - K/2, y0 = blockIdx.y*16 - K/2;
  for (int i = threadIdx.x; i < CH*T*T; i += 256){
    int ci = i/(T*T); int r = i%(T*T); int yy = r/T, xx = r%T;
    int gy = y0+yy, gx = x0+xx;
    tile[i] = (gy>=0 && gy<H && gx>=0 && gx<W) ? in[((size_t)ci*H+gy)*W+gx] : 0.f;
  }
  __syncthreads();
  float acc[CH];
  #pragma unroll
  for (int co=0;co<CH;co++) acc[co]=0.f;
  for (int ci=0; ci<CH; ci++){
    const float* wci = w + ci*K*K;
    const float* tci = tile + ci*T*T;
    for (int ky=0; ky<K; ky++){
      const float* trow = tci + (ty+ky)*T + tx;
      const float* wrow = wci + ky*K;
      #pragma unroll
      for (int kx=0; kx<K; kx++){
        float v = trow[kx];
        #pragma unroll
        for (int co=0;co<CH;co++) acc[co] = fmaf(v, wrow[co*CH*K*K + kx], acc[co]);
      }
    }
  }
  int oy = blockIdx.y*16+ty, ox = blockIdx.x*16+tx;
  float* ob = out + (size_t)oy*W + ox;
  #pragma unroll
  for (int co=0;co<CH;co++) ob[(size_t)co*H*W] = acc[co];
}

// 1x1 conv 24->24 (+ channel mean/max maps). May run in-place (no restrict on in/out).
__global__ void k_pw(const float* in, const float* __restrict__ w,
                     float* out, float* __restrict__ mm, int HW){
  int p = blockIdx.x*256 + threadIdx.x;
  if (p >= HW) return;
  float v[CH];
  #pragma unroll
  for (int ci=0;ci<CH;ci++) v[ci] = in[(size_t)ci*HW + p];
  float mean = 0.f, mx = -3.4e38f;
  float r[CH];
  #pragma unroll
  for (int co=0;co<CH;co++){
    float a = 0.f;
    const float* wr = w + co*CH;
    #pragma unroll
    for (int ci=0;ci<CH;ci++) a = fmaf(v[ci], wr[ci], a);
    r[co] = a;
    mean += a; mx = fmaxf(mx, a);
  }
  #pragma unroll
  for (int co=0;co<CH;co++) out[(size_t)co*HW + p] = r[co];
  mm[p]      = mean * (1.f/24.f);
  mm[HW + p] = mx;
}

// spatial attn (7x7 2->1 conv on mean/max maps) + sigmoid + relu + residual add.
// out may alias X (no restrict on X/out).
__global__ void k_attn_res(const float* __restrict__ R, const float* __restrict__ M,
                           const float* X, const float* __restrict__ wsa,
                           float* out, int H, int W){
  int p = blockIdx.x*256 + threadIdx.x;
  int HW = H*W;
  if (p >= HW) return;
  int px = p % W, py = p / W;
  float s = 0.f;
  #pragma unroll
  for (int cc=0;cc<2;cc++){
    for (int ky=0;ky<7;ky++){
      int gy = py+ky-3;
      if (gy<0||gy>=H) continue;
      const float* mr = M + (size_t)cc*HW + (size_t)gy*W;
      const float* wr = wsa + (cc*7+ky)*7;
      #pragma unroll
      for (int kx=0;kx<7;kx++){
        int gx = px+kx-3;
        if (gx>=0 && gx<W) s = fmaf(mr[gx], wr[kx], s);
      }
    }
  }
  float g = 1.f/(1.f+expf(-s));
  #pragma unroll
  for (int c=0;c<CH;c++){
    float vv = R[(size_t)c*HW + p]*g;
    out[(size_t)c*HW + p] = X[(size_t)c*HW + p] + fmaxf(vv, 0.f);
  }
}

// 4x4 stride-2 pad-1 conv (downsample), OIHW weights
__global__ void k_down(const float* __restrict__ in, const float* __restrict__ w,
                       float* __restrict__ out, int Ho, int Wo){
  int tx = threadIdx.x & 15, ty = threadIdx.x >> 4;
  int ox = blockIdx.x*16 + tx, oy = blockIdx.y*16 + ty;
  int Hi = Ho*2, Wi = Wo*2;
  float acc[CH];
  #pragma unroll
  for (int c=0;c<CH;c++) acc[c]=0.f;
  for (int ci=0; ci<CH; ci++){
    const float* ip = in + (size_t)ci*Hi*Wi;
    #pragma unroll
    for (int ky=0;ky<4;ky++){
      int iy = 2*oy + ky - 1;
      if (iy < 0 || iy >= Hi) continue;
      #pragma unroll
      for (int kx=0;kx<4;kx++){
        int ix = 2*ox + kx - 1;
        if (ix < 0 || ix >= Wi) continue;
        float v = ip[(size_t)iy*Wi + ix];
        const float* wp = w + (ci*4+ky)*4 + kx;
        #pragma unroll
        for (int co=0;co<CH;co++) acc[co] = fmaf(v, wp[co*CH*16], acc[co]);
      }
    }
  }
  float* ob = out + (size_t)oy*Wo + ox;
  #pragma unroll
  for (int co=0;co<CH;co++) ob[(size_t)co*Ho*Wo] = acc[co];
}

// ConvTranspose2d(k=4,s=2,p=1), torch weight layout [in,out,4,4]
__global__ void k_convT(const float* __restrict__ in, const float* __restrict__ w,
                        float* __restrict__ out, int Ho, int Wo){
  int tx = threadIdx.x & 15, ty = threadIdx.x >> 4;
  int ox = blockIdx.x*16 + tx, oy = blockIdx.y*16 + ty;
  int Hi = Ho >> 1, Wi = Wo >> 1;
  float acc[CH];
  #pragma unroll
  for (int c=0;c<CH;c++) acc[c]=0.f;
  int ky0 = (oy+1)&1, kx0 = (ox+1)&1;
  for (int ci=0; ci<CH; ci++){
    const float* ip = in + (size_t)ci*Hi*Wi;
    const float* wci = w + (size_t)ci*CH*16;
    #pragma unroll
    for (int t2=0;t2<2;t2++){
      int ky = ky0 + 2*t2;
      int iy = (oy+1-ky) >> 1;
      if (iy < 0 || iy >= Hi) continue;
      #pragma unroll
      for (int u=0;u<2;u++){
        int kx = kx0 + 2*u;
        int ix = (ox+1-kx) >> 1;
        if (ix < 0 || ix >= Wi) continue;
        float v = ip[(size_t)iy*Wi + ix];
        const float* wp = wci + ky*4 + kx;
        #pragma unroll
        for (int co=0;co<CH;co++) acc[co] = fmaf(v, wp[co*16], acc[co]);
      }
    }
  }
  float* ob = out + (size_t)oy*Wo + ox;
  #pragma unroll
  for (int co=0;co<CH;co++) ob[(size_t)co*Ho*Wo] = acc[co];
}

// 1x1 conv 48->24 over concat(A,B)
__global__ void k_squeeze(const float* __restrict__ inA, const float* __restrict__ inB,
                          const float* __restrict__ w, float* __restrict__ out, int HW){
  int p = blockIdx.x*256 + threadIdx.x;
  if (p >= HW) return;
  float va[CH], vb[CH];
  #pragma unroll
  for (int c=0;c<CH;c++){ va[c]=inA[(size_t)c*HW + p]; vb[c]=inB[(size_t)c*HW + p]; }
  #pragma unroll
  for (int co=0;co<CH;co++){
    float a = 0.f;
    const float* wr = w + co*48;
    #pragma unroll
    for (int c=0;c<CH;c++) a = fmaf(va[c], wr[c], a);
    #pragma unroll
    for (int c=0;c<CH;c++) a = fmaf(vb[c], wr[24+c], a);
    out[(size_t)co*HW + p] = a;
  }
}

// vector quantization: argmin over 256 codes, dim 24. enc/qt: [24][HW]
__global__ void k_quant(const float* __restrict__ enc, const float* __restrict__ embed,
                        float* __restrict__ qt, float* __restrict__ diffAcc, int HW){
  __shared__ float em[CH*256];   // -2 * embed
  __shared__ float e2[256];
  __shared__ float red[4];
  for (int i = threadIdx.x; i < CH*256; i += 256) em[i] = -2.0f * embed[i];
  {
    int j = threadIdx.x;
    float s = 0.f;
    #pragma unroll
    for (int c=0;c<CH;c++){ float e = embed[c*256+j]; s = fmaf(e,e,s); }
    e2[j] = s;
  }
  __syncthreads();
  int p = blockIdx.x*256 + threadIdx.x;
  float d = 0.f;
  if (p < HW){
    float f[CH];
    #pragma unroll
    for (int c=0;c<CH;c++) f[c] = enc[(size_t)c*HW + p];
    float best = 3.4e38f; int bj = 0;
    for (int j=0;j<256;j++){
      float s = e2[j];
      #pragma unroll
      for (int c=0;c<CH;c++) s = fmaf(f[c], em[c*256+j], s);
      if (s < best){ best = s; bj = j; }
    }
    #pragma unroll
    for (int c=0;c<CH;c++){
      float q = embed[c*256+bj];
      qt[(size_t)c*HW + p] = q;
      float e = q - f[c];
      d = fmaf(e,e,d);
    }
  }
  #pragma unroll
  for (int off=32; off>0; off>>=1) d += __shfl_down(d, off, 64);
  int lane = threadIdx.x & 63, wv = threadIdx.x >> 6;
  if (lane==0) red[wv] = d;
  __syncthreads();
  if (threadIdx.x==0) atomicAdd(diffAcc, red[0]+red[1]+red[2]+red[3]);
}

// final: mask = 1x1(24->1), clean = xl - mask
__global__ void k_final(const float* __restrict__ dec1, const float* __restrict__ w,
                        const float* __restrict__ xl, float* __restrict__ outMask,
                        float* __restrict__ outClean, int HW){
  int p = blockIdx.x*256 + threadIdx.x;
  if (p >= HW) return;
  float m = 0.f;
  #pragma unroll
  for (int c=0;c<CH;c++) m = fmaf(dec1[(size_t)c*HW + p], w[c], m);
  outMask[p] = m;
  outClean[p] = xl[p] - m;
}

__global__ void k_diff(const float* __restrict__ acc, float* __restrict__ out){
  out[0] = acc[0]*(1.f/3145728.f) + acc[1]*(1.f/786432.f);
}

// =======================================================================
extern "C" void kernel_launch(void* const* d_in, const int* in_sizes, int n_in,
                              void* d_out, int out_size, void* d_ws, size_t ws_size,
                              hipStream_t stream) {
  const float* x        = (const float*)d_in[0];
  const float* embed2   = (const float*)d_in[1];
  const float* embed3   = (const float*)d_in[2];
  const float* w_img_in = (const float*)d_in[3];
  const float* w_img_out= (const float*)d_in[4];
  const float* w_out_dd = (const float*)d_in[5];
  const float* w_out_dm = (const float*)d_in[6];
  const float* w_out_dt = (const float*)d_in[7];
  const float* w_out_ed = (const float*)d_in[8];
  const float* w_out_em = (const float*)d_in[9];
  const float* w_out_et = (const float*)d_in[10];
  const float* w_pw_dd  = (const float*)d_in[11];
  const float* w_pw_dm  = (const float*)d_in[12];
  const float* w_pw_dt  = (const float*)d_in[13];
  const float* w_pw_ed  = (const float*)d_in[14];
  const float* w_pw_em  = (const float*)d_in[15];
  const float* w_pw_et  = (const float*)d_in[16];
  const float* w_res_dd = (const float*)d_in[17];
  const float* w_res_dm = (const float*)d_in[18];
  const float* w_res_dt = (const float*)d_in[19];
  const float* w_res_ed = (const float*)d_in[20];
  const float* w_res_em = (const float*)d_in[21];
  const float* w_res_et = (const float*)d_in[22];
  const float* w_sa_dd  = (const float*)d_in[23];
  const float* w_sa_dm  = (const float*)d_in[24];
  const float* w_sa_dt  = (const float*)d_in[25];
  const float* w_sa_ed  = (const float*)d_in[26];
  const float* w_sa_em  = (const float*)d_in[27];
  const float* w_sa_et  = (const float*)d_in[28];
  const float* w_squ1   = (const float*)d_in[29];
  const float* w_squ2   = (const float*)d_in[30];
  (void)in_sizes; (void)n_in; (void)out_size;

  const int HW512 = 512*512, HW256 = 256*256, HW128 = 128*128, HW64 = 64*64;

  // ---- per-image workspace layout (floats), total 15,925,250 (~63.7 MB) ----
  float* ws   = (float*)d_ws;
  float* XLb  = ws;                 // 262,144
  float* A512 = ws + 262144;        // 6,291,456
  float* B512 = ws + 6553600;       // 6,291,456
  float* E1b  = ws + 12845056;      // 1,572,864 (24 x 256^2)
  float* E2b  = ws + 14417920;      //   393,216 (24 x 128^2)
  float* Q2b  = ws + 14811136;      //   393,216
  float* E3b  = ws + 15204352;      //    98,304 (24 x 64^2)
  float* Q3b  = ws + 15302656;      //    98,304
  float* MMb  = ws + 15400960;      //   524,288 (2 x 512^2)
  float* DIFF = ws + 15925248;      // 2
  const size_t NEED = (size_t)15925250 * sizeof(float);
  if (ws_size < NEED) return;

  float* SA = A512;   // @256/@128 scratch aliases (A512/B512 dead then)
  float* SB = B512;
  float* OUT = (float*)d_out;

  hipMemsetAsync(DIFF, 0, 2*sizeof(float), stream);

  for (int b = 0; b < 8; b++){
    const float* xb = x + (size_t)b*3*HW512;

    // stage 0
    k_lap<<<dim3(HW512/256), 256, 0, stream>>>(xb, XLb, 512, 512);
    k_expand<<<dim3(CH*HW512/256), 256, 0, stream>>>(XLb, w_img_in, A512, HW512);

    // enc et @512
    k_conv<7><<<dim3(32,32), 256, 0, stream>>>(A512, w_res_et, B512, 512, 512);
    k_pw<<<dim3(HW512/256), 256, 0, stream>>>(B512, w_pw_et, B512, MMb, HW512);
    k_attn_res<<<dim3(HW512/256), 256, 0, stream>>>(B512, MMb, A512, w_sa_et, A512, 512, 512);
    k_down<<<dim3(16,16), 256, 0, stream>>>(A512, w_out_et, E1b, 256, 256);

    // enc em @256
    k_conv<5><<<dim3(16,16), 256, 0, stream>>>(E1b, w_res_em, SA, 256, 256);
    k_pw<<<dim3(HW256/256), 256, 0, stream>>>(SA, w_pw_em, SA, MMb, HW256);
    k_attn_res<<<dim3(HW256/256), 256, 0, stream>>>(SA, MMb, E1b, w_sa_em, SB, 256, 256);
    k_down<<<dim3(8,8), 256, 0, stream>>>(SB, w_out_em, E2b, 128, 128);

    // enc ed @128
    k_conv<3><<<dim3(8,8), 256, 0, stream>>>(E2b, w_res_ed, SA, 128, 128);
    k_pw<<<dim3(HW128/256), 256, 0, stream>>>(SA, w_pw_ed, SA, MMb, HW128);
    k_attn_res<<<dim3(HW128/256), 256, 0, stream>>>(SA, MMb, E2b, w_sa_ed, SB, 128, 128);
    k_down<<<dim3(4,4), 256, 0, stream>>>(SB, w_out_ed, E3b, 64, 64);

    // quantize
    k_quant<<<dim3(HW128/256), 256, 0, stream>>>(E2b, embed2, Q2b, DIFF+0, HW128);
    k_quant<<<dim3(HW64/256), 256, 0, stream>>>(E3b, embed3, Q3b, DIFF+1, HW64);

    // dec dd @128
    k_convT<<<dim3(8,8), 256, 0, stream>>>(Q3b, w_out_dd, SA, 128, 128);
    k_conv<3><<<dim3(8,8), 256, 0, stream>>>(SA, w_res_dd, SB, 128, 128);
    k_pw<<<dim3(HW128/256), 256, 0, stream>>>(SB, w_pw_dd, SB, MMb, HW128);
    k_attn_res<<<dim3(HW128/256), 256, 0, stream>>>(SB, MMb, SA, w_sa_dd, SA, 128, 128);

    // squ2: concat[dec3(SA), qt2] -> SB
    k_squeeze<<<dim3(HW128/256), 256, 0, stream>>>(SA, Q2b, w_squ2, SB, HW128);

    // dec dm @256
    k_convT<<<dim3(16,16), 256, 0, stream>>>(SB, w_out_dm, SA, 256, 256);
    k_conv<5><<<dim3(16,16), 256, 0, stream>>>(SA, w_res_dm, SB, 256, 256);
    k_pw<<<dim3(HW256/256), 256, 0, stream>>>(SB, w_pw_dm, SB, MMb, HW256);
    k_attn_res<<<dim3(HW256/256), 256, 0, stream>>>(SB, MMb, SA, w_sa_dm, SA, 256, 256);

    // squ1: concat[dec2(SA), enc1] -> SB
    k_squeeze<<<dim3(HW256/256), 256, 0, stream>>>(SA, E1b, w_squ1, SB, HW256);

    // dec dt @512
    k_convT<<<dim3(32,32), 256, 0, stream>>>(SB, w_out_dt, A512, 512, 512);
    k_conv<7><<<dim3(32,32), 256, 0, stream>>>(A512, w_res_dt, B512, 512, 512);
    k_pw<<<dim3(HW512/256), 256, 0, stream>>>(B512, w_pw_dt, B512, MMb, HW512);
    k_attn_res<<<dim3(HW512/256), 256, 0, stream>>>(B512, MMb, A512, w_sa_dt, A512, 512, 512);

    // final outputs for image b
    k_final<<<dim3(HW512/256), 256, 0, stream>>>(A512, w_img_out, XLb,
                                                 OUT + (size_t)b*HW512,
                                                 OUT + 2097152 + (size_t)b*HW512, HW512);
  }

  k_diff<<<1, 1, 0, stream>>>(DIFF, OUT + 4194304);
}

// Round 3
// 8215.758 us; speedup vs baseline: 2.3966x; 2.3966x over previous
//
#include <hip/hip_runtime.h>
#include <math.h>

#define CH 24

// ================= weight reorder kernels (run each call, negligible) =================
// res conv [co][ci][ky][kx] -> [ky][kx][ci][co]
__global__ void k_r_res(const float* __restrict__ w, float* __restrict__ wT, int K){
  int i = blockIdx.x*256 + threadIdx.x;
  int n = 576*K*K; if (i >= n) return;
  int co = i % 24, ci = (i/24) % 24, kk = i/576;
  int ky = kk / K, kx = kk % K;
  wT[i] = w[((co*24+ci)*K+ky)*K+kx];
}
// 4x4 kernels: OIHW (tr=0) or IOHW (tr=1) -> [ky][kx][ci][co]
__global__ void k_r4(const float* __restrict__ w, float* __restrict__ wT, int tr){
  int i = blockIdx.x*256 + threadIdx.x;
  if (i >= 9216) return;
  int co = i % 24, ci = (i/24) % 24, kk = i/576;
  int ky = kk / 4, kx = kk % 4;
  wT[i] = tr ? w[((ci*24+co)*4+ky)*4+kx] : w[((co*24+ci)*4+ky)*4+kx];
}
// pointwise [co][cin] -> [cin][co]
__global__ void k_r_pw(const float* __restrict__ w, float* __restrict__ wT, int CIN){
  int i = blockIdx.x*256 + threadIdx.x;
  if (i >= CIN*24) return;
  int co = i % 24, ci = i/24;
  wT[i] = w[co*CIN+ci];
}

// ================= compute kernels (z = image index via stride) =================

// mean over 3 ch + 3x3 Laplacian (zero pad). x: [3][H][W] -> xl: [H][W]  (per-image base)
__global__ void k_lap(const float* __restrict__ x, float* __restrict__ xl, int H, int W){
  int idx = blockIdx.x*256 + threadIdx.x;
  int HW = H*W;
  if (idx >= HW) return;
  int px = idx % W, py = idx / W;
#define MEANV(yy,xx) (((yy)>=0&&(yy)<H&&(xx)>=0&&(xx)<W) ? (x[(yy)*W+(xx)]+x[HW+(yy)*W+(xx)]+x[2*HW+(yy)*W+(xx)])*(1.f/3.f) : 0.f)
  float v = 4.f*MEANV(py,px) - MEANV(py-1,px) - MEANV(py+1,px) - MEANV(py,px-1) - MEANV(py,px+1);
#undef MEANV
  xl[idx] = v;
}

// 1x1 conv 1 -> 24, float4
__global__ void k_expand(const float* __restrict__ xl, const float* __restrict__ w,
                         float* __restrict__ out, int HW){
  int p = (blockIdx.x*256 + threadIdx.x)*4;
  if (p >= HW) return;
  float4 v = *(const float4*)(xl + p);
  #pragma unroll
  for (int c=0;c<CH;c++){
    float wc = w[c];
    float4 o; o.x=v.x*wc; o.y=v.y*wc; o.z=v.z*wc; o.w=v.w*wc;
    *(float4*)(out + (size_t)c*HW + p) = o;
  }
}

// KxK conv 24->24, pad K/2, stride 1. Register-blocked, wT=[ky][kx][ci][co].
template<int K, int TH>
__launch_bounds__(256)
__global__ void k_conv(const float* __restrict__ in, const float* __restrict__ wT,
                       float* __restrict__ out, int H, int W, int istrIn, int istrOut){
  constexpr int TW = 32;
  constexpr int PX = (TW*TH)/256;     // pixels per thread (x-dir)
  constexpr int XT = TW/PX;           // threads across x
  constexpr int SW = TW + K - 1;
  constexpr int SWP = SW | 1;         // odd stride -> no 4-way bank conflicts
  constexpr int SH = TH + K - 1;
  constexpr int CC = 8;               // ci chunk
  __shared__ float tile[CC*SH*SWP];
  int tx = threadIdx.x % XT, ty = threadIdx.x / XT;
  int x0 = blockIdx.x*TW - K/2, y0 = blockIdx.y*TH - K/2;
  const float* inb = in + (size_t)blockIdx.z*istrIn;
  float acc[CH][PX];
  #pragma unroll
  for (int co=0;co<CH;co++)
    #pragma unroll
    for (int px=0;px<PX;px++) acc[co][px] = 0.f;

  #pragma unroll 1
  for (int c0=0;c0<CH;c0+=CC){
    __syncthreads();
    for (int i=threadIdx.x; i<CC*SH*SW; i+=256){
      int col = i % SW; int rr = i / SW; int row = rr % SH; int c = rr / SH;
      int gy = y0+row, gx = x0+col;
      tile[(c*SH+row)*SWP+col] = (gy>=0 && gy<H && gx>=0 && gx<W)
          ? inb[(size_t)(c0+c)*H*W + (size_t)gy*W + gx] : 0.f;
    }
    __syncthreads();
    #pragma unroll 1
    for (int ci=0;ci<CC;ci++){
      #pragma unroll 1
      for (int ky=0;ky<K;ky++){
        const float* trow = &tile[(ci*SH + ty+ky)*SWP + tx*PX];
        #pragma unroll
        for (int kx=0;kx<K;kx++){
          float v[PX];
          #pragma unroll
          for (int px=0;px<PX;px++) v[px] = trow[kx+px];
          const float* wp = wT + ((ky*K+kx)*24 + c0+ci)*24;
          #pragma unroll
          for (int co=0;co<CH;co++){
            float wv = wp[co];
            #pragma unroll
            for (int px=0;px<PX;px++) acc[co][px] = fmaf(v[px], wv, acc[co][px]);
          }
        }
      }
    }
  }
  int oy = blockIdx.y*TH+ty, ox = blockIdx.x*TW+tx*PX;
  float* ob = out + (size_t)blockIdx.z*istrOut + (size_t)oy*W + ox;
  #pragma unroll
  for (int co=0;co<CH;co++){
    if (PX == 4){
      float4 o; o.x=acc[co][0]; o.y=acc[co][1]; o.z=acc[co][PX>2?2:0]; o.w=acc[co][PX>3?3:0];
      *(float4*)(ob + (size_t)co*H*W) = o;
    } else {
      float2 o; o.x=acc[co][0]; o.y=acc[co][1];
      *(float2*)(ob + (size_t)co*H*W) = o;
    }
  }
}

// 1x1 conv 24->24 (+mean/max maps), float4, in-place safe
__global__ void k_pw(const float* in, const float* __restrict__ wT,
                     float* out, float* __restrict__ mm, int HW, int istr, int istrMM){
  int p = (blockIdx.x*256 + threadIdx.x)*4;
  if (p >= HW) return;
  const float* ib = in + (size_t)blockIdx.z*istr;
  float acc[CH][4];
  #pragma unroll
  for (int co=0;co<CH;co++){ acc[co][0]=0;acc[co][1]=0;acc[co][2]=0;acc[co][3]=0; }
  #pragma unroll 1
  for (int ci=0;ci<CH;ci++){
    float4 v = *(const float4*)(ib + (size_t)ci*HW + p);
    const float* wp = wT + ci*24;
    #pragma unroll
    for (int co=0;co<CH;co++){
      float wv = wp[co];
      acc[co][0] = fmaf(v.x, wv, acc[co][0]);
      acc[co][1] = fmaf(v.y, wv, acc[co][1]);
      acc[co][2] = fmaf(v.z, wv, acc[co][2]);
      acc[co][3] = fmaf(v.w, wv, acc[co][3]);
    }
  }
  float mean[4]={0,0,0,0}, mx[4]={-3.4e38f,-3.4e38f,-3.4e38f,-3.4e38f};
  #pragma unroll
  for (int co=0;co<CH;co++)
    #pragma unroll
    for (int j=0;j<4;j++){ mean[j]+=acc[co][j]; mx[j]=fmaxf(mx[j],acc[co][j]); }
  float* ob = out + (size_t)blockIdx.z*istr;
  #pragma unroll
  for (int co=0;co<CH;co++){
    float4 o; o.x=acc[co][0]; o.y=acc[co][1]; o.z=acc[co][2]; o.w=acc[co][3];
    *(float4*)(ob + (size_t)co*HW + p) = o;
  }
  float* mb = mm + (size_t)blockIdx.z*istrMM;
  float4 me; me.x=mean[0]*(1.f/24.f); me.y=mean[1]*(1.f/24.f); me.z=mean[2]*(1.f/24.f); me.w=mean[3]*(1.f/24.f);
  float4 mxo; mxo.x=mx[0]; mxo.y=mx[1]; mxo.z=mx[2]; mxo.w=mx[3];
  *(float4*)(mb + p) = me;
  *(float4*)(mb + HW + p) = mxo;
}

// spatial attn (7x7 2->1) + sigmoid + relu + residual add; out may alias X
__global__ void k_attn_res(const float* __restrict__ R, const float* __restrict__ M,
                           const float* X, const float* __restrict__ wsa,
                           float* out, int H, int W, int istr, int istrMM){
  int p = (blockIdx.x*256 + threadIdx.x)*4;
  int HW = H*W;
  if (p >= HW) return;
  int py = p / W, px0 = p % W;
  const float* Mb = M + (size_t)blockIdx.z*istrMM;
  float s[4]={0,0,0,0};
  #pragma unroll
  for (int cc=0;cc<2;cc++){
    const float* Mc = Mb + (size_t)cc*HW;
    #pragma unroll 1
    for (int ky=0;ky<7;ky++){
      int gy = py+ky-3;
      if (gy<0||gy>=H) continue;
      const float* mr = Mc + (size_t)gy*W;
      float mv[10];
      #pragma unroll
      for (int j=0;j<10;j++){
        int gx = px0-3+j;
        mv[j] = (gx>=0 && gx<W) ? mr[gx] : 0.f;
      }
      const float* wr = wsa + (cc*7+ky)*7;
      #pragma unroll
      for (int kx=0;kx<7;kx++){
        float wv = wr[kx];
        #pragma unroll
        for (int px=0;px<4;px++) s[px] = fmaf(mv[kx+px], wv, s[px]);
      }
    }
  }
  float g[4];
  #pragma unroll
  for (int px=0;px<4;px++) g[px] = 1.f/(1.f+expf(-s[px]));
  const float* Rb = R + (size_t)blockIdx.z*istr;
  const float* Xb = X + (size_t)blockIdx.z*istr;
  float* Ob = out + (size_t)blockIdx.z*istr;
  #pragma unroll
  for (int c=0;c<CH;c++){
    float4 r = *(const float4*)(Rb + (size_t)c*HW + p);
    float4 xv = *(const float4*)(Xb + (size_t)c*HW + p);
    float4 o;
    o.x = xv.x + fmaxf(r.x*g[0], 0.f);
    o.y = xv.y + fmaxf(r.y*g[1], 0.f);
    o.z = xv.z + fmaxf(r.z*g[2], 0.f);
    o.w = xv.w + fmaxf(r.w*g[3], 0.f);
    *(float4*)(Ob + (size_t)c*HW + p) = o;
  }
}

// 4x4 s2 p1 downsample; wT=[ky][kx][ci][co]; 2px/thread, tile 32x16
__global__ void k_down(const float* __restrict__ in, const float* __restrict__ wT,
                       float* __restrict__ out, int Ho, int Wo, int istrIn, int istrOut){
  int tx = threadIdx.x % 16, ty = threadIdx.x / 16;
  int ox0 = blockIdx.x*32 + tx*2, oy = blockIdx.y*16 + ty;
  int Hi = Ho*2, Wi = Wo*2;
  const float* inb = in + (size_t)blockIdx.z*istrIn;
  float acc[CH][2];
  #pragma unroll
  for (int c=0;c<CH;c++){ acc[c][0]=0; acc[c][1]=0; }
  #pragma unroll 1
  for (int ci=0;ci<CH;ci++){
    const float* ip = inb + (size_t)ci*Hi*Wi;
    #pragma unroll
    for (int ky=0;ky<4;ky++){
      int iy = 2*oy + ky - 1;
      if (iy < 0 || iy >= Hi) continue;
      #pragma unroll
      for (int kx=0;kx<4;kx++){
        int ix0 = 2*ox0 + kx - 1;
        float v0 = (ix0>=0 && ix0<Wi) ? ip[(size_t)iy*Wi + ix0] : 0.f;
        int ix1 = ix0 + 2;
        float v1 = (ix1 < Wi) ? ip[(size_t)iy*Wi + ix1] : 0.f;
        const float* wp = wT + ((ky*4+kx)*24+ci)*24;
        #pragma unroll
        for (int co=0;co<CH;co++){
          float wv = wp[co];
          acc[co][0] = fmaf(v0, wv, acc[co][0]);
          acc[co][1] = fmaf(v1, wv, acc[co][1]);
        }
      }
    }
  }
  float* ob = out + (size_t)blockIdx.z*istrOut + (size_t)oy*Wo + ox0;
  #pragma unroll
  for (int co=0;co<CH;co++){
    float2 o; o.x=acc[co][0]; o.y=acc[co][1];
    *(float2*)(ob + (size_t)co*Ho*Wo) = o;
  }
}

// ConvTranspose2d(k=4,s=2,p=1); wT=[ky][kx][ci][co] from IOHW; 2px/thread
__global__ void k_convT(const float* __restrict__ in, const float* __restrict__ wT,
                        float* __restrict__ out, int Ho, int Wo, int istrIn, int istrOut){
  int tx = threadIdx.x % 16, ty = threadIdx.x / 16;
  int ox0 = blockIdx.x*32 + tx*2, oy = blockIdx.y*16 + ty;
  int Hi = Ho >> 1, Wi = Wo >> 1;
  const float* inb = in + (size_t)blockIdx.z*istrIn;
  float acc[CH][2];
  #pragma unroll
  for (int c=0;c<CH;c++){ acc[c][0]=0; acc[c][1]=0; }
  int ky0 = (oy+1)&1;
  #pragma unroll 1
  for (int ci=0;ci<CH;ci++){
    const float* ip = inb + (size_t)ci*Hi*Wi;
    #pragma unroll
    for (int px=0;px<2;px++){
      int ox = ox0 + px;
      int kx0 = (ox+1)&1;
      #pragma unroll
      for (int t2=0;t2<2;t2++){
        int ky = ky0 + 2*t2;
        int iy = (oy+1-ky) >> 1;
        if (iy < 0 || iy >= Hi) continue;
        #pragma unroll
        for (int u=0;u<2;u++){
          int kx = kx0 + 2*u;
          int ix = (ox+1-kx) >> 1;
          if (ix < 0 || ix >= Wi) continue;
          float v = ip[(size_t)iy*Wi + ix];
          const float* wp = wT + ((ky*4+kx)*24+ci)*24;
          #pragma unroll
          for (int co=0;co<CH;co++) acc[co][px] = fmaf(v, wp[co], acc[co][px]);
        }
      }
    }
  }
  float* ob = out + (size_t)blockIdx.z*istrOut + (size_t)oy*Wo + ox0;
  #pragma unroll
  for (int co=0;co<CH;co++){
    float2 o; o.x=acc[co][0]; o.y=acc[co][1];
    *(float2*)(ob + (size_t)co*Ho*Wo) = o;
  }
}

// 1x1 conv 48->24 over concat(A,B); wT=[ci(48)][co]
__global__ void k_squeeze(const float* __restrict__ inA, const float* __restrict__ inB,
                          const float* __restrict__ wT, float* __restrict__ out, int HW, int istr){
  int p = (blockIdx.x*256 + threadIdx.x)*4;
  if (p >= HW) return;
  const float* Ab = inA + (size_t)blockIdx.z*istr;
  const float* Bb = inB + (size_t)blockIdx.z*istr;
  float acc[CH][4];
  #pragma unroll
  for (int co=0;co<CH;co++){ acc[co][0]=0;acc[co][1]=0;acc[co][2]=0;acc[co][3]=0; }
  #pragma unroll 1
  for (int ci=0;ci<48;ci++){
    const float* src = (ci<24) ? (Ab + (size_t)ci*HW) : (Bb + (size_t)(ci-24)*HW);
    float4 v = *(const float4*)(src + p);
    const float* wp = wT + ci*24;
    #pragma unroll
    for (int co=0;co<CH;co++){
      float wv = wp[co];
      acc[co][0] = fmaf(v.x, wv, acc[co][0]);
      acc[co][1] = fmaf(v.y, wv, acc[co][1]);
      acc[co][2] = fmaf(v.z, wv, acc[co][2]);
      acc[co][3] = fmaf(v.w, wv, acc[co][3]);
    }
  }
  float* ob = out + (size_t)blockIdx.z*istr;
  #pragma unroll
  for (int co=0;co<CH;co++){
    float4 o; o.x=acc[co][0]; o.y=acc[co][1]; o.z=acc[co][2]; o.w=acc[co][3];
    *(float4*)(ob + (size_t)co*HW + p) = o;
  }
}

// VQ: argmin over 256 codes dim 24; codebook transposed in LDS, rows of 28
__global__ void k_quant(const float* __restrict__ enc, const float* __restrict__ embed,
                        float* __restrict__ qt, float* __restrict__ diffAcc, int HW, int istr){
  __shared__ float em[256*28];
  __shared__ float red[4];
  {
    int j = threadIdx.x;
    float s = 0.f;
    #pragma unroll
    for (int c=0;c<CH;c++){
      float e = embed[c*256+j];
      em[j*28+c] = -2.0f*e;
      s = fmaf(e,e,s);
    }
    em[j*28+24] = s; em[j*28+25]=0.f; em[j*28+26]=0.f; em[j*28+27]=0.f;
  }
  __syncthreads();
  int p = blockIdx.x*256 + threadIdx.x;
  const float* eb = enc + (size_t)blockIdx.z*istr;
  float f[CH];
  #pragma unroll
  for (int c=0;c<CH;c++) f[c] = eb[(size_t)c*HW + p];
  float best = 3.4e38f; int bj = 0;
  #pragma unroll 1
  for (int j=0;j<256;j++){
    const float4* row = (const float4*)&em[j*28];
    float s = em[j*28+24];
    #pragma unroll
    for (int q4=0;q4<6;q4++){
      float4 r = row[q4];
      s = fmaf(f[q4*4+0], r.x, s);
      s = fmaf(f[q4*4+1], r.y, s);
      s = fmaf(f[q4*4+2], r.z, s);
      s = fmaf(f[q4*4+3], r.w, s);
    }
    if (s < best){ best = s; bj = j; }
  }
  float* qb = qt + (size_t)blockIdx.z*istr;
  float d = 0.f;
  #pragma unroll
  for (int c=0;c<CH;c++){
    float q = embed[c*256+bj];
    qb[(size_t)c*HW + p] = q;
    float e = q - f[c];
    d = fmaf(e,e,d);
  }
  #pragma unroll
  for (int off=32; off>0; off>>=1) d += __shfl_down(d, off, 64);
  int lane = threadIdx.x & 63, wv = threadIdx.x >> 6;
  if (lane==0) red[wv] = d;
  __syncthreads();
  if (threadIdx.x==0) atomicAdd(diffAcc, red[0]+red[1]+red[2]+red[3]);
}

// final: mask = 1x1(24->1), clean = xl - mask (per-image bases)
__global__ void k_final(const float* __restrict__ dec1, const float* __restrict__ w,
                        const float* __restrict__ xl, float* __restrict__ outMask,
                        float* __restrict__ outClean, int HW){
  int p = (blockIdx.x*256 + threadIdx.x)*4;
  if (p >= HW) return;
  float m[4]={0,0,0,0};
  #pragma unroll
  for (int c=0;c<CH;c++){
    float4 d = *(const float4*)(dec1 + (size_t)c*HW + p);
    float wc = w[c];
    m[0]=fmaf(d.x,wc,m[0]); m[1]=fmaf(d.y,wc,m[1]); m[2]=fmaf(d.z,wc,m[2]); m[3]=fmaf(d.w,wc,m[3]);
  }
  float4 xv = *(const float4*)(xl + p);
  float4 mo; mo.x=m[0]; mo.y=m[1]; mo.z=m[2]; mo.w=m[3];
  float4 co; co.x=xv.x-m[0]; co.y=xv.y-m[1]; co.z=xv.z-m[2]; co.w=xv.w-m[3];
  *(float4*)(outMask + p) = mo;
  *(float4*)(outClean + p) = co;
}

__global__ void k_diff(const float* __restrict__ acc, float* __restrict__ out){
  out[0] = acc[0]*(1.f/3145728.f) + acc[1]*(1.f/786432.f);
}

// =======================================================================
extern "C" void kernel_launch(void* const* d_in, const int* in_sizes, int n_in,
                              void* d_out, int out_size, void* d_ws, size_t ws_size,
                              hipStream_t stream) {
  const float* x        = (const float*)d_in[0];
  const float* embed2   = (const float*)d_in[1];
  const float* embed3   = (const float*)d_in[2];
  const float* w_img_in = (const float*)d_in[3];
  const float* w_img_out= (const float*)d_in[4];
  const float* w_out_dd = (const float*)d_in[5];
  const float* w_out_dm = (const float*)d_in[6];
  const float* w_out_dt = (const float*)d_in[7];
  const float* w_out_ed = (const float*)d_in[8];
  const float* w_out_em = (const float*)d_in[9];
  const float* w_out_et = (const float*)d_in[10];
  const float* w_pw_dd  = (const float*)d_in[11];
  const float* w_pw_dm  = (const float*)d_in[12];
  const float* w_pw_dt  = (const float*)d_in[13];
  const float* w_pw_ed  = (const float*)d_in[14];
  const float* w_pw_em  = (const float*)d_in[15];
  const float* w_pw_et  = (const float*)d_in[16];
  const float* w_res_dd = (const float*)d_in[17];
  const float* w_res_dm = (const float*)d_in[18];
  const float* w_res_dt = (const float*)d_in[19];
  const float* w_res_ed = (const float*)d_in[20];
  const float* w_res_em = (const float*)d_in[21];
  const float* w_res_et = (const float*)d_in[22];
  const float* w_sa_dd  = (const float*)d_in[23];
  const float* w_sa_dm  = (const float*)d_in[24];
  const float* w_sa_dt  = (const float*)d_in[25];
  const float* w_sa_ed  = (const float*)d_in[26];
  const float* w_sa_em  = (const float*)d_in[27];
  const float* w_sa_et  = (const float*)d_in[28];
  const float* w_squ1   = (const float*)d_in[29];
  const float* w_squ2   = (const float*)d_in[30];
  (void)in_sizes; (void)n_in; (void)out_size;

  const int HW512 = 512*512, HW256 = 256*256, HW128 = 128*128, HW64 = 64*64;
  const int S256 = 24*HW256, S128 = 24*HW128, S64 = 24*HW64;   // per-image channel-plane strides

  float* ws = (float*)d_ws;
  float* OUT = (float*)d_out;

  // ---- mode A (batched deep stages): 61,501,698 floats ----
  const size_t NEED_A = (size_t)61501698 * sizeof(float);
  // ---- mode B (per-image): 16,085,250 floats ----
  const size_t NEED_B = (size_t)16085250 * sizeof(float);
  bool modeA = (ws_size >= NEED_A);
  if (!modeA && ws_size < NEED_B) return;

  // WT sub-offsets (floats)
  float* WT      = ws;
  float* wt_et7  = WT + 0;
  float* wt_dt7  = WT + 28224;
  float* wt_em5  = WT + 56448;
  float* wt_dm5  = WT + 70848;
  float* wt_ed3  = WT + 85248;
  float* wt_dd3  = WT + 90432;
  float* wt_d_et = WT + 95616;
  float* wt_d_em = WT + 104832;
  float* wt_d_ed = WT + 114048;
  float* wt_c_dd = WT + 123264;
  float* wt_c_dm = WT + 132480;
  float* wt_c_dt = WT + 141696;
  float* wt_pw_et= WT + 150912;
  float* wt_pw_em= WT + 151488;
  float* wt_pw_ed= WT + 152064;
  float* wt_pw_dd= WT + 152640;
  float* wt_pw_dm= WT + 153216;
  float* wt_pw_dt= WT + 153792;
  float* wt_squ1 = WT + 154368;
  float* wt_squ2 = WT + 155520;
  size_t off = 160000;

  float *XL, *A512, *B512, *E1, *SA, *SB, *E2, *Q2, *E3, *Q3, *MM, *DIFF;
  if (modeA){
    XL   = ws + off; off += 2097152;
    A512 = ws + off; off += 6291456;
    B512 = ws + off; off += 6291456;
    E1   = ws + off; off += 12582912;
    SA   = ws + off; off += 12582912;
    SB   = ws + off; off += 12582912;
    E2   = ws + off; off += 3145728;
    Q2   = ws + off; off += 3145728;
    E3   = ws + off; off += 786432;
    Q3   = ws + off; off += 786432;
    MM   = ws + off; off += 1048576;
    DIFF = ws + off;
  } else {
    XL   = ws + off; off += 262144;
    A512 = ws + off; off += 6291456;
    B512 = ws + off; off += 6291456;
    E1   = ws + off; off += 1572864;
    E2   = ws + off; off += 393216;
    Q2   = ws + off; off += 393216;
    E3   = ws + off; off += 98304;
    Q3   = ws + off; off += 98304;
    MM   = ws + off; off += 524288;
    DIFF = ws + off;
    SA = A512; SB = B512;
  }

  // ---- weight reorders ----
  k_r_res<<<dim3((576*49+255)/256), 256, 0, stream>>>(w_res_et, wt_et7, 7);
  k_r_res<<<dim3((576*49+255)/256), 256, 0, stream>>>(w_res_dt, wt_dt7, 7);
  k_r_res<<<dim3((576*25+255)/256), 256, 0, stream>>>(w_res_em, wt_em5, 5);
  k_r_res<<<dim3((576*25+255)/256), 256, 0, stream>>>(w_res_dm, wt_dm5, 5);
  k_r_res<<<dim3((576*9+255)/256), 256, 0, stream>>>(w_res_ed, wt_ed3, 3);
  k_r_res<<<dim3((576*9+255)/256), 256, 0, stream>>>(w_res_dd, wt_dd3, 3);
  k_r4<<<dim3(36), 256, 0, stream>>>(w_out_et, wt_d_et, 0);
  k_r4<<<dim3(36), 256, 0, stream>>>(w_out_em, wt_d_em, 0);
  k_r4<<<dim3(36), 256, 0, stream>>>(w_out_ed, wt_d_ed, 0);
  k_r4<<<dim3(36), 256, 0, stream>>>(w_out_dd, wt_c_dd, 1);
  k_r4<<<dim3(36), 256, 0, stream>>>(w_out_dm, wt_c_dm, 1);
  k_r4<<<dim3(36), 256, 0, stream>>>(w_out_dt, wt_c_dt, 1);
  k_r_pw<<<dim3(3), 256, 0, stream>>>(w_pw_et, wt_pw_et, 24);
  k_r_pw<<<dim3(3), 256, 0, stream>>>(w_pw_em, wt_pw_em, 24);
  k_r_pw<<<dim3(3), 256, 0, stream>>>(w_pw_ed, wt_pw_ed, 24);
  k_r_pw<<<dim3(3), 256, 0, stream>>>(w_pw_dd, wt_pw_dd, 24);
  k_r_pw<<<dim3(3), 256, 0, stream>>>(w_pw_dm, wt_pw_dm, 24);
  k_r_pw<<<dim3(3), 256, 0, stream>>>(w_pw_dt, wt_pw_dt, 24);
  k_r_pw<<<dim3(5), 256, 0, stream>>>(w_squ1, wt_squ1, 48);
  k_r_pw<<<dim3(5), 256, 0, stream>>>(w_squ2, wt_squ2, 48);

  hipMemsetAsync(DIFF, 0, 2*sizeof(float), stream);

  // ---- phase helpers ----
  auto phase1 = [&](int b, float* XLb, float* E1dst){
    const float* xb = x + (size_t)b*3*HW512;
    k_lap<<<dim3(HW512/256), 256, 0, stream>>>(xb, XLb, 512, 512);
    k_expand<<<dim3(HW512/1024), 256, 0, stream>>>(XLb, w_img_in, A512, HW512);
    k_conv<7,16><<<dim3(16,32,1), 256, 0, stream>>>(A512, wt_et7, B512, 512, 512, 0, 0);
    k_pw<<<dim3(HW512/1024,1,1), 256, 0, stream>>>(B512, wt_pw_et, B512, MM, HW512, 0, 0);
    k_attn_res<<<dim3(HW512/1024,1,1), 256, 0, stream>>>(B512, MM, A512, w_sa_et, A512, 512, 512, 0, 0);
    k_down<<<dim3(8,16,1), 256, 0, stream>>>(A512, wt_d_et, E1dst, 256, 256, 0, 0);
  };

  auto deep = [&](int nb, float* E1p, float* SAp, float* SBp, float* E2p, float* Q2p,
                  float* E3p, float* Q3p, float* MMp){
    int mm256 = 2*HW256, mm128 = 2*HW128;
    // enc em @256: E1 -> SB (enc result pre-down), E2
    if (nb==8) k_conv<5,32><<<dim3(8,8,8), 256, 0, stream>>>(E1p, wt_em5, SAp, 256, 256, S256, S256);
    else       k_conv<5,16><<<dim3(8,16,1), 256, 0, stream>>>(E1p, wt_em5, SAp, 256, 256, S256, S256);
    k_pw<<<dim3(HW256/1024,1,nb), 256, 0, stream>>>(SAp, wt_pw_em, SAp, MMp, HW256, S256, mm256);
    k_attn_res<<<dim3(HW256/1024,1,nb), 256, 0, stream>>>(SAp, MMp, E1p, w_sa_em, SBp, 256, 256, S256, mm256);
    k_down<<<dim3(4,8,nb), 256, 0, stream>>>(SBp, wt_d_em, E2p, 128, 128, S256, S128);
    // enc ed @128
    if (nb==8) k_conv<3,32><<<dim3(4,4,8), 256, 0, stream>>>(E2p, wt_ed3, SAp, 128, 128, S128, S128);
    else       k_conv<3,16><<<dim3(4,8,1), 256, 0, stream>>>(E2p, wt_ed3, SAp, 128, 128, S128, S128);
    k_pw<<<dim3(HW128/1024,1,nb), 256, 0, stream>>>(SAp, wt_pw_ed, SAp, MMp, HW128, S128, mm128);
    k_attn_res<<<dim3(HW128/1024,1,nb), 256, 0, stream>>>(SAp, MMp, E2p, w_sa_ed, SBp, 128, 128, S128, mm128);
    k_down<<<dim3(2,4,nb), 256, 0, stream>>>(SBp, wt_d_ed, E3p, 64, 64, S128, S64);
    // quantize
    k_quant<<<dim3(HW128/256,1,nb), 256, 0, stream>>>(E2p, embed2, Q2p, DIFF+0, HW128, S128);
    k_quant<<<dim3(HW64/256,1,nb), 256, 0, stream>>>(E3p, embed3, Q3p, DIFF+1, HW64, S64);
    // dec dd @128: convT(Q3) -> SA; res -> SA
    k_convT<<<dim3(4,8,nb), 256, 0, stream>>>(Q3p, wt_c_dd, SAp, 128, 128, S64, S128);
    if (nb==8) k_conv<3,32><<<dim3(4,4,8), 256, 0, stream>>>(SAp, wt_dd3, SBp, 128, 128, S128, S128);
    else       k_conv<3,16><<<dim3(4,8,1), 256, 0, stream>>>(SAp, wt_dd3, SBp, 128, 128, S128, S128);
    k_pw<<<dim3(HW128/1024,1,nb), 256, 0, stream>>>(SBp, wt_pw_dd, SBp, MMp, HW128, S128, mm128);
    k_attn_res<<<dim3(HW128/1024,1,nb), 256, 0, stream>>>(SBp, MMp, SAp, w_sa_dd, SAp, 128, 128, S128, mm128);
    // squ2: concat[dec3(SA), Q2] -> SB
    k_squeeze<<<dim3(HW128/1024,1,nb), 256, 0, stream>>>(SAp, Q2p, wt_squ2, SBp, HW128, S128);
    // dec dm @256: convT(SB) -> SA; res -> SA
    k_convT<<<dim3(8,16,nb), 256, 0, stream>>>(SBp, wt_c_dm, SAp, 256, 256, S128, S256);
    if (nb==8) k_conv<5,32><<<dim3(8,8,8), 256, 0, stream>>>(SAp, wt_dm5, SBp, 256, 256, S256, S256);
    else       k_conv<5,16><<<dim3(8,16,1), 256, 0, stream>>>(SAp, wt_dm5, SBp, 256, 256, S256, S256);
    k_pw<<<dim3(HW256/1024,1,nb), 256, 0, stream>>>(SBp, wt_pw_dm, SBp, MMp, HW256, S256, mm256);
    k_attn_res<<<dim3(HW256/1024,1,nb), 256, 0, stream>>>(SBp, MMp, SAp, w_sa_dm, SAp, 256, 256, S256, mm256);
    // squ1: concat[dec2(SA), E1] -> SB  (phase-3 input)
    k_squeeze<<<dim3(HW256/1024,1,nb), 256, 0, stream>>>(SAp, E1p, wt_squ1, SBp, HW256, S256);
  };

  auto phase3 = [&](int b, const float* D1INb, const float* XLb){
    k_convT<<<dim3(16,32,1), 256, 0, stream>>>(D1INb, wt_c_dt, A512, 512, 512, 0, 0);
    k_conv<7,16><<<dim3(16,32,1), 256, 0, stream>>>(A512, wt_dt7, B512, 512, 512, 0, 0);
    k_pw<<<dim3(HW512/1024,1,1), 256, 0, stream>>>(B512, wt_pw_dt, B512, MM, HW512, 0, 0);
    k_attn_res<<<dim3(HW512/1024,1,1), 256, 0, stream>>>(B512, MM, A512, w_sa_dt, A512, 512, 512, 0, 0);
    k_final<<<dim3(HW512/1024), 256, 0, stream>>>(A512, w_img_out, XLb,
                                                  OUT + (size_t)b*HW512,
                                                  OUT + 2097152 + (size_t)b*HW512, HW512);
  };

  if (modeA){
    for (int b=0;b<8;b++) phase1(b, XL + (size_t)b*HW512, E1 + (size_t)b*S256);
    deep(8, E1, SA, SB, E2, Q2, E3, Q3, MM);
    for (int b=0;b<8;b++) phase3(b, SB + (size_t)b*S256, XL + (size_t)b*HW512);
  } else {
    for (int b=0;b<8;b++){
      phase1(b, XL, E1);
      deep(1, E1, SA, SB, E2, Q2, E3, Q3, MM);
      phase3(b, SB, XL);
    }
  }

  k_diff<<<1, 1, 0, stream>>>(DIFF, OUT + 4194304);
}

// Round 4
// 5594.801 us; speedup vs baseline: 3.5193x; 1.4685x over previous
//
#include <hip/hip_runtime.h>
#include <math.h>

#define CH 24

// ================= weight reorder kernels =================
__global__ void k_r_res(const float* __restrict__ w, float* __restrict__ wT, int K){
  int i = blockIdx.x*256 + threadIdx.x;
  int n = 576*K*K; if (i >= n) return;
  int co = i % 24, ci = (i/24) % 24, kk = i/576;
  int ky = kk / K, kx = kk % K;
  wT[i] = w[((co*24+ci)*K+ky)*K+kx];
}
__global__ void k_r4(const float* __restrict__ w, float* __restrict__ wT, int tr){
  int i = blockIdx.x*256 + threadIdx.x;
  if (i >= 9216) return;
  int co = i % 24, ci = (i/24) % 24, kk = i/576;
  int ky = kk / 4, kx = kk % 4;
  wT[i] = tr ? w[((ci*24+co)*4+ky)*4+kx] : w[((co*24+ci)*4+ky)*4+kx];
}
__global__ void k_r_pw(const float* __restrict__ w, float* __restrict__ wT, int CIN){
  int i = blockIdx.x*256 + threadIdx.x;
  if (i >= CIN*24) return;
  int co = i % 24, ci = i/24;
  wT[i] = w[co*CIN+ci];
}

// ================= compute kernels (blockIdx.z = image, via strides) =================

__global__ void k_lap(const float* __restrict__ x, float* __restrict__ xl, int H, int W){
  int idx = blockIdx.x*256 + threadIdx.x;
  int HW = H*W;
  if (idx >= HW) return;
  const float* xb = x + (size_t)blockIdx.z*3*HW;
  float* xo = xl + (size_t)blockIdx.z*HW;
  int px = idx % W, py = idx / W;
#define MEANV(yy,xx) (((yy)>=0&&(yy)<H&&(xx)>=0&&(xx)<W) ? (xb[(yy)*W+(xx)]+xb[HW+(yy)*W+(xx)]+xb[2*HW+(yy)*W+(xx)])*(1.f/3.f) : 0.f)
  float v = 4.f*MEANV(py,px) - MEANV(py-1,px) - MEANV(py+1,px) - MEANV(py,px-1) - MEANV(py,px+1);
#undef MEANV
  xo[idx] = v;
}

__global__ void k_expand(const float* __restrict__ xl, const float* __restrict__ w,
                         float* __restrict__ out, int HW, int ostr){
  int p = (blockIdx.x*256 + threadIdx.x)*4;
  if (p >= HW) return;
  float4 v = *(const float4*)(xl + (size_t)blockIdx.z*HW + p);
  float* ob = out + (size_t)blockIdx.z*ostr;
  #pragma unroll
  for (int c=0;c<CH;c++){
    float wc = w[c];
    float4 o; o.x=v.x*wc; o.y=v.y*wc; o.z=v.z*wc; o.w=v.w*wc;
    *(float4*)(ob + (size_t)c*HW + p) = o;
  }
}

// KxK conv 24->24, pad K/2, stride 1. wT=[ky][kx][ci][co]. Tile 32 x TH.
template<int K, int TH>
__launch_bounds__(256)
__global__ void k_conv(const float* __restrict__ in, const float* __restrict__ wT,
                       float* __restrict__ out, int H, int W, int istrIn, int istrOut){
  constexpr int TW = 32;
  constexpr int PX = (TW*TH)/256;     // pixels per thread in x
  constexpr int XT = TW/PX;
  constexpr int SW = TW + K - 1;
  constexpr int SWP = SW | 1;
  constexpr int SH = TH + K - 1;
  constexpr int CC = 8;
  __shared__ float tile[CC*SH*SWP];
  int tx = threadIdx.x % XT, ty = threadIdx.x / XT;
  int x0 = blockIdx.x*TW - K/2, y0 = blockIdx.y*TH - K/2;
  const float* inb = in + (size_t)blockIdx.z*istrIn;
  float acc[CH][PX];
  #pragma unroll
  for (int co=0;co<CH;co++)
    #pragma unroll
    for (int px=0;px<PX;px++) acc[co][px] = 0.f;

  #pragma unroll 1
  for (int c0=0;c0<CH;c0+=CC){
    __syncthreads();
    for (int i=threadIdx.x; i<CC*SH*SW; i+=256){
      int col = i % SW; int rr = i / SW; int row = rr % SH; int c = rr / SH;
      int gy = y0+row, gx = x0+col;
      tile[(c*SH+row)*SWP+col] = (gy>=0 && gy<H && gx>=0 && gx<W)
          ? inb[(size_t)(c0+c)*H*W + (size_t)gy*W + gx] : 0.f;
    }
    __syncthreads();
    #pragma unroll 1
    for (int ci=0;ci<CC;ci++){
      #pragma unroll 1
      for (int ky=0;ky<K;ky++){
        const float* trow = &tile[(ci*SH + ty+ky)*SWP + tx*PX];
        #pragma unroll
        for (int kx=0;kx<K;kx++){
          float v[PX];
          #pragma unroll
          for (int px=0;px<PX;px++) v[px] = trow[kx+px];
          const float* wp = wT + ((ky*K+kx)*24 + c0+ci)*24;
          #pragma unroll
          for (int co=0;co<CH;co++){
            float wv = wp[co];
            #pragma unroll
            for (int px=0;px<PX;px++) acc[co][px] = fmaf(v[px], wv, acc[co][px]);
          }
        }
      }
    }
  }
  int oy = blockIdx.y*TH+ty, ox = blockIdx.x*TW+tx*PX;
  float* ob = out + (size_t)blockIdx.z*istrOut + (size_t)oy*W + ox;
  #pragma unroll
  for (int co=0;co<CH;co++){
    if (PX == 4){
      float4 o; o.x=acc[co][0]; o.y=acc[co][1]; o.z=acc[co][PX>2?2:0]; o.w=acc[co][PX>3?3:0];
      *(float4*)(ob + (size_t)co*H*W) = o;
    } else if (PX == 2){
      float2 o; o.x=acc[co][0]; o.y=acc[co][1];
      *(float2*)(ob + (size_t)co*H*W) = o;
    } else {
      ob[(size_t)co*H*W] = acc[co][0];
    }
  }
}

__global__ void k_pw(const float* in, const float* __restrict__ wT,
                     float* out, float* __restrict__ mm, int HW, int istr, int istrMM){
  int p = (blockIdx.x*256 + threadIdx.x)*4;
  if (p >= HW) return;
  const float* ib = in + (size_t)blockIdx.z*istr;
  float acc[CH][4];
  #pragma unroll
  for (int co=0;co<CH;co++){ acc[co][0]=0;acc[co][1]=0;acc[co][2]=0;acc[co][3]=0; }
  #pragma unroll 1
  for (int ci=0;ci<CH;ci++){
    float4 v = *(const float4*)(ib + (size_t)ci*HW + p);
    const float* wp = wT + ci*24;
    #pragma unroll
    for (int co=0;co<CH;co++){
      float wv = wp[co];
      acc[co][0] = fmaf(v.x, wv, acc[co][0]);
      acc[co][1] = fmaf(v.y, wv, acc[co][1]);
      acc[co][2] = fmaf(v.z, wv, acc[co][2]);
      acc[co][3] = fmaf(v.w, wv, acc[co][3]);
    }
  }
  float mean[4]={0,0,0,0}, mx[4]={-3.4e38f,-3.4e38f,-3.4e38f,-3.4e38f};
  #pragma unroll
  for (int co=0;co<CH;co++)
    #pragma unroll
    for (int j=0;j<4;j++){ mean[j]+=acc[co][j]; mx[j]=fmaxf(mx[j],acc[co][j]); }
  float* ob = out + (size_t)blockIdx.z*istr;
  #pragma unroll
  for (int co=0;co<CH;co++){
    float4 o; o.x=acc[co][0]; o.y=acc[co][1]; o.z=acc[co][2]; o.w=acc[co][3];
    *(float4*)(ob + (size_t)co*HW + p) = o;
  }
  float* mb = mm + (size_t)blockIdx.z*istrMM;
  float4 me; me.x=mean[0]*(1.f/24.f); me.y=mean[1]*(1.f/24.f); me.z=mean[2]*(1.f/24.f); me.w=mean[3]*(1.f/24.f);
  float4 mxo; mxo.x=mx[0]; mxo.y=mx[1]; mxo.z=mx[2]; mxo.w=mx[3];
  *(float4*)(mb + p) = me;
  *(float4*)(mb + HW + p) = mxo;
}

__global__ void k_attn_res(const float* __restrict__ R, const float* __restrict__ M,
                           const float* X, const float* __restrict__ wsa,
                           float* out, int H, int W, int istr, int istrMM){
  int p = (blockIdx.x*256 + threadIdx.x)*4;
  int HW = H*W;
  if (p >= HW) return;
  int py = p / W, px0 = p % W;
  const float* Mb = M + (size_t)blockIdx.z*istrMM;
  float s[4]={0,0,0,0};
  #pragma unroll
  for (int cc=0;cc<2;cc++){
    const float* Mc = Mb + (size_t)cc*HW;
    #pragma unroll 1
    for (int ky=0;ky<7;ky++){
      int gy = py+ky-3;
      if (gy<0||gy>=H) continue;
      const float* mr = Mc + (size_t)gy*W;
      float mv[10];
      #pragma unroll
      for (int j=0;j<10;j++){
        int gx = px0-3+j;
        mv[j] = (gx>=0 && gx<W) ? mr[gx] : 0.f;
      }
      const float* wr = wsa + (cc*7+ky)*7;
      #pragma unroll
      for (int kx=0;kx<7;kx++){
        float wv = wr[kx];
        #pragma unroll
        for (int px=0;px<4;px++) s[px] = fmaf(mv[kx+px], wv, s[px]);
      }
    }
  }
  float g[4];
  #pragma unroll
  for (int px=0;px<4;px++) g[px] = 1.f/(1.f+expf(-s[px]));
  const float* Rb = R + (size_t)blockIdx.z*istr;
  const float* Xb = X + (size_t)blockIdx.z*istr;
  float* Ob = out + (size_t)blockIdx.z*istr;
  #pragma unroll
  for (int c=0;c<CH;c++){
    float4 r = *(const float4*)(Rb + (size_t)c*HW + p);
    float4 xv = *(const float4*)(Xb + (size_t)c*HW + p);
    float4 o;
    o.x = xv.x + fmaxf(r.x*g[0], 0.f);
    o.y = xv.y + fmaxf(r.y*g[1], 0.f);
    o.z = xv.z + fmaxf(r.z*g[2], 0.f);
    o.w = xv.w + fmaxf(r.w*g[3], 0.f);
    *(float4*)(Ob + (size_t)c*HW + p) = o;
  }
}

__global__ void k_down(const float* __restrict__ in, const float* __restrict__ wT,
                       float* __restrict__ out, int Ho, int Wo, int istrIn, int istrOut){
  int tx = threadIdx.x % 16, ty = threadIdx.x / 16;
  int ox0 = blockIdx.x*32 + tx*2, oy = blockIdx.y*16 + ty;
  int Hi = Ho*2, Wi = Wo*2;
  const float* inb = in + (size_t)blockIdx.z*istrIn;
  float acc[CH][2];
  #pragma unroll
  for (int c=0;c<CH;c++){ acc[c][0]=0; acc[c][1]=0; }
  #pragma unroll 1
  for (int ci=0;ci<CH;ci++){
    const float* ip = inb + (size_t)ci*Hi*Wi;
    #pragma unroll
    for (int ky=0;ky<4;ky++){
      int iy = 2*oy + ky - 1;
      if (iy < 0 || iy >= Hi) continue;
      #pragma unroll
      for (int kx=0;kx<4;kx++){
        int ix0 = 2*ox0 + kx - 1;
        float v0 = (ix0>=0 && ix0<Wi) ? ip[(size_t)iy*Wi + ix0] : 0.f;
        int ix1 = ix0 + 2;
        float v1 = (ix1 < Wi) ? ip[(size_t)iy*Wi + ix1] : 0.f;
        const float* wp = wT + ((ky*4+kx)*24+ci)*24;
        #pragma unroll
        for (int co=0;co<CH;co++){
          float wv = wp[co];
          acc[co][0] = fmaf(v0, wv, acc[co][0]);
          acc[co][1] = fmaf(v1, wv, acc[co][1]);
        }
      }
    }
  }
  float* ob = out + (size_t)blockIdx.z*istrOut + (size_t)oy*Wo + ox0;
  #pragma unroll
  for (int co=0;co<CH;co++){
    float2 o; o.x=acc[co][0]; o.y=acc[co][1];
    *(float2*)(ob + (size_t)co*Ho*Wo) = o;
  }
}

__global__ void k_convT(const float* __restrict__ in, const float* __restrict__ wT,
                        float* __restrict__ out, int Ho, int Wo, int istrIn, int istrOut){
  int tx = threadIdx.x % 16, ty = threadIdx.x / 16;
  int ox0 = blockIdx.x*32 + tx*2, oy = blockIdx.y*16 + ty;
  int Hi = Ho >> 1, Wi = Wo >> 1;
  const float* inb = in + (size_t)blockIdx.z*istrIn;
  float acc[CH][2];
  #pragma unroll
  for (int c=0;c<CH;c++){ acc[c][0]=0; acc[c][1]=0; }
  int ky0 = (oy+1)&1;
  #pragma unroll 1
  for (int ci=0;ci<CH;ci++){
    const float* ip = inb + (size_t)ci*Hi*Wi;
    #pragma unroll
    for (int px=0;px<2;px++){
      int ox = ox0 + px;
      int kx0 = (ox+1)&1;
      #pragma unroll
      for (int t2=0;t2<2;t2++){
        int ky = ky0 + 2*t2;
        int iy = (oy+1-ky) >> 1;
        if (iy < 0 || iy >= Hi) continue;
        #pragma unroll
        for (int u=0;u<2;u++){
          int kx = kx0 + 2*u;
          int ix = (ox+1-kx) >> 1;
          if (ix < 0 || ix >= Wi) continue;
          float v = ip[(size_t)iy*Wi + ix];
          const float* wp = wT + ((ky*4+kx)*24+ci)*24;
          #pragma unroll
          for (int co=0;co<CH;co++) acc[co][px] = fmaf(v, wp[co], acc[co][px]);
        }
      }
    }
  }
  float* ob = out + (size_t)blockIdx.z*istrOut + (size_t)oy*Wo + ox0;
  #pragma unroll
  for (int co=0;co<CH;co++){
    float2 o; o.x=acc[co][0]; o.y=acc[co][1];
    *(float2*)(ob + (size_t)co*Ho*Wo) = o;
  }
}

// 1x1 conv 48->24 over concat(A,B); out may alias inB (per-pixel in-place safe)
__global__ void k_squeeze(const float* __restrict__ inA, const float* inB,
                          const float* __restrict__ wT, float* out, int HW, int istr){
  int p = (blockIdx.x*256 + threadIdx.x)*4;
  if (p >= HW) return;
  const float* Ab = inA + (size_t)blockIdx.z*istr;
  const float* Bb = inB + (size_t)blockIdx.z*istr;
  float acc[CH][4];
  #pragma unroll
  for (int co=0;co<CH;co++){ acc[co][0]=0;acc[co][1]=0;acc[co][2]=0;acc[co][3]=0; }
  #pragma unroll 1
  for (int ci=0;ci<48;ci++){
    const float* src = (ci<24) ? (Ab + (size_t)ci*HW) : (Bb + (size_t)(ci-24)*HW);
    float4 v = *(const float4*)(src + p);
    const float* wp = wT + ci*24;
    #pragma unroll
    for (int co=0;co<CH;co++){
      float wv = wp[co];
      acc[co][0] = fmaf(v.x, wv, acc[co][0]);
      acc[co][1] = fmaf(v.y, wv, acc[co][1]);
      acc[co][2] = fmaf(v.z, wv, acc[co][2]);
      acc[co][3] = fmaf(v.w, wv, acc[co][3]);
    }
  }
  float* ob = out + (size_t)blockIdx.z*istr;
  #pragma unroll
  for (int co=0;co<CH;co++){
    float4 o; o.x=acc[co][0]; o.y=acc[co][1]; o.z=acc[co][2]; o.w=acc[co][3];
    *(float4*)(ob + (size_t)co*HW + p) = o;
  }
}

__global__ void k_quant(const float* __restrict__ enc, const float* __restrict__ embed,
                        float* __restrict__ qt, float* __restrict__ diffAcc, int HW, int istr){
  __shared__ float em[256*28];
  __shared__ float red[4];
  {
    int j = threadIdx.x;
    float s = 0.f;
    #pragma unroll
    for (int c=0;c<CH;c++){
      float e = embed[c*256+j];
      em[j*28+c] = -2.0f*e;
      s = fmaf(e,e,s);
    }
    em[j*28+24] = s; em[j*28+25]=0.f; em[j*28+26]=0.f; em[j*28+27]=0.f;
  }
  __syncthreads();
  int p = blockIdx.x*256 + threadIdx.x;
  const float* eb = enc + (size_t)blockIdx.z*istr;
  float f[CH];
  #pragma unroll
  for (int c=0;c<CH;c++) f[c] = eb[(size_t)c*HW + p];
  float best = 3.4e38f; int bj = 0;
  #pragma unroll 1
  for (int j=0;j<256;j++){
    const float4* row = (const float4*)&em[j*28];
    float s = em[j*28+24];
    #pragma unroll
    for (int q4=0;q4<6;q4++){
      float4 r = row[q4];
      s = fmaf(f[q4*4+0], r.x, s);
      s = fmaf(f[q4*4+1], r.y, s);
      s = fmaf(f[q4*4+2], r.z, s);
      s = fmaf(f[q4*4+3], r.w, s);
    }
    if (s < best){ best = s; bj = j; }
  }
  float* qb = qt + (size_t)blockIdx.z*istr;
  float d = 0.f;
  #pragma unroll
  for (int c=0;c<CH;c++){
    float q = embed[c*256+bj];
    qb[(size_t)c*HW + p] = q;
    float e = q - f[c];
    d = fmaf(e,e,d);
  }
  #pragma unroll
  for (int off=32; off>0; off>>=1) d += __shfl_down(d, off, 64);
  int lane = threadIdx.x & 63, wv = threadIdx.x >> 6;
  if (lane==0) red[wv] = d;
  __syncthreads();
  if (threadIdx.x==0) atomicAdd(diffAcc, red[0]+red[1]+red[2]+red[3]);
}

__global__ void k_final(const float* __restrict__ dec1, const float* __restrict__ w,
                        const float* __restrict__ xl, float* __restrict__ outMask,
                        float* __restrict__ outClean, int HW, int dstr){
  int p = (blockIdx.x*256 + threadIdx.x)*4;
  if (p >= HW) return;
  const float* db = dec1 + (size_t)blockIdx.z*dstr;
  float m[4]={0,0,0,0};
  #pragma unroll
  for (int c=0;c<CH;c++){
    float4 d = *(const float4*)(db + (size_t)c*HW + p);
    float wc = w[c];
    m[0]=fmaf(d.x,wc,m[0]); m[1]=fmaf(d.y,wc,m[1]); m[2]=fmaf(d.z,wc,m[2]); m[3]=fmaf(d.w,wc,m[3]);
  }
  float4 xv = *(const float4*)(xl + (size_t)blockIdx.z*HW + p);
  float4 mo; mo.x=m[0]; mo.y=m[1]; mo.z=m[2]; mo.w=m[3];
  float4 co; co.x=xv.x-m[0]; co.y=xv.y-m[1]; co.z=xv.z-m[2]; co.w=xv.w-m[3];
  *(float4*)(outMask + (size_t)blockIdx.z*HW + p) = mo;
  *(float4*)(outClean + (size_t)blockIdx.z*HW + p) = co;
}

__global__ void k_diff(const float* __restrict__ acc, float* __restrict__ out){
  out[0] = acc[0]*(1.f/3145728.f) + acc[1]*(1.f/786432.f);
}

// =======================================================================
extern "C" void kernel_launch(void* const* d_in, const int* in_sizes, int n_in,
                              void* d_out, int out_size, void* d_ws, size_t ws_size,
                              hipStream_t stream) {
  const float* x        = (const float*)d_in[0];
  const float* embed2   = (const float*)d_in[1];
  const float* embed3   = (const float*)d_in[2];
  const float* w_img_in = (const float*)d_in[3];
  const float* w_img_out= (const float*)d_in[4];
  const float* w_out_dd = (const float*)d_in[5];
  const float* w_out_dm = (const float*)d_in[6];
  const float* w_out_dt = (const float*)d_in[7];
  const float* w_out_ed = (const float*)d_in[8];
  const float* w_out_em = (const float*)d_in[9];
  const float* w_out_et = (const float*)d_in[10];
  const float* w_pw_dd  = (const float*)d_in[11];
  const float* w_pw_dm  = (const float*)d_in[12];
  const float* w_pw_dt  = (const float*)d_in[13];
  const float* w_pw_ed  = (const float*)d_in[14];
  const float* w_pw_em  = (const float*)d_in[15];
  const float* w_pw_et  = (const float*)d_in[16];
  const float* w_res_dd = (const float*)d_in[17];
  const float* w_res_dm = (const float*)d_in[18];
  const float* w_res_dt = (const float*)d_in[19];
  const float* w_res_ed = (const float*)d_in[20];
  const float* w_res_em = (const float*)d_in[21];
  const float* w_res_et = (const float*)d_in[22];
  const float* w_sa_dd  = (const float*)d_in[23];
  const float* w_sa_dm  = (const float*)d_in[24];
  const float* w_sa_dt  = (const float*)d_in[25];
  const float* w_sa_ed  = (const float*)d_in[26];
  const float* w_sa_em  = (const float*)d_in[27];
  const float* w_sa_et  = (const float*)d_in[28];
  const float* w_squ1   = (const float*)d_in[29];
  const float* w_squ2   = (const float*)d_in[30];
  (void)in_sizes; (void)n_in; (void)out_size;

  const int HW512 = 512*512, HW256 = 256*256, HW128 = 128*128, HW64 = 64*64;
  const int S512 = 24*HW512, S256 = 24*HW256, S128 = 24*HW128, S64 = 24*HW64;

  float* ws = (float*)d_ws;
  float* OUT = (float*)d_out;
  size_t F = ws_size / sizeof(float);

  // ---- weight-reorder region ----
  float* WT      = ws;
  float* wt_et7  = WT + 0;
  float* wt_dt7  = WT + 28224;
  float* wt_em5  = WT + 56448;
  float* wt_dm5  = WT + 70848;
  float* wt_ed3  = WT + 85248;
  float* wt_dd3  = WT + 90432;
  float* wt_d_et = WT + 95616;
  float* wt_d_em = WT + 104832;
  float* wt_d_ed = WT + 114048;
  float* wt_c_dd = WT + 123264;
  float* wt_c_dm = WT + 132480;
  float* wt_c_dt = WT + 141696;
  float* wt_pw_et= WT + 150912;
  float* wt_pw_em= WT + 151488;
  float* wt_pw_ed= WT + 152064;
  float* wt_pw_dd= WT + 152640;
  float* wt_pw_dm= WT + 153216;
  float* wt_pw_dt= WT + 153792;
  float* wt_squ1 = WT + 154368;
  float* wt_squ2 = WT + 155520;

  // ---- choose mode: batched (CB images chunked @512, deep z=8) vs per-image ----
  auto needBatched = [&](size_t CB)->size_t{
    size_t u = (CB*(size_t)S512 > (size_t)8*S256) ? CB*(size_t)S512 : (size_t)8*S256;
    return 160000 + 2097152 + 12582912 + 3145728 + 786432 + 2 + CB*2*(size_t)HW512 + 2*u;
  };
  int CB = 0;
  if (F >= needBatched(8)) CB = 8;
  else if (F >= needBatched(4)) CB = 4;
  else if (F >= needBatched(2)) CB = 2;
  const size_t NEED_B = 16085250;
  if (CB == 0 && F < NEED_B) return;

  float *XL, *E1, *E2, *Q2, *E3, *Q3, *MM, *DIFF, *U1, *U2;
  if (CB > 0){
    size_t off = 160000;
    size_t u = (CB*(size_t)S512 > (size_t)8*S256) ? CB*(size_t)S512 : (size_t)8*S256;
    XL = ws + off; off += 2097152;
    E1 = ws + off; off += 12582912;
    Q2 = ws + off; off += 3145728;
    Q3 = ws + off; off += 786432;
    MM = ws + off; off += CB*2*(size_t)HW512;
    U1 = ws + off; off += u;
    U2 = ws + off; off += u;
    DIFF = ws + off;
    E2 = OUT;                 // dead before k_final writes
    E3 = OUT + 3145728;
  } else {
    size_t off = 160000;
    XL = ws + off; off += 262144;
    U1 = ws + off; off += 6291456;
    U2 = ws + off; off += 6291456;
    E1 = ws + off; off += 1572864;
    E2 = ws + off; off += 393216;
    Q2 = ws + off; off += 393216;
    E3 = ws + off; off += 98304;
    Q3 = ws + off; off += 98304;
    MM = ws + off; off += 524288;
    DIFF = ws + off;
  }

  // ---- weight reorders ----
  k_r_res<<<dim3((576*49+255)/256), 256, 0, stream>>>(w_res_et, wt_et7, 7);
  k_r_res<<<dim3((576*49+255)/256), 256, 0, stream>>>(w_res_dt, wt_dt7, 7);
  k_r_res<<<dim3((576*25+255)/256), 256, 0, stream>>>(w_res_em, wt_em5, 5);
  k_r_res<<<dim3((576*25+255)/256), 256, 0, stream>>>(w_res_dm, wt_dm5, 5);
  k_r_res<<<dim3((576*9+255)/256), 256, 0, stream>>>(w_res_ed, wt_ed3, 3);
  k_r_res<<<dim3((576*9+255)/256), 256, 0, stream>>>(w_res_dd, wt_dd3, 3);
  k_r4<<<dim3(36), 256, 0, stream>>>(w_out_et, wt_d_et, 0);
  k_r4<<<dim3(36), 256, 0, stream>>>(w_out_em, wt_d_em, 0);
  k_r4<<<dim3(36), 256, 0, stream>>>(w_out_ed, wt_d_ed, 0);
  k_r4<<<dim3(36), 256, 0, stream>>>(w_out_dd, wt_c_dd, 1);
  k_r4<<<dim3(36), 256, 0, stream>>>(w_out_dm, wt_c_dm, 1);
  k_r4<<<dim3(36), 256, 0, stream>>>(w_out_dt, wt_c_dt, 1);
  k_r_pw<<<dim3(3), 256, 0, stream>>>(w_pw_et, wt_pw_et, 24);
  k_r_pw<<<dim3(3), 256, 0, stream>>>(w_pw_em, wt_pw_em, 24);
  k_r_pw<<<dim3(3), 256, 0, stream>>>(w_pw_ed, wt_pw_ed, 24);
  k_r_pw<<<dim3(3), 256, 0, stream>>>(w_pw_dd, wt_pw_dd, 24);
  k_r_pw<<<dim3(3), 256, 0, stream>>>(w_pw_dm, wt_pw_dm, 24);
  k_r_pw<<<dim3(3), 256, 0, stream>>>(w_pw_dt, wt_pw_dt, 24);
  k_r_pw<<<dim3(5), 256, 0, stream>>>(w_squ1, wt_squ1, 48);
  k_r_pw<<<dim3(5), 256, 0, stream>>>(w_squ2, wt_squ2, 48);

  hipMemsetAsync(DIFF, 0, 2*sizeof(float), stream);

  // ---- phase 1: input -> enc1  (chunk of nz images starting at c0) ----
  auto phase1 = [&](int c0, int nz, float* XLp, float* E1p){
    k_lap<<<dim3(HW512/256,1,nz), 256, 0, stream>>>(x + (size_t)c0*3*HW512, XLp, 512, 512);
    k_expand<<<dim3(HW512/1024,1,nz), 256, 0, stream>>>(XLp, w_img_in, U1, HW512, S512);
    k_conv<7,8><<<dim3(16,64,nz), 256, 0, stream>>>(U1, wt_et7, U2, 512, 512, S512, S512);
    k_pw<<<dim3(HW512/1024,1,nz), 256, 0, stream>>>(U2, wt_pw_et, U2, MM, HW512, S512, 2*HW512);
    k_attn_res<<<dim3(HW512/1024,1,nz), 256, 0, stream>>>(U2, MM, U1, w_sa_et, U1, 512, 512, S512, 2*HW512);
    k_down<<<dim3(8,16,nz), 256, 0, stream>>>(U1, wt_d_et, E1p, 256, 256, S512, S256);
  };

  // ---- deep: enc1 -> squ1 output (written to D1 buffer) ----
  auto deep = [&](int nb, float* E1p, float* SAp, float* SBp, float* E2p, float* Q2p,
                  float* E3p, float* Q3p, float* MMp, float* D1p){
    int mm256 = 2*HW256, mm128 = 2*HW128;
    if (nb==8) k_conv<5,16><<<dim3(8,16,8), 256, 0, stream>>>(E1p, wt_em5, SAp, 256, 256, S256, S256);
    else       k_conv<5,8><<<dim3(8,32,1), 256, 0, stream>>>(E1p, wt_em5, SAp, 256, 256, S256, S256);
    k_pw<<<dim3(HW256/1024,1,nb), 256, 0, stream>>>(SAp, wt_pw_em, SAp, MMp, HW256, S256, mm256);
    k_attn_res<<<dim3(HW256/1024,1,nb), 256, 0, stream>>>(SAp, MMp, E1p, w_sa_em, SBp, 256, 256, S256, mm256);
    k_down<<<dim3(4,8,nb), 256, 0, stream>>>(SBp, wt_d_em, E2p, 128, 128, S256, S128);
    k_conv<3,8><<<dim3(4,16,nb), 256, 0, stream>>>(E2p, wt_ed3, SAp, 128, 128, S128, S128);
    k_pw<<<dim3(HW128/1024,1,nb), 256, 0, stream>>>(SAp, wt_pw_ed, SAp, MMp, HW128, S128, mm128);
    k_attn_res<<<dim3(HW128/1024,1,nb), 256, 0, stream>>>(SAp, MMp, E2p, w_sa_ed, SBp, 128, 128, S128, mm128);
    k_down<<<dim3(2,4,nb), 256, 0, stream>>>(SBp, wt_d_ed, E3p, 64, 64, S128, S64);
    k_quant<<<dim3(HW128/256,1,nb), 256, 0, stream>>>(E2p, embed2, Q2p, DIFF+0, HW128, S128);
    k_quant<<<dim3(HW64/256,1,nb), 256, 0, stream>>>(E3p, embed3, Q3p, DIFF+1, HW64, S64);
    k_convT<<<dim3(4,8,nb), 256, 0, stream>>>(Q3p, wt_c_dd, SAp, 128, 128, S64, S128);
    k_conv<3,8><<<dim3(4,16,nb), 256, 0, stream>>>(SAp, wt_dd3, SBp, 128, 128, S128, S128);
    k_pw<<<dim3(HW128/1024,1,nb), 256, 0, stream>>>(SBp, wt_pw_dd, SBp, MMp, HW128, S128, mm128);
    k_attn_res<<<dim3(HW128/1024,1,nb), 256, 0, stream>>>(SBp, MMp, SAp, w_sa_dd, SAp, 128, 128, S128, mm128);
    k_squeeze<<<dim3(HW128/1024,1,nb), 256, 0, stream>>>(SAp, Q2p, wt_squ2, SBp, HW128, S128);
    k_convT<<<dim3(8,16,nb), 256, 0, stream>>>(SBp, wt_c_dm, SAp, 256, 256, S128, S256);
    if (nb==8) k_conv<5,16><<<dim3(8,16,8), 256, 0, stream>>>(SAp, wt_dm5, SBp, 256, 256, S256, S256);
    else       k_conv<5,8><<<dim3(8,32,1), 256, 0, stream>>>(SAp, wt_dm5, SBp, 256, 256, S256, S256);
    k_pw<<<dim3(HW256/1024,1,nb), 256, 0, stream>>>(SBp, wt_pw_dm, SBp, MMp, HW256, S256, mm256);
    k_attn_res<<<dim3(HW256/1024,1,nb), 256, 0, stream>>>(SBp, MMp, SAp, w_sa_dm, SAp, 256, 256, S256, mm256);
    // squ1: concat[dec2(SA), enc1(E1)] -> D1 (in batched mode D1p==E1p, per-pixel in-place safe)
    k_squeeze<<<dim3(HW256/1024,1,nb), 256, 0, stream>>>(SAp, E1p, wt_squ1, D1p, HW256, S256);
  };

  // ---- phase 3: D1 -> outputs  (chunk of nz images at c0) ----
  auto phase3 = [&](int c0, int nz, const float* D1p, const float* XLp){
    k_convT<<<dim3(16,32,nz), 256, 0, stream>>>(D1p, wt_c_dt, U1, 512, 512, S256, S512);
    k_conv<7,8><<<dim3(16,64,nz), 256, 0, stream>>>(U1, wt_dt7, U2, 512, 512, S512, S512);
    k_pw<<<dim3(HW512/1024,1,nz), 256, 0, stream>>>(U2, wt_pw_dt, U2, MM, HW512, S512, 2*HW512);
    k_attn_res<<<dim3(HW512/1024,1,nz), 256, 0, stream>>>(U2, MM, U1, w_sa_dt, U1, 512, 512, S512, 2*HW512);
    k_final<<<dim3(HW512/1024,1,nz), 256, 0, stream>>>(U1, w_img_out, XLp,
                                                       OUT + (size_t)c0*HW512,
                                                       OUT + 2097152 + (size_t)c0*HW512,
                                                       HW512, S512);
  };

  if (CB > 0){
    for (int c0=0;c0<8;c0+=CB)
      phase1(c0, CB, XL + (size_t)c0*HW512, E1 + (size_t)c0*S256);
    deep(8, E1, U1, U2, E2, Q2, E3, Q3, MM, E1);
    for (int c0=0;c0<8;c0+=CB)
      phase3(c0, CB, E1 + (size_t)c0*S256, XL + (size_t)c0*HW512);
  } else {
    for (int b=0;b<8;b++){
      phase1(b, 1, XL, E1);
      deep(1, E1, U1, U2, E2, Q2, E3, Q3, MM, U2);
      phase3(b, 1, U2, XL);
    }
  }

  k_diff<<<1, 1, 0, stream>>>(DIFF, OUT + 4194304);
}

// Round 5
// 3101.025 us; speedup vs baseline: 6.3495x; 1.8042x over previous
//
#include <hip/hip_runtime.h>
#include <math.h>

#define CH 24

typedef __attribute__((ext_vector_type(8))) short short8v;
typedef __attribute__((ext_vector_type(4))) float f32x4;
typedef unsigned short ushort_t;
typedef unsigned int uint_t;

__device__ inline ushort_t bf16r(float f){
  uint_t u = __float_as_uint(f);
  u += 0x7FFF + ((u>>16)&1);
  return (ushort_t)(u>>16);
}

// ================= weight reorder kernels =================
__global__ void k_r_res(const float* __restrict__ w, float* __restrict__ wT, int K){
  int i = blockIdx.x*256 + threadIdx.x;
  int n = 576*K*K; if (i >= n) return;
  int co = i % 24, ci = (i/24) % 24, kk = i/576;
  int ky = kk / K, kx = kk % K;
  wT[i] = w[((co*24+ci)*K+ky)*K+kx];
}
__global__ void k_r4(const float* __restrict__ w, float* __restrict__ wT, int tr){
  int i = blockIdx.x*256 + threadIdx.x;
  if (i >= 9216) return;
  int co = i % 24, ci = (i/24) % 24, kk = i/576;
  int ky = kk / 4, kx = kk % 4;
  wT[i] = tr ? w[((ci*24+co)*4+ky)*4+kx] : w[((co*24+ci)*4+ky)*4+kx];
}
__global__ void k_r_pw(const float* __restrict__ w, float* __restrict__ wT, int CIN){
  int i = blockIdx.x*256 + threadIdx.x;
  if (i >= CIN*24) return;
  int co = i % 24, ci = i/24;
  wT[i] = w[co*CIN+ci];
}
// MFMA-ready bf16 B-frags: wb[tap*1024 + t*512 + l*8 + j] = W[ci=(l>>4)*8+j][co=t*16+(l&15)]
__global__ void k_rmfma(const float* __restrict__ w, ushort_t* __restrict__ wb, int K){
  int i = blockIdx.x*256 + threadIdx.x;
  int n = K*K*1024; if (i >= n) return;
  int j = i & 7, l = (i>>3) & 63, t = (i>>9) & 1, tap = i >> 10;
  int ci = (l>>4)*8 + j, co = t*16 + (l&15);
  int ky = tap / K, kx = tap % K;
  float v = (ci<24 && co<24) ? w[((co*24+ci)*K+ky)*K+kx] : 0.f;
  wb[i] = bf16r(v);
}

// ================= compute kernels (blockIdx.z = image, via strides) =================

__global__ void k_lap(const float* __restrict__ x, float* __restrict__ xl, int H, int W){
  int idx = blockIdx.x*256 + threadIdx.x;
  int HW = H*W;
  if (idx >= HW) return;
  const float* xb = x + (size_t)blockIdx.z*3*HW;
  float* xo = xl + (size_t)blockIdx.z*HW;
  int px = idx % W, py = idx / W;
#define MEANV(yy,xx) (((yy)>=0&&(yy)<H&&(xx)>=0&&(xx)<W) ? (xb[(yy)*W+(xx)]+xb[HW+(yy)*W+(xx)]+xb[2*HW+(yy)*W+(xx)])*(1.f/3.f) : 0.f)
  float v = 4.f*MEANV(py,px) - MEANV(py-1,px) - MEANV(py+1,px) - MEANV(py,px-1) - MEANV(py,px+1);
#undef MEANV
  xo[idx] = v;
}

__global__ void k_expand(const float* __restrict__ xl, const float* __restrict__ w,
                         float* __restrict__ out, int HW, int ostr){
  int p = (blockIdx.x*256 + threadIdx.x)*4;
  if (p >= HW) return;
  float4 v = *(const float4*)(xl + (size_t)blockIdx.z*HW + p);
  float* ob = out + (size_t)blockIdx.z*ostr;
  #pragma unroll
  for (int c=0;c<CH;c++){
    float wc = w[c];
    float4 o; o.x=v.x*wc; o.y=v.y*wc; o.z=v.z*wc; o.w=v.w*wc;
    *(float4*)(ob + (size_t)c*HW + p) = o;
  }
}

// ---------- MFMA KxK conv 24->24, pad K/2. Block 512 thr = 8 waves, 32x16 out tile ----------
template<int K>
__launch_bounds__(512)
__global__ void k_conv_mfma(const float* __restrict__ in, const ushort_t* __restrict__ wb,
                            float* __restrict__ out, int H, int W, int istrIn, int istrOut){
  constexpr int SW_T = 32 + K - 1;
  constexpr int SH = 16 + K - 1;
  constexpr int NPX = SH*SW_T;
  __shared__ ushort_t lds[NPX*32];
  int tid = threadIdx.x;
  const float* inb = in + (size_t)blockIdx.z*istrIn;
  int x0g = blockIdx.x*32 - K/2, y0g = blockIdx.y*16 - K/2;
  int HW = H*W;
  // stage NCHW fp32 -> [px][32ch] bf16 (ch 24-31 zero), chunk-swizzled
  for (int i = tid; i < NPX*16; i += 512){
    int cpair = i / NPX;
    int pp = i - cpair*NPX;
    int c0 = cpair*2;
    int row = pp / SW_T, col = pp - row*SW_T;
    int gy = y0g + row, gx = x0g + col;
    float v0 = 0.f, v1 = 0.f;
    if (c0 < 24 && gy >= 0 && gy < H && gx >= 0 && gx < W){
      size_t base = (size_t)gy*W + gx;
      v0 = inb[(size_t)c0*HW + base];
      v1 = inb[(size_t)(c0+1)*HW + base];
    }
    uint_t packed = (uint_t)bf16r(v0) | ((uint_t)bf16r(v1) << 16);
    int slot = pp*32 + (c0 ^ ((pp&3)<<3));
    *(uint_t*)(lds + slot) = packed;
  }
  __syncthreads();
  int l = tid & 63, wid = tid >> 6;
  int kg = l >> 4, li = l & 15;
  f32x4 zero = {0.f,0.f,0.f,0.f};
  f32x4 acc[4][2];
  #pragma unroll
  for (int i=0;i<4;i++){ acc[i][0]=zero; acc[i][1]=zero; }

  for (int ky=0; ky<K; ky++){
    for (int kx=0; kx<K; kx++){
      int tap = ky*K + kx;
      const ushort_t* wp = wb + (size_t)tap*1024;
      short8v b0 = *(const short8v*)(wp + l*8);
      short8v b1 = *(const short8v*)(wp + 512 + l*8);
      #pragma unroll
      for (int i=0;i<4;i++){
        int pp = (wid + (i&1)*8 + ky)*SW_T + (i>>1)*16 + kx + li;
        short8v a = *(const short8v*)(lds + pp*32 + ((kg*8) ^ ((pp&3)<<3)));
        acc[i][0] = __builtin_amdgcn_mfma_f32_16x16x32_bf16(a, b0, acc[i][0], 0, 0, 0);
        acc[i][1] = __builtin_amdgcn_mfma_f32_16x16x32_bf16(a, b1, acc[i][1], 0, 0, 0);
      }
    }
  }
  float* outb = out + (size_t)blockIdx.z*istrOut;
  #pragma unroll
  for (int i=0;i<4;i++){
    int gy = blockIdx.y*16 + wid + (i&1)*8;
    int gx = blockIdx.x*32 + (i>>1)*16 + kg*4;
    float* o0 = outb + (size_t)li*HW + (size_t)gy*W + gx;
    *(f32x4*)o0 = acc[i][0];
    if (li < 8){
      float* o1 = outb + (size_t)(16+li)*HW + (size_t)gy*W + gx;
      *(f32x4*)o1 = acc[i][1];
    }
  }
}

// KxK conv fp32 (kept for K=3). wT=[ky][kx][ci][co]. Tile 32 x TH.
template<int K, int TH>
__launch_bounds__(256)
__global__ void k_conv(const float* __restrict__ in, const float* __restrict__ wT,
                       float* __restrict__ out, int H, int W, int istrIn, int istrOut){
  constexpr int TW = 32;
  constexpr int PX = (TW*TH)/256;
  constexpr int XT = TW/PX;
  constexpr int SW = TW + K - 1;
  constexpr int SWP = SW | 1;
  constexpr int SH = TH + K - 1;
  constexpr int CC = 8;
  __shared__ float tile[CC*SH*SWP];
  int tx = threadIdx.x % XT, ty = threadIdx.x / XT;
  int x0 = blockIdx.x*TW - K/2, y0 = blockIdx.y*TH - K/2;
  const float* inb = in + (size_t)blockIdx.z*istrIn;
  float acc[CH][PX];
  #pragma unroll
  for (int co=0;co<CH;co++)
    #pragma unroll
    for (int px=0;px<PX;px++) acc[co][px] = 0.f;

  #pragma unroll 1
  for (int c0=0;c0<CH;c0+=CC){
    __syncthreads();
    for (int i=threadIdx.x; i<CC*SH*SW; i+=256){
      int col = i % SW; int rr = i / SW; int row = rr % SH; int c = rr / SH;
      int gy = y0+row, gx = x0+col;
      tile[(c*SH+row)*SWP+col] = (gy>=0 && gy<H && gx>=0 && gx<W)
          ? inb[(size_t)(c0+c)*H*W + (size_t)gy*W + gx] : 0.f;
    }
    __syncthreads();
    #pragma unroll 1
    for (int ci=0;ci<CC;ci++){
      #pragma unroll 1
      for (int ky=0;ky<K;ky++){
        const float* trow = &tile[(ci*SH + ty+ky)*SWP + tx*PX];
        #pragma unroll
        for (int kx=0;kx<K;kx++){
          float v[PX];
          #pragma unroll
          for (int px=0;px<PX;px++) v[px] = trow[kx+px];
          const float* wp = wT + ((ky*K+kx)*24 + c0+ci)*24;
          #pragma unroll
          for (int co=0;co<CH;co++){
            float wv = wp[co];
            #pragma unroll
            for (int px=0;px<PX;px++) acc[co][px] = fmaf(v[px], wv, acc[co][px]);
          }
        }
      }
    }
  }
  int oy = blockIdx.y*TH+ty, ox = blockIdx.x*TW+tx*PX;
  float* ob = out + (size_t)blockIdx.z*istrOut + (size_t)oy*W + ox;
  #pragma unroll
  for (int co=0;co<CH;co++){
    if (PX == 4){
      float4 o; o.x=acc[co][0]; o.y=acc[co][1]; o.z=acc[co][PX>2?2:0]; o.w=acc[co][PX>3?3:0];
      *(float4*)(ob + (size_t)co*H*W) = o;
    } else if (PX == 2){
      float2 o; o.x=acc[co][0]; o.y=acc[co][1];
      *(float2*)(ob + (size_t)co*H*W) = o;
    } else {
      ob[(size_t)co*H*W] = acc[co][0];
    }
  }
}

__global__ void k_pw(const float* in, const float* __restrict__ wT,
                     float* out, float* __restrict__ mm, int HW, int istr, int istrMM){
  int p = (blockIdx.x*256 + threadIdx.x)*4;
  if (p >= HW) return;
  const float* ib = in + (size_t)blockIdx.z*istr;
  float acc[CH][4];
  #pragma unroll
  for (int co=0;co<CH;co++){ acc[co][0]=0;acc[co][1]=0;acc[co][2]=0;acc[co][3]=0; }
  #pragma unroll 1
  for (int ci=0;ci<CH;ci++){
    float4 v = *(const float4*)(ib + (size_t)ci*HW + p);
    const float* wp = wT + ci*24;
    #pragma unroll
    for (int co=0;co<CH;co++){
      float wv = wp[co];
      acc[co][0] = fmaf(v.x, wv, acc[co][0]);
      acc[co][1] = fmaf(v.y, wv, acc[co][1]);
      acc[co][2] = fmaf(v.z, wv, acc[co][2]);
      acc[co][3] = fmaf(v.w, wv, acc[co][3]);
    }
  }
  float mean[4]={0,0,0,0}, mx[4]={-3.4e38f,-3.4e38f,-3.4e38f,-3.4e38f};
  #pragma unroll
  for (int co=0;co<CH;co++)
    #pragma unroll
    for (int j=0;j<4;j++){ mean[j]+=acc[co][j]; mx[j]=fmaxf(mx[j],acc[co][j]); }
  float* ob = out + (size_t)blockIdx.z*istr;
  #pragma unroll
  for (int co=0;co<CH;co++){
    float4 o; o.x=acc[co][0]; o.y=acc[co][1]; o.z=acc[co][2]; o.w=acc[co][3];
    *(float4*)(ob + (size_t)co*HW + p) = o;
  }
  float* mb = mm + (size_t)blockIdx.z*istrMM;
  float4 me; me.x=mean[0]*(1.f/24.f); me.y=mean[1]*(1.f/24.f); me.z=mean[2]*(1.f/24.f); me.w=mean[3]*(1.f/24.f);
  float4 mxo; mxo.x=mx[0]; mxo.y=mx[1]; mxo.z=mx[2]; mxo.w=mx[3];
  *(float4*)(mb + p) = me;
  *(float4*)(mb + HW + p) = mxo;
}

__global__ void k_attn_res(const float* __restrict__ R, const float* __restrict__ M,
                           const float* X, const float* __restrict__ wsa,
                           float* out, int H, int W, int istr, int istrMM){
  int p = (blockIdx.x*256 + threadIdx.x)*4;
  int HW = H*W;
  if (p >= HW) return;
  int py = p / W, px0 = p % W;
  const float* Mb = M + (size_t)blockIdx.z*istrMM;
  float s[4]={0,0,0,0};
  #pragma unroll
  for (int cc=0;cc<2;cc++){
    const float* Mc = Mb + (size_t)cc*HW;
    #pragma unroll 1
    for (int ky=0;ky<7;ky++){
      int gy = py+ky-3;
      if (gy<0||gy>=H) continue;
      const float* mr = Mc + (size_t)gy*W;
      float mv[10];
      #pragma unroll
      for (int j=0;j<10;j++){
        int gx = px0-3+j;
        mv[j] = (gx>=0 && gx<W) ? mr[gx] : 0.f;
      }
      const float* wr = wsa + (cc*7+ky)*7;
      #pragma unroll
      for (int kx=0;kx<7;kx++){
        float wv = wr[kx];
        #pragma unroll
        for (int px=0;px<4;px++) s[px] = fmaf(mv[kx+px], wv, s[px]);
      }
    }
  }
  float g[4];
  #pragma unroll
  for (int px=0;px<4;px++) g[px] = 1.f/(1.f+expf(-s[px]));
  const float* Rb = R + (size_t)blockIdx.z*istr;
  const float* Xb = X + (size_t)blockIdx.z*istr;
  float* Ob = out + (size_t)blockIdx.z*istr;
  #pragma unroll
  for (int c=0;c<CH;c++){
    float4 r = *(const float4*)(Rb + (size_t)c*HW + p);
    float4 xv = *(const float4*)(Xb + (size_t)c*HW + p);
    float4 o;
    o.x = xv.x + fmaxf(r.x*g[0], 0.f);
    o.y = xv.y + fmaxf(r.y*g[1], 0.f);
    o.z = xv.z + fmaxf(r.z*g[2], 0.f);
    o.w = xv.w + fmaxf(r.w*g[3], 0.f);
    *(float4*)(Ob + (size_t)c*HW + p) = o;
  }
}

__global__ void k_down(const float* __restrict__ in, const float* __restrict__ wT,
                       float* __restrict__ out, int Ho, int Wo, int istrIn, int istrOut){
  int tx = threadIdx.x % 16, ty = threadIdx.x / 16;
  int ox0 = blockIdx.x*32 + tx*2, oy = blockIdx.y*16 + ty;
  int Hi = Ho*2, Wi = Wo*2;
  const float* inb = in + (size_t)blockIdx.z*istrIn;
  float acc[CH][2];
  #pragma unroll
  for (int c=0;c<CH;c++){ acc[c][0]=0; acc[c][1]=0; }
  #pragma unroll 1
  for (int ci=0;ci<CH;ci++){
    const float* ip = inb + (size_t)ci*Hi*Wi;
    #pragma unroll
    for (int ky=0;ky<4;ky++){
      int iy = 2*oy + ky - 1;
      if (iy < 0 || iy >= Hi) continue;
      #pragma unroll
      for (int kx=0;kx<4;kx++){
        int ix0 = 2*ox0 + kx - 1;
        float v0 = (ix0>=0 && ix0<Wi) ? ip[(size_t)iy*Wi + ix0] : 0.f;
        int ix1 = ix0 + 2;
        float v1 = (ix1 < Wi) ? ip[(size_t)iy*Wi + ix1] : 0.f;
        const float* wp = wT + ((ky*4+kx)*24+ci)*24;
        #pragma unroll
        for (int co=0;co<CH;co++){
          float wv = wp[co];
          acc[co][0] = fmaf(v0, wv, acc[co][0]);
          acc[co][1] = fmaf(v1, wv, acc[co][1]);
        }
      }
    }
  }
  float* ob = out + (size_t)blockIdx.z*istrOut + (size_t)oy*Wo + ox0;
  #pragma unroll
  for (int co=0;co<CH;co++){
    float2 o; o.x=acc[co][0]; o.y=acc[co][1];
    *(float2*)(ob + (size_t)co*Ho*Wo) = o;
  }
}

__global__ void k_convT(const float* __restrict__ in, const float* __restrict__ wT,
                        float* __restrict__ out, int Ho, int Wo, int istrIn, int istrOut){
  int tx = threadIdx.x % 16, ty = threadIdx.x / 16;
  int ox0 = blockIdx.x*32 + tx*2, oy = blockIdx.y*16 + ty;
  int Hi = Ho >> 1, Wi = Wo >> 1;
  const float* inb = in + (size_t)blockIdx.z*istrIn;
  float acc[CH][2];
  #pragma unroll
  for (int c=0;c<CH;c++){ acc[c][0]=0; acc[c][1]=0; }
  int ky0 = (oy+1)&1;
  #pragma unroll 1
  for (int ci=0;ci<CH;ci++){
    const float* ip = inb + (size_t)ci*Hi*Wi;
    #pragma unroll
    for (int px=0;px<2;px++){
      int ox = ox0 + px;
      int kx0 = (ox+1)&1;
      #pragma unroll
      for (int t2=0;t2<2;t2++){
        int ky = ky0 + 2*t2;
        int iy = (oy+1-ky) >> 1;
        if (iy < 0 || iy >= Hi) continue;
        #pragma unroll
        for (int u=0;u<2;u++){
          int kx = kx0 + 2*u;
          int ix = (ox+1-kx) >> 1;
          if (ix < 0 || ix >= Wi) continue;
          float v = ip[(size_t)iy*Wi + ix];
          const float* wp = wT + ((ky*4+kx)*24+ci)*24;
          #pragma unroll
          for (int co=0;co<CH;co++) acc[co][px] = fmaf(v, wp[co], acc[co][px]);
        }
      }
    }
  }
  float* ob = out + (size_t)blockIdx.z*istrOut + (size_t)oy*Wo + ox0;
  #pragma unroll
  for (int co=0;co<CH;co++){
    float2 o; o.x=acc[co][0]; o.y=acc[co][1];
    *(float2*)(ob + (size_t)co*Ho*Wo) = o;
  }
}

__global__ void k_squeeze(const float* __restrict__ inA, const float* inB,
                          const float* __restrict__ wT, float* out, int HW, int istr){
  int p = (blockIdx.x*256 + threadIdx.x)*4;
  if (p >= HW) return;
  const float* Ab = inA + (size_t)blockIdx.z*istr;
  const float* Bb = inB + (size_t)blockIdx.z*istr;
  float acc[CH][4];
  #pragma unroll
  for (int co=0;co<CH;co++){ acc[co][0]=0;acc[co][1]=0;acc[co][2]=0;acc[co][3]=0; }
  #pragma unroll 1
  for (int ci=0;ci<48;ci++){
    const float* src = (ci<24) ? (Ab + (size_t)ci*HW) : (Bb + (size_t)(ci-24)*HW);
    float4 v = *(const float4*)(src + p);
    const float* wp = wT + ci*24;
    #pragma unroll
    for (int co=0;co<CH;co++){
      float wv = wp[co];
      acc[co][0] = fmaf(v.x, wv, acc[co][0]);
      acc[co][1] = fmaf(v.y, wv, acc[co][1]);
      acc[co][2] = fmaf(v.z, wv, acc[co][2]);
      acc[co][3] = fmaf(v.w, wv, acc[co][3]);
    }
  }
  float* ob = out + (size_t)blockIdx.z*istr;
  #pragma unroll
  for (int co=0;co<CH;co++){
    float4 o; o.x=acc[co][0]; o.y=acc[co][1]; o.z=acc[co][2]; o.w=acc[co][3];
    *(float4*)(ob + (size_t)co*HW + p) = o;
  }
}

__global__ void k_quant(const float* __restrict__ enc, const float* __restrict__ embed,
                        float* __restrict__ qt, float* __restrict__ diffAcc, int HW, int istr){
  __shared__ float em[256*28];
  __shared__ float red[4];
  {
    int j = threadIdx.x;
    float s = 0.f;
    #pragma unroll
    for (int c=0;c<CH;c++){
      float e = embed[c*256+j];
      em[j*28+c] = -2.0f*e;
      s = fmaf(e,e,s);
    }
    em[j*28+24] = s; em[j*28+25]=0.f; em[j*28+26]=0.f; em[j*28+27]=0.f;
  }
  __syncthreads();
  int p = blockIdx.x*256 + threadIdx.x;
  const float* eb = enc + (size_t)blockIdx.z*istr;
  float f[CH];
  #pragma unroll
  for (int c=0;c<CH;c++) f[c] = eb[(size_t)c*HW + p];
  float best = 3.4e38f; int bj = 0;
  #pragma unroll 1
  for (int j=0;j<256;j++){
    const float4* row = (const float4*)&em[j*28];
    float s = em[j*28+24];
    #pragma unroll
    for (int q4=0;q4<6;q4++){
      float4 r = row[q4];
      s = fmaf(f[q4*4+0], r.x, s);
      s = fmaf(f[q4*4+1], r.y, s);
      s = fmaf(f[q4*4+2], r.z, s);
      s = fmaf(f[q4*4+3], r.w, s);
    }
    if (s < best){ best = s; bj = j; }
  }
  float* qb = qt + (size_t)blockIdx.z*istr;
  float d = 0.f;
  #pragma unroll
  for (int c=0;c<CH;c++){
    float q = embed[c*256+bj];
    qb[(size_t)c*HW + p] = q;
    float e = q - f[c];
    d = fmaf(e,e,d);
  }
  #pragma unroll
  for (int off=32; off>0; off>>=1) d += __shfl_down(d, off, 64);
  int lane = threadIdx.x & 63, wv = threadIdx.x >> 6;
  if (lane==0) red[wv] = d;
  __syncthreads();
  if (threadIdx.x==0) atomicAdd(diffAcc, red[0]+red[1]+red[2]+red[3]);
}

__global__ void k_final(const float* __restrict__ dec1, const float* __restrict__ w,
                        const float* __restrict__ xl, float* __restrict__ outMask,
                        float* __restrict__ outClean, int HW, int dstr){
  int p = (blockIdx.x*256 + threadIdx.x)*4;
  if (p >= HW) return;
  const float* db = dec1 + (size_t)blockIdx.z*dstr;
  float m[4]={0,0,0,0};
  #pragma unroll
  for (int c=0;c<CH;c++){
    float4 d = *(const float4*)(db + (size_t)c*HW + p);
    float wc = w[c];
    m[0]=fmaf(d.x,wc,m[0]); m[1]=fmaf(d.y,wc,m[1]); m[2]=fmaf(d.z,wc,m[2]); m[3]=fmaf(d.w,wc,m[3]);
  }
  float4 xv = *(const float4*)(xl + (size_t)blockIdx.z*HW + p);
  float4 mo; mo.x=m[0]; mo.y=m[1]; mo.z=m[2]; mo.w=m[3];
  float4 co; co.x=xv.x-m[0]; co.y=xv.y-m[1]; co.z=xv.z-m[2]; co.w=xv.w-m[3];
  *(float4*)(outMask + (size_t)blockIdx.z*HW + p) = mo;
  *(float4*)(outClean + (size_t)blockIdx.z*HW + p) = co;
}

__global__ void k_diff(const float* __restrict__ acc, float* __restrict__ out){
  out[0] = acc[0]*(1.f/3145728.f) + acc[1]*(1.f/786432.f);
}

// =======================================================================
extern "C" void kernel_launch(void* const* d_in, const int* in_sizes, int n_in,
                              void* d_out, int out_size, void* d_ws, size_t ws_size,
                              hipStream_t stream) {
  const float* x        = (const float*)d_in[0];
  const float* embed2   = (const float*)d_in[1];
  const float* embed3   = (const float*)d_in[2];
  const float* w_img_in = (const float*)d_in[3];
  const float* w_img_out= (const float*)d_in[4];
  const float* w_out_dd = (const float*)d_in[5];
  const float* w_out_dm = (const float*)d_in[6];
  const float* w_out_dt = (const float*)d_in[7];
  const float* w_out_ed = (const float*)d_in[8];
  const float* w_out_em = (const float*)d_in[9];
  const float* w_out_et = (const float*)d_in[10];
  const float* w_pw_dd  = (const float*)d_in[11];
  const float* w_pw_dm  = (const float*)d_in[12];
  const float* w_pw_dt  = (const float*)d_in[13];
  const float* w_pw_ed  = (const float*)d_in[14];
  const float* w_pw_em  = (const float*)d_in[15];
  const float* w_pw_et  = (const float*)d_in[16];
  const float* w_res_dd = (const float*)d_in[17];
  const float* w_res_dm = (const float*)d_in[18];
  const float* w_res_dt = (const float*)d_in[19];
  const float* w_res_ed = (const float*)d_in[20];
  const float* w_res_em = (const float*)d_in[21];
  const float* w_res_et = (const float*)d_in[22];
  const float* w_sa_dd  = (const float*)d_in[23];
  const float* w_sa_dm  = (const float*)d_in[24];
  const float* w_sa_dt  = (const float*)d_in[25];
  const float* w_sa_ed  = (const float*)d_in[26];
  const float* w_sa_em  = (const float*)d_in[27];
  const float* w_sa_et  = (const float*)d_in[28];
  const float* w_squ1   = (const float*)d_in[29];
  const float* w_squ2   = (const float*)d_in[30];
  (void)in_sizes; (void)n_in; (void)out_size;

  const int HW512 = 512*512, HW256 = 256*256, HW128 = 128*128, HW64 = 64*64;
  const int S512 = 24*HW512, S256 = 24*HW256, S128 = 24*HW128, S64 = 24*HW64;

  float* ws = (float*)d_ws;
  float* OUT = (float*)d_out;
  size_t F = ws_size / sizeof(float);

  // ---- fp32-reordered weights (conv3 / down / convT / pw / squeeze) ----
  float* WT      = ws;
  float* wt_ed3  = WT + 85248;
  float* wt_dd3  = WT + 90432;
  float* wt_d_et = WT + 95616;
  float* wt_d_em = WT + 104832;
  float* wt_d_ed = WT + 114048;
  float* wt_c_dd = WT + 123264;
  float* wt_c_dm = WT + 132480;
  float* wt_c_dt = WT + 141696;
  float* wt_pw_et= WT + 150912;
  float* wt_pw_em= WT + 151488;
  float* wt_pw_ed= WT + 152064;
  float* wt_pw_dd= WT + 152640;
  float* wt_pw_dm= WT + 153216;
  float* wt_pw_dt= WT + 153792;
  float* wt_squ1 = WT + 154368;
  float* wt_squ2 = WT + 155520;

  // ---- MFMA bf16 B-frag weights ----
  ushort_t* WB = (ushort_t*)(ws + 160000);
  ushort_t* wb_et7 = WB;
  ushort_t* wb_dt7 = WB + 50176;
  ushort_t* wb_em5 = WB + 100352;
  ushort_t* wb_dm5 = WB + 125952;   // total 151552 ushorts = 75776 floats

  const size_t ABASE = 236032;

  // ---- choose mode ----
  auto needBatched = [&](size_t CB)->size_t{
    size_t u = (CB*(size_t)S512 > (size_t)8*S256) ? CB*(size_t)S512 : (size_t)8*S256;
    return ABASE + 2097152 + 12582912 + 3145728 + 786432 + CB*524288 + 2*u + 2;
  };
  int CB = 0;
  if (F >= needBatched(8)) CB = 8;
  else if (F >= needBatched(4)) CB = 4;
  else if (F >= needBatched(2)) CB = 2;
  const size_t NEED_B = 16161282;
  if (CB == 0 && F < NEED_B) return;

  float *XL, *E1, *E2, *Q2, *E3, *Q3, *MM, *DIFF, *U1, *U2;
  if (CB > 0){
    size_t off = ABASE;
    size_t u = (CB*(size_t)S512 > (size_t)8*S256) ? CB*(size_t)S512 : (size_t)8*S256;
    XL = ws + off; off += 2097152;
    E1 = ws + off; off += 12582912;
    Q2 = ws + off; off += 3145728;
    Q3 = ws + off; off += 786432;
    MM = ws + off; off += CB*524288;
    U1 = ws + off; off += u;
    U2 = ws + off; off += u;
    DIFF = ws + off;
    E2 = OUT;                 // dead before k_final writes
    E3 = OUT + 3145728;
  } else {
    size_t off = ABASE;
    XL = ws + off; off += 262144;
    U1 = ws + off; off += 6291456;
    U2 = ws + off; off += 6291456;
    E1 = ws + off; off += 1572864;
    E2 = ws + off; off += 393216;
    Q2 = ws + off; off += 393216;
    E3 = ws + off; off += 98304;
    Q3 = ws + off; off += 98304;
    MM = ws + off; off += 524288;
    DIFF = ws + off;
  }

  // ---- weight reorders ----
  k_rmfma<<<dim3(196), 256, 0, stream>>>(w_res_et, wb_et7, 7);
  k_rmfma<<<dim3(196), 256, 0, stream>>>(w_res_dt, wb_dt7, 7);
  k_rmfma<<<dim3(100), 256, 0, stream>>>(w_res_em, wb_em5, 5);
  k_rmfma<<<dim3(100), 256, 0, stream>>>(w_res_dm, wb_dm5, 5);
  k_r_res<<<dim3((576*9+255)/256), 256, 0, stream>>>(w_res_ed, wt_ed3, 3);
  k_r_res<<<dim3((576*9+255)/256), 256, 0, stream>>>(w_res_dd, wt_dd3, 3);
  k_r4<<<dim3(36), 256, 0, stream>>>(w_out_et, wt_d_et, 0);
  k_r4<<<dim3(36), 256, 0, stream>>>(w_out_em, wt_d_em, 0);
  k_r4<<<dim3(36), 256, 0, stream>>>(w_out_ed, wt_d_ed, 0);
  k_r4<<<dim3(36), 256, 0, stream>>>(w_out_dd, wt_c_dd, 1);
  k_r4<<<dim3(36), 256, 0, stream>>>(w_out_dm, wt_c_dm, 1);
  k_r4<<<dim3(36), 256, 0, stream>>>(w_out_dt, wt_c_dt, 1);
  k_r_pw<<<dim3(3), 256, 0, stream>>>(w_pw_et, wt_pw_et, 24);
  k_r_pw<<<dim3(3), 256, 0, stream>>>(w_pw_em, wt_pw_em, 24);
  k_r_pw<<<dim3(3), 256, 0, stream>>>(w_pw_ed, wt_pw_ed, 24);
  k_r_pw<<<dim3(3), 256, 0, stream>>>(w_pw_dd, wt_pw_dd, 24);
  k_r_pw<<<dim3(3), 256, 0, stream>>>(w_pw_dm, wt_pw_dm, 24);
  k_r_pw<<<dim3(3), 256, 0, stream>>>(w_pw_dt, wt_pw_dt, 24);
  k_r_pw<<<dim3(5), 256, 0, stream>>>(w_squ1, wt_squ1, 48);
  k_r_pw<<<dim3(5), 256, 0, stream>>>(w_squ2, wt_squ2, 48);

  hipMemsetAsync(DIFF, 0, 2*sizeof(float), stream);

  // ---- phase 1: input -> enc1 ----
  auto phase1 = [&](int c0, int nz, float* XLp, float* E1p){
    k_lap<<<dim3(HW512/256,1,nz), 256, 0, stream>>>(x + (size_t)c0*3*HW512, XLp, 512, 512);
    k_expand<<<dim3(HW512/1024,1,nz), 256, 0, stream>>>(XLp, w_img_in, U1, HW512, S512);
    k_conv_mfma<7><<<dim3(16,32,nz), 512, 0, stream>>>(U1, wb_et7, U2, 512, 512, S512, S512);
    k_pw<<<dim3(HW512/1024,1,nz), 256, 0, stream>>>(U2, wt_pw_et, U2, MM, HW512, S512, 2*HW512);
    k_attn_res<<<dim3(HW512/1024,1,nz), 256, 0, stream>>>(U2, MM, U1, w_sa_et, U1, 512, 512, S512, 2*HW512);
    k_down<<<dim3(8,16,nz), 256, 0, stream>>>(U1, wt_d_et, E1p, 256, 256, S512, S256);
  };

  // ---- deep: enc1 -> squ1 output (written to D1p) ----
  auto deep = [&](int nb, float* E1p, float* SAp, float* SBp, float* E2p, float* Q2p,
                  float* E3p, float* Q3p, float* MMp, float* D1p){
    int mm256 = 2*HW256, mm128 = 2*HW128;
    k_conv_mfma<5><<<dim3(8,16,nb), 512, 0, stream>>>(E1p, wb_em5, SAp, 256, 256, S256, S256);
    k_pw<<<dim3(HW256/1024,1,nb), 256, 0, stream>>>(SAp, wt_pw_em, SAp, MMp, HW256, S256, mm256);
    k_attn_res<<<dim3(HW256/1024,1,nb), 256, 0, stream>>>(SAp, MMp, E1p, w_sa_em, SBp, 256, 256, S256, mm256);
    k_down<<<dim3(4,8,nb), 256, 0, stream>>>(SBp, wt_d_em, E2p, 128, 128, S256, S128);
    k_conv<3,8><<<dim3(4,16,nb), 256, 0, stream>>>(E2p, wt_ed3, SAp, 128, 128, S128, S128);
    k_pw<<<dim3(HW128/1024,1,nb), 256, 0, stream>>>(SAp, wt_pw_ed, SAp, MMp, HW128, S128, mm128);
    k_attn_res<<<dim3(HW128/1024,1,nb), 256, 0, stream>>>(SAp, MMp, E2p, w_sa_ed, SBp, 128, 128, S128, mm128);
    k_down<<<dim3(2,4,nb), 256, 0, stream>>>(SBp, wt_d_ed, E3p, 64, 64, S128, S64);
    k_quant<<<dim3(HW128/256,1,nb), 256, 0, stream>>>(E2p, embed2, Q2p, DIFF+0, HW128, S128);
    k_quant<<<dim3(HW64/256,1,nb), 256, 0, stream>>>(E3p, embed3, Q3p, DIFF+1, HW64, S64);
    k_convT<<<dim3(4,8,nb), 256, 0, stream>>>(Q3p, wt_c_dd, SAp, 128, 128, S64, S128);
    k_conv<3,8><<<dim3(4,16,nb), 256, 0, stream>>>(SAp, wt_dd3, SBp, 128, 128, S128, S128);
    k_pw<<<dim3(HW128/1024,1,nb), 256, 0, stream>>>(SBp, wt_pw_dd, SBp, MMp, HW128, S128, mm128);
    k_attn_res<<<dim3(HW128/1024,1,nb), 256, 0, stream>>>(SBp, MMp, SAp, w_sa_dd, SAp, 128, 128, S128, mm128);
    k_squeeze<<<dim3(HW128/1024,1,nb), 256, 0, stream>>>(SAp, Q2p, wt_squ2, SBp, HW128, S128);
    k_convT<<<dim3(8,16,nb), 256, 0, stream>>>(SBp, wt_c_dm, SAp, 256, 256, S128, S256);
    k_conv_mfma<5><<<dim3(8,16,nb), 512, 0, stream>>>(SAp, wb_dm5, SBp, 256, 256, S256, S256);
    k_pw<<<dim3(HW256/1024,1,nb), 256, 0, stream>>>(SBp, wt_pw_dm, SBp, MMp, HW256, S256, mm256);
    k_attn_res<<<dim3(HW256/1024,1,nb), 256, 0, stream>>>(SBp, MMp, SAp, w_sa_dm, SAp, 256, 256, S256, mm256);
    k_squeeze<<<dim3(HW256/1024,1,nb), 256, 0, stream>>>(SAp, E1p, wt_squ1, D1p, HW256, S256);
  };

  // ---- phase 3: D1 -> outputs ----
  auto phase3 = [&](int c0, int nz, const float* D1p, const float* XLp){
    k_convT<<<dim3(16,32,nz), 256, 0, stream>>>(D1p, wt_c_dt, U1, 512, 512, S256, S512);
    k_conv_mfma<7><<<dim3(16,32,nz), 512, 0, stream>>>(U1, wb_dt7, U2, 512, 512, S512, S512);
    k_pw<<<dim3(HW512/1024,1,nz), 256, 0, stream>>>(U2, wt_pw_dt, U2, MM, HW512, S512, 2*HW512);
    k_attn_res<<<dim3(HW512/1024,1,nz), 256, 0, stream>>>(U2, MM, U1, w_sa_dt, U1, 512, 512, S512, 2*HW512);
    k_final<<<dim3(HW512/1024,1,nz), 256, 0, stream>>>(U1, w_img_out, XLp,
                                                       OUT + (size_t)c0*HW512,
                                                       OUT + 2097152 + (size_t)c0*HW512,
                                                       HW512, S512);
  };

  if (CB > 0){
    for (int c0=0;c0<8;c0+=CB)
      phase1(c0, CB, XL + (size_t)c0*HW512, E1 + (size_t)c0*S256);
    deep(8, E1, U1, U2, E2, Q2, E3, Q3, MM, E1);
    for (int c0=0;c0<8;c0+=CB)
      phase3(c0, CB, E1 + (size_t)c0*S256, XL + (size_t)c0*HW512);
  } else {
    for (int b=0;b<8;b++){
      phase1(b, 1, XL, E1);
      deep(1, E1, U1, U2, E2, Q2, E3, Q3, MM, U2);
      phase3(b, 1, U2, XL);
    }
  }

  k_diff<<<1, 1, 0, stream>>>(DIFF, OUT + 4194304);
}

// Round 6
// 2906.732 us; speedup vs baseline: 6.7739x; 1.0668x over previous
//
#include <hip/hip_runtime.h>
#include <math.h>

#define CH 24

typedef __attribute__((ext_vector_type(8))) short short8v;
typedef __attribute__((ext_vector_type(4))) float f32x4;
typedef unsigned short ushort_t;
typedef unsigned int uint_t;

__device__ inline ushort_t bf16r(float f){
  uint_t u = __float_as_uint(f);
  u += 0x7FFF + ((u>>16)&1);
  return (ushort_t)(u>>16);
}

// ================= weight reorder kernels =================
__global__ void k_r_res(const float* __restrict__ w, float* __restrict__ wT, int K){
  int i = blockIdx.x*256 + threadIdx.x;
  int n = 576*K*K; if (i >= n) return;
  int co = i % 24, ci = (i/24) % 24, kk = i/576;
  int ky = kk / K, kx = kk % K;
  wT[i] = w[((co*24+ci)*K+ky)*K+kx];
}
__global__ void k_r4(const float* __restrict__ w, float* __restrict__ wT, int tr){
  int i = blockIdx.x*256 + threadIdx.x;
  if (i >= 9216) return;
  int co = i % 24, ci = (i/24) % 24, kk = i/576;
  int ky = kk / 4, kx = kk % 4;
  wT[i] = tr ? w[((ci*24+co)*4+ky)*4+kx] : w[((co*24+ci)*4+ky)*4+kx];
}
__global__ void k_r_pw(const float* __restrict__ w, float* __restrict__ wT, int CIN){
  int i = blockIdx.x*256 + threadIdx.x;
  if (i >= CIN*24) return;
  int co = i % 24, ci = i/24;
  wT[i] = w[co*CIN+ci];
}
// MFMA-ready bf16 B-frags: wb[tap*1024 + t*512 + l*8 + j] = W[ci=(l>>4)*8+j][co=t*16+(l&15)]
__global__ void k_rmfma(const float* __restrict__ w, ushort_t* __restrict__ wb, int K){
  int i = blockIdx.x*256 + threadIdx.x;
  int n = K*K*1024; if (i >= n) return;
  int j = i & 7, l = (i>>3) & 63, t = (i>>9) & 1, tap = i >> 10;
  int ci = (l>>4)*8 + j, co = t*16 + (l&15);
  int ky = tap / K, kx = tap % K;
  float v = (ci<24 && co<24) ? w[((co*24+ci)*K+ky)*K+kx] : 0.f;
  wb[i] = bf16r(v);
}

// ================= compute kernels =================

__global__ void k_lap(const float* __restrict__ x, float* __restrict__ xl, int H, int W){
  int idx = blockIdx.x*256 + threadIdx.x;
  int HW = H*W;
  if (idx >= HW) return;
  const float* xb = x + (size_t)blockIdx.z*3*HW;
  float* xo = xl + (size_t)blockIdx.z*HW;
  int px = idx % W, py = idx / W;
#define MEANV(yy,xx) (((yy)>=0&&(yy)<H&&(xx)>=0&&(xx)<W) ? (xb[(yy)*W+(xx)]+xb[HW+(yy)*W+(xx)]+xb[2*HW+(yy)*W+(xx)])*(1.f/3.f) : 0.f)
  float v = 4.f*MEANV(py,px) - MEANV(py-1,px) - MEANV(py+1,px) - MEANV(py,px-1) - MEANV(py,px+1);
#undef MEANV
  xo[idx] = v;
}

// ---------- MFMA KxK conv 24->24 (pad K/2) FUSED with 1x1 pw conv + mean/max maps ----------
// EXPAND: input is 1-plane XL, channel c = xl * wexp[c].
template<int K, bool EXPAND>
__launch_bounds__(512)
__global__ void k_conv_mfma(const float* __restrict__ in, const ushort_t* __restrict__ wb,
                            const ushort_t* __restrict__ wbpw, const float* __restrict__ wexp,
                            float* __restrict__ out, float* __restrict__ mm,
                            int H, int W, int istrIn, int istrOut, int istrMM){
  constexpr int SW_T = 32 + K - 1;
  constexpr int SH = 16 + K - 1;
  constexpr int NPX = SH*SW_T;
  __shared__ ushort_t lds[NPX*32];
  __shared__ uint_t sc[8][16*20];
  int tid = threadIdx.x;
  const float* inb = in + (size_t)blockIdx.z*istrIn;
  int x0g = blockIdx.x*32 - K/2, y0g = blockIdx.y*16 - K/2;
  int HW = H*W;
  // stage -> [px][32ch] bf16, chunk-swizzled with ((pp>>1)&3)
  for (int i = tid; i < NPX*16; i += 512){
    int cpair = i / NPX;
    int pp = i - cpair*NPX;
    int c0 = cpair*2;
    int row = pp / SW_T, col = pp - row*SW_T;
    int gy = y0g + row, gx = x0g + col;
    float v0 = 0.f, v1 = 0.f;
    if (gy >= 0 && gy < H && gx >= 0 && gx < W){
      if (EXPAND){
        float val = inb[(size_t)gy*W + gx];
        v0 = val * wexp[c0];
        v1 = val * wexp[c0+1];
      } else {
        size_t base = (size_t)gy*W + gx;
        v0 = inb[(size_t)c0*HW + base];
        v1 = inb[(size_t)(c0+1)*HW + base];
      }
    }
    uint_t packed = (uint_t)bf16r(v0) | ((uint_t)bf16r(v1) << 16);
    int slot = pp*32 + (c0 ^ (((pp>>1)&3)<<3));
    *(uint_t*)(lds + slot) = packed;
  }
  __syncthreads();
  int l = tid & 63, wid = tid >> 6;
  int kg = l >> 4, li = l & 15;
  f32x4 zero = {0.f,0.f,0.f,0.f};
  f32x4 acc[4][2];
  #pragma unroll
  for (int i=0;i<4;i++){ acc[i][0]=zero; acc[i][1]=zero; }

  for (int ky=0; ky<K; ky++){
    for (int kx=0; kx<K; kx++){
      int tap = ky*K + kx;
      const ushort_t* wp = wb + (size_t)tap*1024;
      short8v b0 = *(const short8v*)(wp + l*8);
      short8v b1 = *(const short8v*)(wp + 512 + l*8);
      #pragma unroll
      for (int i=0;i<4;i++){
        int pp = (wid + (i&1)*8 + ky)*SW_T + (i>>1)*16 + kx + li;
        short8v a = *(const short8v*)(lds + pp*32 + ((kg*8) ^ (((pp>>1)&3)<<3)));
        acc[i][0] = __builtin_amdgcn_mfma_f32_16x16x32_bf16(a, b0, acc[i][0], 0, 0, 0);
        acc[i][1] = __builtin_amdgcn_mfma_f32_16x16x32_bf16(a, b1, acc[i][1], 0, 0, 0);
      }
    }
  }
  // ---- stage 2: pw 1x1 via second MFMA, + mean/max ----
  short8v bpw0 = *(const short8v*)(wbpw + l*8);
  short8v bpw1 = *(const short8v*)(wbpw + 512 + l*8);
  uint_t* s = sc[wid];
  float* outb = out + (size_t)blockIdx.z*istrOut;
  float* mmb = mm + (size_t)blockIdx.z*istrMM;
  #pragma unroll 1
  for (int i=0;i<4;i++){
    __asm__ volatile("s_waitcnt lgkmcnt(0)" ::: "memory");
    __builtin_amdgcn_sched_barrier(0);
    #pragma unroll
    for (int reg=0; reg<4; reg++){
      float v0 = acc[i][0][reg], v1 = acc[i][1][reg];
      float v0n = __shfl_xor(v0, 1, 64);
      float v1n = __shfl_xor(v1, 1, 64);
      int pxr = kg*4 + reg;
      uint_t packed; int uidx;
      if ((li & 1) == 0){
        packed = (uint_t)bf16r(v0) | ((uint_t)bf16r(v0n) << 16);
        uidx = li >> 1;
      } else {
        packed = (uint_t)bf16r(v1n) | ((uint_t)bf16r(v1) << 16);
        uidx = 8 + (li >> 1);
      }
      s[pxr*20 + uidx] = packed;
    }
    __asm__ volatile("s_waitcnt lgkmcnt(0)" ::: "memory");
    __builtin_amdgcn_sched_barrier(0);
    short8v a2 = *(const short8v*)((const ushort_t*)s + li*40 + kg*8);
    f32x4 d0 = __builtin_amdgcn_mfma_f32_16x16x32_bf16(a2, bpw0, zero, 0, 0, 0);
    f32x4 d1 = __builtin_amdgcn_mfma_f32_16x16x32_bf16(a2, bpw1, zero, 0, 0, 0);
    int gy = blockIdx.y*16 + wid + (i&1)*8;
    int gx = blockIdx.x*32 + (i>>1)*16 + kg*4;
    float* o0 = outb + (size_t)li*HW + (size_t)gy*W + gx;
    *(f32x4*)o0 = d0;
    if (li < 8){
      float* o1 = outb + (size_t)(16+li)*HW + (size_t)gy*W + gx;
      *(f32x4*)o1 = d1;
    }
    f32x4 sm, mx;
    #pragma unroll
    for (int reg=0; reg<4; reg++){
      sm[reg] = d0[reg] + d1[reg];                    // d1 is 0 for li>=8 (zero pw weights)
      mx[reg] = fmaxf(d0[reg], (li<8) ? d1[reg] : -3.4e38f);
    }
    #pragma unroll
    for (int m=1; m<16; m<<=1){
      #pragma unroll
      for (int reg=0; reg<4; reg++){
        sm[reg] += __shfl_xor(sm[reg], m, 64);
        mx[reg] = fmaxf(mx[reg], __shfl_xor(mx[reg], m, 64));
      }
    }
    if (li == 0){
      f32x4 me; me[0]=sm[0]*(1.f/24.f); me[1]=sm[1]*(1.f/24.f); me[2]=sm[2]*(1.f/24.f); me[3]=sm[3]*(1.f/24.f);
      *(f32x4*)(mmb + (size_t)gy*W + gx) = me;
      *(f32x4*)(mmb + (size_t)HW + (size_t)gy*W + gx) = mx;
    }
  }
}

// KxK conv fp32 (K=3 @128). wT=[ky][kx][ci][co]. Tile 32 x TH.
template<int K, int TH>
__launch_bounds__(256)
__global__ void k_conv(const float* __restrict__ in, const float* __restrict__ wT,
                       float* __restrict__ out, int H, int W, int istrIn, int istrOut){
  constexpr int TW = 32;
  constexpr int PX = (TW*TH)/256;
  constexpr int XT = TW/PX;
  constexpr int SW = TW + K - 1;
  constexpr int SWP = SW | 1;
  constexpr int SH = TH + K - 1;
  constexpr int CC = 8;
  __shared__ float tile[CC*SH*SWP];
  int tx = threadIdx.x % XT, ty = threadIdx.x / XT;
  int x0 = blockIdx.x*TW - K/2, y0 = blockIdx.y*TH - K/2;
  const float* inb = in + (size_t)blockIdx.z*istrIn;
  float acc[CH][PX];
  #pragma unroll
  for (int co=0;co<CH;co++)
    #pragma unroll
    for (int px=0;px<PX;px++) acc[co][px] = 0.f;

  #pragma unroll 1
  for (int c0=0;c0<CH;c0+=CC){
    __syncthreads();
    for (int i=threadIdx.x; i<CC*SH*SW; i+=256){
      int col = i % SW; int rr = i / SW; int row = rr % SH; int c = rr / SH;
      int gy = y0+row, gx = x0+col;
      tile[(c*SH+row)*SWP+col] = (gy>=0 && gy<H && gx>=0 && gx<W)
          ? inb[(size_t)(c0+c)*H*W + (size_t)gy*W + gx] : 0.f;
    }
    __syncthreads();
    #pragma unroll 1
    for (int ci=0;ci<CC;ci++){
      #pragma unroll 1
      for (int ky=0;ky<K;ky++){
        const float* trow = &tile[(ci*SH + ty+ky)*SWP + tx*PX];
        #pragma unroll
        for (int kx=0;kx<K;kx++){
          float v[PX];
          #pragma unroll
          for (int px=0;px<PX;px++) v[px] = trow[kx+px];
          const float* wp = wT + ((ky*K+kx)*24 + c0+ci)*24;
          #pragma unroll
          for (int co=0;co<CH;co++){
            float wv = wp[co];
            #pragma unroll
            for (int px=0;px<PX;px++) acc[co][px] = fmaf(v[px], wv, acc[co][px]);
          }
        }
      }
    }
  }
  int oy = blockIdx.y*TH+ty, ox = blockIdx.x*TW+tx*PX;
  float* ob = out + (size_t)blockIdx.z*istrOut + (size_t)oy*W + ox;
  #pragma unroll
  for (int co=0;co<CH;co++){
    if (PX == 2){
      float2 o; o.x=acc[co][0]; o.y=acc[co][1];
      *(float2*)(ob + (size_t)co*H*W) = o;
    } else {
      ob[(size_t)co*H*W] = acc[co][0];
    }
  }
}

__global__ void k_pw(const float* in, const float* __restrict__ wT,
                     float* out, float* __restrict__ mm, int HW, int istr, int istrMM){
  int p = (blockIdx.x*256 + threadIdx.x)*4;
  if (p >= HW) return;
  const float* ib = in + (size_t)blockIdx.z*istr;
  float acc[CH][4];
  #pragma unroll
  for (int co=0;co<CH;co++){ acc[co][0]=0;acc[co][1]=0;acc[co][2]=0;acc[co][3]=0; }
  #pragma unroll 1
  for (int ci=0;ci<CH;ci++){
    float4 v = *(const float4*)(ib + (size_t)ci*HW + p);
    const float* wp = wT + ci*24;
    #pragma unroll
    for (int co=0;co<CH;co++){
      float wv = wp[co];
      acc[co][0] = fmaf(v.x, wv, acc[co][0]);
      acc[co][1] = fmaf(v.y, wv, acc[co][1]);
      acc[co][2] = fmaf(v.z, wv, acc[co][2]);
      acc[co][3] = fmaf(v.w, wv, acc[co][3]);
    }
  }
  float mean[4]={0,0,0,0}, mx[4]={-3.4e38f,-3.4e38f,-3.4e38f,-3.4e38f};
  #pragma unroll
  for (int co=0;co<CH;co++)
    #pragma unroll
    for (int j=0;j<4;j++){ mean[j]+=acc[co][j]; mx[j]=fmaxf(mx[j],acc[co][j]); }
  float* ob = out + (size_t)blockIdx.z*istr;
  #pragma unroll
  for (int co=0;co<CH;co++){
    float4 o; o.x=acc[co][0]; o.y=acc[co][1]; o.z=acc[co][2]; o.w=acc[co][3];
    *(float4*)(ob + (size_t)co*HW + p) = o;
  }
  float* mb = mm + (size_t)blockIdx.z*istrMM;
  float4 me; me.x=mean[0]*(1.f/24.f); me.y=mean[1]*(1.f/24.f); me.z=mean[2]*(1.f/24.f); me.w=mean[3]*(1.f/24.f);
  float4 mxo; mxo.x=mx[0]; mxo.y=mx[1]; mxo.z=mx[2]; mxo.w=mx[3];
  *(float4*)(mb + p) = me;
  *(float4*)(mb + HW + p) = mxo;
}

// spatial attn + sigmoid + relu + residual add; out may alias X
__global__ void k_attn_res(const float* __restrict__ R, const float* __restrict__ M,
                           const float* X, const float* __restrict__ wsa,
                           float* out, int H, int W, int istr, int istrMM){
  int p = (blockIdx.x*256 + threadIdx.x)*4;
  int HW = H*W;
  if (p >= HW) return;
  int py = p / W, px0 = p % W;
  const float* Mb = M + (size_t)blockIdx.z*istrMM;
  float s[4]={0,0,0,0};
  #pragma unroll
  for (int cc=0;cc<2;cc++){
    const float* Mc = Mb + (size_t)cc*HW;
    #pragma unroll 1
    for (int ky=0;ky<7;ky++){
      int gy = py+ky-3;
      if (gy<0||gy>=H) continue;
      const float* mr = Mc + (size_t)gy*W;
      float mv[10];
      #pragma unroll
      for (int j=0;j<10;j++){
        int gx = px0-3+j;
        mv[j] = (gx>=0 && gx<W) ? mr[gx] : 0.f;
      }
      const float* wr = wsa + (cc*7+ky)*7;
      #pragma unroll
      for (int kx=0;kx<7;kx++){
        float wv = wr[kx];
        #pragma unroll
        for (int px=0;px<4;px++) s[px] = fmaf(mv[kx+px], wv, s[px]);
      }
    }
  }
  float g[4];
  #pragma unroll
  for (int px=0;px<4;px++) g[px] = 1.f/(1.f+expf(-s[px]));
  const float* Rb = R + (size_t)blockIdx.z*istr;
  const float* Xb = X + (size_t)blockIdx.z*istr;
  float* Ob = out + (size_t)blockIdx.z*istr;
  #pragma unroll
  for (int c=0;c<CH;c++){
    float4 r = *(const float4*)(Rb + (size_t)c*HW + p);
    float4 xv = *(const float4*)(Xb + (size_t)c*HW + p);
    float4 o;
    o.x = xv.x + fmaxf(r.x*g[0], 0.f);
    o.y = xv.y + fmaxf(r.y*g[1], 0.f);
    o.z = xv.z + fmaxf(r.z*g[2], 0.f);
    o.w = xv.w + fmaxf(r.w*g[3], 0.f);
    *(float4*)(Ob + (size_t)c*HW + p) = o;
  }
}

// variant: residual X computed on the fly as xl*wexp[c]
__global__ void k_attn_res_x(const float* __restrict__ R, const float* __restrict__ M,
                             const float* __restrict__ XL, const float* __restrict__ wsa,
                             const float* __restrict__ wexp,
                             float* __restrict__ out, int H, int W, int istr, int istrMM){
  int p = (blockIdx.x*256 + threadIdx.x)*4;
  int HW = H*W;
  if (p >= HW) return;
  int py = p / W, px0 = p % W;
  const float* Mb = M + (size_t)blockIdx.z*istrMM;
  float s[4]={0,0,0,0};
  #pragma unroll
  for (int cc=0;cc<2;cc++){
    const float* Mc = Mb + (size_t)cc*HW;
    #pragma unroll 1
    for (int ky=0;ky<7;ky++){
      int gy = py+ky-3;
      if (gy<0||gy>=H) continue;
      const float* mr = Mc + (size_t)gy*W;
      float mv[10];
      #pragma unroll
      for (int j=0;j<10;j++){
        int gx = px0-3+j;
        mv[j] = (gx>=0 && gx<W) ? mr[gx] : 0.f;
      }
      const float* wr = wsa + (cc*7+ky)*7;
      #pragma unroll
      for (int kx=0;kx<7;kx++){
        float wv = wr[kx];
        #pragma unroll
        for (int px=0;px<4;px++) s[px] = fmaf(mv[kx+px], wv, s[px]);
      }
    }
  }
  float g[4];
  #pragma unroll
  for (int px=0;px<4;px++) g[px] = 1.f/(1.f+expf(-s[px]));
  float4 xl4 = *(const float4*)(XL + (size_t)blockIdx.z*HW + p);
  const float* Rb = R + (size_t)blockIdx.z*istr;
  float* Ob = out + (size_t)blockIdx.z*istr;
  #pragma unroll
  for (int c=0;c<CH;c++){
    float wc = wexp[c];
    float4 r = *(const float4*)(Rb + (size_t)c*HW + p);
    float4 o;
    o.x = xl4.x*wc + fmaxf(r.x*g[0], 0.f);
    o.y = xl4.y*wc + fmaxf(r.y*g[1], 0.f);
    o.z = xl4.z*wc + fmaxf(r.z*g[2], 0.f);
    o.w = xl4.w*wc + fmaxf(r.w*g[3], 0.f);
    *(float4*)(Ob + (size_t)c*HW + p) = o;
  }
}

__global__ void k_down(const float* __restrict__ in, const float* __restrict__ wT,
                       float* __restrict__ out, int Ho, int Wo, int istrIn, int istrOut){
  int tx = threadIdx.x % 16, ty = threadIdx.x / 16;
  int ox0 = blockIdx.x*32 + tx*2, oy = blockIdx.y*16 + ty;
  int Hi = Ho*2, Wi = Wo*2;
  const float* inb = in + (size_t)blockIdx.z*istrIn;
  float acc[CH][2];
  #pragma unroll
  for (int c=0;c<CH;c++){ acc[c][0]=0; acc[c][1]=0; }
  #pragma unroll 1
  for (int ci=0;ci<CH;ci++){
    const float* ip = inb + (size_t)ci*Hi*Wi;
    #pragma unroll
    for (int ky=0;ky<4;ky++){
      int iy = 2*oy + ky - 1;
      if (iy < 0 || iy >= Hi) continue;
      #pragma unroll
      for (int kx=0;kx<4;kx++){
        int ix0 = 2*ox0 + kx - 1;
        float v0 = (ix0>=0 && ix0<Wi) ? ip[(size_t)iy*Wi + ix0] : 0.f;
        int ix1 = ix0 + 2;
        float v1 = (ix1 < Wi) ? ip[(size_t)iy*Wi + ix1] : 0.f;
        const float* wp = wT + ((ky*4+kx)*24+ci)*24;
        #pragma unroll
        for (int co=0;co<CH;co++){
          float wv = wp[co];
          acc[co][0] = fmaf(v0, wv, acc[co][0]);
          acc[co][1] = fmaf(v1, wv, acc[co][1]);
        }
      }
    }
  }
  float* ob = out + (size_t)blockIdx.z*istrOut + (size_t)oy*Wo + ox0;
  #pragma unroll
  for (int co=0;co<CH;co++){
    float2 o; o.x=acc[co][0]; o.y=acc[co][1];
    *(float2*)(ob + (size_t)co*Ho*Wo) = o;
  }
}

// ConvTranspose2d(k=4,s=2,p=1), LDS-staged. 32x16 output tile.
__launch_bounds__(256)
__global__ void k_convT2(const float* __restrict__ in, const float* __restrict__ wT,
                         float* __restrict__ out, int Ho, int Wo, int istrIn, int istrOut){
  const int Hi = Ho>>1, Wi = Wo>>1;
  __shared__ float t[24*190];          // [ci][dy(10)][dx(19 padded)]
  int tx = threadIdx.x & 15, ty = threadIdx.x >> 4;
  int ix0 = blockIdx.x*16 - 1, iy0 = blockIdx.y*8 - 1;
  const float* inb = in + (size_t)blockIdx.z*istrIn;
  for (int i = threadIdx.x; i < 24*180; i += 256){
    int ci = i/180; int r = i - ci*180; int dy = r/18, dx = r - dy*18;
    int gy = iy0+dy, gx = ix0+dx;
    t[ci*190 + dy*19 + dx] = (gy>=0 && gy<Hi && gx>=0 && gx<Wi)
        ? inb[(size_t)ci*Hi*Wi + (size_t)gy*Wi + gx] : 0.f;
  }
  __syncthreads();
  float acc[CH][2];
  #pragma unroll
  for (int c=0;c<CH;c++){ acc[c][0]=0.f; acc[c][1]=0.f; }
  int ky0 = (ty+1)&1;
  #pragma unroll 1
  for (int ci=0;ci<24;ci++){
    const float* tc = t + ci*190;
    #pragma unroll
    for (int t2=0;t2<2;t2++){
      int ky = ky0 + 2*t2;
      int dy = ((ty+1-ky)>>1) + 1;
      const float* trow = tc + dy*19;
      float ta = trow[tx], tb = trow[tx+1], tcv = trow[tx+2];
      const float* w0 = wT + ((ky*4+0)*24+ci)*24;
      const float* w1 = wT + ((ky*4+1)*24+ci)*24;
      const float* w2 = wT + ((ky*4+2)*24+ci)*24;
      const float* w3 = wT + ((ky*4+3)*24+ci)*24;
      #pragma unroll
      for (int co=0;co<24;co++){
        acc[co][0] = fmaf(tb, w1[co], fmaf(ta, w3[co], acc[co][0]));
        acc[co][1] = fmaf(tcv, w0[co], fmaf(tb, w2[co], acc[co][1]));
      }
    }
  }
  int oy = blockIdx.y*16 + ty, ox = blockIdx.x*32 + tx*2;
  float* ob = out + (size_t)blockIdx.z*istrOut + (size_t)oy*Wo + ox;
  #pragma unroll
  for (int co=0;co<24;co++){
    float2 o; o.x=acc[co][0]; o.y=acc[co][1];
    *(float2*)(ob + (size_t)co*Ho*Wo) = o;
  }
}

__global__ void k_squeeze(const float* __restrict__ inA, const float* inB,
                          const float* __restrict__ wT, float* out, int HW, int istr){
  int p = (blockIdx.x*256 + threadIdx.x)*4;
  if (p >= HW) return;
  const float* Ab = inA + (size_t)blockIdx.z*istr;
  const float* Bb = inB + (size_t)blockIdx.z*istr;
  float acc[CH][4];
  #pragma unroll
  for (int co=0;co<CH;co++){ acc[co][0]=0;acc[co][1]=0;acc[co][2]=0;acc[co][3]=0; }
  #pragma unroll 1
  for (int ci=0;ci<48;ci++){
    const float* src = (ci<24) ? (Ab + (size_t)ci*HW) : (Bb + (size_t)(ci-24)*HW);
    float4 v = *(const float4*)(src + p);
    const float* wp = wT + ci*24;
    #pragma unroll
    for (int co=0;co<CH;co++){
      float wv = wp[co];
      acc[co][0] = fmaf(v.x, wv, acc[co][0]);
      acc[co][1] = fmaf(v.y, wv, acc[co][1]);
      acc[co][2] = fmaf(v.z, wv, acc[co][2]);
      acc[co][3] = fmaf(v.w, wv, acc[co][3]);
    }
  }
  float* ob = out + (size_t)blockIdx.z*istr;
  #pragma unroll
  for (int co=0;co<CH;co++){
    float4 o; o.x=acc[co][0]; o.y=acc[co][1]; o.z=acc[co][2]; o.w=acc[co][3];
    *(float4*)(ob + (size_t)co*HW + p) = o;
  }
}

__global__ void k_quant(const float* __restrict__ enc, const float* __restrict__ embed,
                        float* __restrict__ qt, float* __restrict__ diffAcc, int HW, int istr){
  __shared__ float em[256*28];
  __shared__ float red[4];
  {
    int j = threadIdx.x;
    float s = 0.f;
    #pragma unroll
    for (int c=0;c<CH;c++){
      float e = embed[c*256+j];
      em[j*28+c] = -2.0f*e;
      s = fmaf(e,e,s);
    }
    em[j*28+24] = s; em[j*28+25]=0.f; em[j*28+26]=0.f; em[j*28+27]=0.f;
  }
  __syncthreads();
  int p = blockIdx.x*256 + threadIdx.x;
  const float* eb = enc + (size_t)blockIdx.z*istr;
  float f[CH];
  #pragma unroll
  for (int c=0;c<CH;c++) f[c] = eb[(size_t)c*HW + p];
  float best = 3.4e38f; int bj = 0;
  #pragma unroll 1
  for (int j=0;j<256;j++){
    const float4* row = (const float4*)&em[j*28];
    float s = em[j*28+24];
    #pragma unroll
    for (int q4=0;q4<6;q4++){
      float4 r = row[q4];
      s = fmaf(f[q4*4+0], r.x, s);
      s = fmaf(f[q4*4+1], r.y, s);
      s = fmaf(f[q4*4+2], r.z, s);
      s = fmaf(f[q4*4+3], r.w, s);
    }
    if (s < best){ best = s; bj = j; }
  }
  float* qb = qt + (size_t)blockIdx.z*istr;
  float d = 0.f;
  #pragma unroll
  for (int c=0;c<CH;c++){
    float q = embed[c*256+bj];
    qb[(size_t)c*HW + p] = q;
    float e = q - f[c];
    d = fmaf(e,e,d);
  }
  #pragma unroll
  for (int off=32; off>0; off>>=1) d += __shfl_down(d, off, 64);
  int lane = threadIdx.x & 63, wv = threadIdx.x >> 6;
  if (lane==0) red[wv] = d;
  __syncthreads();
  if (threadIdx.x==0) atomicAdd(diffAcc, red[0]+red[1]+red[2]+red[3]);
}

__global__ void k_final(const float* __restrict__ dec1, const float* __restrict__ w,
                        const float* __restrict__ xl, float* __restrict__ outMask,
                        float* __restrict__ outClean, int HW, int dstr){
  int p = (blockIdx.x*256 + threadIdx.x)*4;
  if (p >= HW) return;
  const float* db = dec1 + (size_t)blockIdx.z*dstr;
  float m[4]={0,0,0,0};
  #pragma unroll
  for (int c=0;c<CH;c++){
    float4 d = *(const float4*)(db + (size_t)c*HW + p);
    float wc = w[c];
    m[0]=fmaf(d.x,wc,m[0]); m[1]=fmaf(d.y,wc,m[1]); m[2]=fmaf(d.z,wc,m[2]); m[3]=fmaf(d.w,wc,m[3]);
  }
  float4 xv = *(const float4*)(xl + (size_t)blockIdx.z*HW + p);
  float4 mo; mo.x=m[0]; mo.y=m[1]; mo.z=m[2]; mo.w=m[3];
  float4 co; co.x=xv.x-m[0]; co.y=xv.y-m[1]; co.z=xv.z-m[2]; co.w=xv.w-m[3];
  *(float4*)(outMask + (size_t)blockIdx.z*HW + p) = mo;
  *(float4*)(outClean + (size_t)blockIdx.z*HW + p) = co;
}

__global__ void k_diff(const float* __restrict__ acc, float* __restrict__ out){
  out[0] = acc[0]*(1.f/3145728.f) + acc[1]*(1.f/786432.f);
}

// =======================================================================
extern "C" void kernel_launch(void* const* d_in, const int* in_sizes, int n_in,
                              void* d_out, int out_size, void* d_ws, size_t ws_size,
                              hipStream_t stream) {
  const float* x        = (const float*)d_in[0];
  const float* embed2   = (const float*)d_in[1];
  const float* embed3   = (const float*)d_in[2];
  const float* w_img_in = (const float*)d_in[3];
  const float* w_img_out= (const float*)d_in[4];
  const float* w_out_dd = (const float*)d_in[5];
  const float* w_out_dm = (const float*)d_in[6];
  const float* w_out_dt = (const float*)d_in[7];
  const float* w_out_ed = (const float*)d_in[8];
  const float* w_out_em = (const float*)d_in[9];
  const float* w_out_et = (const float*)d_in[10];
  const float* w_pw_dd  = (const float*)d_in[11];
  const float* w_pw_dm  = (const float*)d_in[12];
  const float* w_pw_dt  = (const float*)d_in[13];
  const float* w_pw_ed  = (const float*)d_in[14];
  const float* w_pw_em  = (const float*)d_in[15];
  const float* w_pw_et  = (const float*)d_in[16];
  const float* w_res_dd = (const float*)d_in[17];
  const float* w_res_dm = (const float*)d_in[18];
  const float* w_res_dt = (const float*)d_in[19];
  const float* w_res_ed = (const float*)d_in[20];
  const float* w_res_em = (const float*)d_in[21];
  const float* w_res_et = (const float*)d_in[22];
  const float* w_sa_dd  = (const float*)d_in[23];
  const float* w_sa_dm  = (const float*)d_in[24];
  const float* w_sa_dt  = (const float*)d_in[25];
  const float* w_sa_ed  = (const float*)d_in[26];
  const float* w_sa_em  = (const float*)d_in[27];
  const float* w_sa_et  = (const float*)d_in[28];
  const float* w_squ1   = (const float*)d_in[29];
  const float* w_squ2   = (const float*)d_in[30];
  (void)in_sizes; (void)n_in; (void)out_size;

  const int HW512 = 512*512, HW256 = 256*256, HW128 = 128*128, HW64 = 64*64;
  const int S512 = 24*HW512, S256 = 24*HW256, S128 = 24*HW128, S64 = 24*HW64;

  float* ws = (float*)d_ws;
  float* OUT = (float*)d_out;
  size_t F = ws_size / sizeof(float);

  // fp32-reordered weights
  float* WT      = ws;
  float* wt_ed3  = WT + 85248;
  float* wt_dd3  = WT + 90432;
  float* wt_d_et = WT + 95616;
  float* wt_d_em = WT + 104832;
  float* wt_d_ed = WT + 114048;
  float* wt_c_dd = WT + 123264;
  float* wt_c_dm = WT + 132480;
  float* wt_c_dt = WT + 141696;
  float* wt_pw_ed= WT + 152064;
  float* wt_pw_dd= WT + 152640;
  float* wt_squ1 = WT + 154368;
  float* wt_squ2 = WT + 155520;

  // MFMA bf16 B-frag weights
  ushort_t* WB = (ushort_t*)(ws + 160000);
  ushort_t* wb_et7   = WB;
  ushort_t* wb_dt7   = WB + 50176;
  ushort_t* wb_em5   = WB + 100352;
  ushort_t* wb_dm5   = WB + 125952;
  ushort_t* wb_pw_et = WB + 151552;
  ushort_t* wb_pw_em = WB + 152576;
  ushort_t* wb_pw_dm = WB + 153600;
  ushort_t* wb_pw_dt = WB + 154624;   // end 155648 ushorts

  const size_t ABASE = 240000;

  auto needBatched = [&](size_t CB)->size_t{
    size_t u = (CB*(size_t)S512 > (size_t)8*S256) ? CB*(size_t)S512 : (size_t)8*S256;
    return ABASE + 2097152 + 12582912 + 3145728 + 786432 + CB*524288 + 2*u + 2;
  };
  int CB = 0;
  if (F >= needBatched(8)) CB = 8;
  else if (F >= needBatched(4)) CB = 4;
  else if (F >= needBatched(2)) CB = 2;
  const size_t NEED_B = ABASE + 15925250;
  if (CB == 0 && F < NEED_B) return;

  float *XL, *E1, *E2, *Q2, *E3, *Q3, *MM, *DIFF, *U1, *U2;
  if (CB > 0){
    size_t off = ABASE;
    size_t u = (CB*(size_t)S512 > (size_t)8*S256) ? CB*(size_t)S512 : (size_t)8*S256;
    XL = ws + off; off += 2097152;
    E1 = ws + off; off += 12582912;
    Q2 = ws + off; off += 3145728;
    Q3 = ws + off; off += 786432;
    MM = ws + off; off += CB*524288;
    U1 = ws + off; off += u;
    U2 = ws + off; off += u;
    DIFF = ws + off;
    E2 = OUT;
    E3 = OUT + 3145728;
  } else {
    size_t off = ABASE;
    XL = ws + off; off += 262144;
    U1 = ws + off; off += 6291456;
    U2 = ws + off; off += 6291456;
    E1 = ws + off; off += 1572864;
    E2 = ws + off; off += 393216;
    Q2 = ws + off; off += 393216;
    E3 = ws + off; off += 98304;
    Q3 = ws + off; off += 98304;
    MM = ws + off; off += 524288;
    DIFF = ws + off;
  }

  // ---- weight reorders ----
  k_rmfma<<<dim3(196), 256, 0, stream>>>(w_res_et, wb_et7, 7);
  k_rmfma<<<dim3(196), 256, 0, stream>>>(w_res_dt, wb_dt7, 7);
  k_rmfma<<<dim3(100), 256, 0, stream>>>(w_res_em, wb_em5, 5);
  k_rmfma<<<dim3(100), 256, 0, stream>>>(w_res_dm, wb_dm5, 5);
  k_rmfma<<<dim3(4), 256, 0, stream>>>(w_pw_et, wb_pw_et, 1);
  k_rmfma<<<dim3(4), 256, 0, stream>>>(w_pw_em, wb_pw_em, 1);
  k_rmfma<<<dim3(4), 256, 0, stream>>>(w_pw_dm, wb_pw_dm, 1);
  k_rmfma<<<dim3(4), 256, 0, stream>>>(w_pw_dt, wb_pw_dt, 1);
  k_r_res<<<dim3((576*9+255)/256), 256, 0, stream>>>(w_res_ed, wt_ed3, 3);
  k_r_res<<<dim3((576*9+255)/256), 256, 0, stream>>>(w_res_dd, wt_dd3, 3);
  k_r4<<<dim3(36), 256, 0, stream>>>(w_out_et, wt_d_et, 0);
  k_r4<<<dim3(36), 256, 0, stream>>>(w_out_em, wt_d_em, 0);
  k_r4<<<dim3(36), 256, 0, stream>>>(w_out_ed, wt_d_ed, 0);
  k_r4<<<dim3(36), 256, 0, stream>>>(w_out_dd, wt_c_dd, 1);
  k_r4<<<dim3(36), 256, 0, stream>>>(w_out_dm, wt_c_dm, 1);
  k_r4<<<dim3(36), 256, 0, stream>>>(w_out_dt, wt_c_dt, 1);
  k_r_pw<<<dim3(3), 256, 0, stream>>>(w_pw_ed, wt_pw_ed, 24);
  k_r_pw<<<dim3(3), 256, 0, stream>>>(w_pw_dd, wt_pw_dd, 24);
  k_r_pw<<<dim3(5), 256, 0, stream>>>(w_squ1, wt_squ1, 48);
  k_r_pw<<<dim3(5), 256, 0, stream>>>(w_squ2, wt_squ2, 48);

  hipMemsetAsync(DIFF, 0, 2*sizeof(float), stream);

  // ---- phase 1: input -> enc1 ----
  auto phase1 = [&](int c0, int nz, float* XLp, float* E1p){
    k_lap<<<dim3(HW512/256,1,nz), 256, 0, stream>>>(x + (size_t)c0*3*HW512, XLp, 512, 512);
    k_conv_mfma<7,true><<<dim3(16,32,nz), 512, 0, stream>>>(XLp, wb_et7, wb_pw_et, w_img_in,
                                                            U2, MM, 512, 512, HW512, S512, 2*HW512);
    k_attn_res_x<<<dim3(HW512/1024,1,nz), 256, 0, stream>>>(U2, MM, XLp, w_sa_et, w_img_in,
                                                            U1, 512, 512, S512, 2*HW512);
    k_down<<<dim3(8,16,nz), 256, 0, stream>>>(U1, wt_d_et, E1p, 256, 256, S512, S256);
  };

  // ---- deep: enc1 -> squ1 output ----
  auto deep = [&](int nb, float* E1p, float* SAp, float* SBp, float* E2p, float* Q2p,
                  float* E3p, float* Q3p, float* MMp, float* D1p){
    int mm256 = 2*HW256, mm128 = 2*HW128;
    k_conv_mfma<5,false><<<dim3(8,16,nb), 512, 0, stream>>>(E1p, wb_em5, wb_pw_em, nullptr,
                                                            SAp, MMp, 256, 256, S256, S256, mm256);
    k_attn_res<<<dim3(HW256/1024,1,nb), 256, 0, stream>>>(SAp, MMp, E1p, w_sa_em, SBp, 256, 256, S256, mm256);
    k_down<<<dim3(4,8,nb), 256, 0, stream>>>(SBp, wt_d_em, E2p, 128, 128, S256, S128);
    k_conv<3,8><<<dim3(4,16,nb), 256, 0, stream>>>(E2p, wt_ed3, SAp, 128, 128, S128, S128);
    k_pw<<<dim3(HW128/1024,1,nb), 256, 0, stream>>>(SAp, wt_pw_ed, SAp, MMp, HW128, S128, mm128);
    k_attn_res<<<dim3(HW128/1024,1,nb), 256, 0, stream>>>(SAp, MMp, E2p, w_sa_ed, SBp, 128, 128, S128, mm128);
    k_down<<<dim3(2,4,nb), 256, 0, stream>>>(SBp, wt_d_ed, E3p, 64, 64, S128, S64);
    k_quant<<<dim3(HW128/256,1,nb), 256, 0, stream>>>(E2p, embed2, Q2p, DIFF+0, HW128, S128);
    k_quant<<<dim3(HW64/256,1,nb), 256, 0, stream>>>(E3p, embed3, Q3p, DIFF+1, HW64, S64);
    k_convT2<<<dim3(4,8,nb), 256, 0, stream>>>(Q3p, wt_c_dd, SAp, 128, 128, S64, S128);
    k_conv<3,8><<<dim3(4,16,nb), 256, 0, stream>>>(SAp, wt_dd3, SBp, 128, 128, S128, S128);
    k_pw<<<dim3(HW128/1024,1,nb), 256, 0, stream>>>(SBp, wt_pw_dd, SBp, MMp, HW128, S128, mm128);
    k_attn_res<<<dim3(HW128/1024,1,nb), 256, 0, stream>>>(SBp, MMp, SAp, w_sa_dd, SAp, 128, 128, S128, mm128);
    k_squeeze<<<dim3(HW128/1024,1,nb), 256, 0, stream>>>(SAp, Q2p, wt_squ2, SBp, HW128, S128);
    k_convT2<<<dim3(8,16,nb), 256, 0, stream>>>(SBp, wt_c_dm, SAp, 256, 256, S128, S256);
    k_conv_mfma<5,false><<<dim3(8,16,nb), 512, 0, stream>>>(SAp, wb_dm5, wb_pw_dm, nullptr,
                                                            SBp, MMp, 256, 256, S256, S256, mm256);
    k_attn_res<<<dim3(HW256/1024,1,nb), 256, 0, stream>>>(SBp, MMp, SAp, w_sa_dm, SAp, 256, 256, S256, mm256);
    k_squeeze<<<dim3(HW256/1024,1,nb), 256, 0, stream>>>(SAp, E1p, wt_squ1, D1p, HW256, S256);
  };

  // ---- phase 3: D1 -> outputs ----
  auto phase3 = [&](int c0, int nz, const float* D1p, const float* XLp){
    k_convT2<<<dim3(16,32,nz), 256, 0, stream>>>(D1p, wt_c_dt, U1, 512, 512, S256, S512);
    k_conv_mfma<7,false><<<dim3(16,32,nz), 512, 0, stream>>>(U1, wb_dt7, wb_pw_dt, nullptr,
                                                             U2, MM, 512, 512, S512, S512, 2*HW512);
    k_attn_res<<<dim3(HW512/1024,1,nz), 256, 0, stream>>>(U2, MM, U1, w_sa_dt, U1, 512, 512, S512, 2*HW512);
    k_final<<<dim3(HW512/1024,1,nz), 256, 0, stream>>>(U1, w_img_out, XLp,
                                                       OUT + (size_t)c0*HW512,
                                                       OUT + 2097152 + (size_t)c0*HW512,
                                                       HW512, S512);
  };

  if (CB > 0){
    for (int c0=0;c0<8;c0+=CB)
      phase1(c0, CB, XL + (size_t)c0*HW512, E1 + (size_t)c0*S256);
    deep(8, E1, U1, U2, E2, Q2, E3, Q3, MM, E1);
    for (int c0=0;c0<8;c0+=CB)
      phase3(c0, CB, E1 + (size_t)c0*S256, XL + (size_t)c0*HW512);
  } else {
    for (int b=0;b<8;b++){
      phase1(b, 1, XL, E1);
      deep(1, E1, U1, U2, E2, Q2, E3, Q3, MM, U2);
      phase3(b, 1, U2, XL);
    }
  }

  k_diff<<<1, 1, 0, stream>>>(DIFF, OUT + 4194304);
}

// Round 7
// 2371.991 us; speedup vs baseline: 8.3010x; 1.2254x over previous
//
#include <hip/hip_runtime.h>
#include <math.h>

#define CH 24

typedef __attribute__((ext_vector_type(8))) short short8v;
typedef __attribute__((ext_vector_type(4))) float f32x4;
typedef unsigned short ushort_t;
typedef unsigned int uint_t;

__device__ inline ushort_t bf16r(float f){
  uint_t u = __float_as_uint(f);
  u += 0x7FFF + ((u>>16)&1);
  return (ushort_t)(u>>16);
}

// ================= weight reorder kernels =================
__global__ void k_r_res(const float* __restrict__ w, float* __restrict__ wT, int K){
  int i = blockIdx.x*256 + threadIdx.x;
  int n = 576*K*K; if (i >= n) return;
  int co = i % 24, ci = (i/24) % 24, kk = i/576;
  int ky = kk / K, kx = kk % K;
  wT[i] = w[((co*24+ci)*K+ky)*K+kx];
}
__global__ void k_r4(const float* __restrict__ w, float* __restrict__ wT, int tr){
  int i = blockIdx.x*256 + threadIdx.x;
  if (i >= 9216) return;
  int co = i % 24, ci = (i/24) % 24, kk = i/576;
  int ky = kk / 4, kx = kk % 4;
  wT[i] = tr ? w[((ci*24+co)*4+ky)*4+kx] : w[((co*24+ci)*4+ky)*4+kx];
}
__global__ void k_r_pw(const float* __restrict__ w, float* __restrict__ wT, int CIN){
  int i = blockIdx.x*256 + threadIdx.x;
  if (i >= CIN*24) return;
  int co = i % 24, ci = i/24;
  wT[i] = w[co*CIN+ci];
}
// MFMA-ready bf16 B-frags (OIHW source): wb[tap*1024 + t*512 + l*8 + j] = W[ci][co]
__global__ void k_rmfma(const float* __restrict__ w, ushort_t* __restrict__ wb, int K){
  int i = blockIdx.x*256 + threadIdx.x;
  int n = K*K*1024; if (i >= n) return;
  int j = i & 7, l = (i>>3) & 63, t = (i>>9) & 1, tap = i >> 10;
  int ci = (l>>4)*8 + j, co = t*16 + (l&15);
  int ky = tap / K, kx = tap % K;
  float v = (ci<24 && co<24) ? w[((co*24+ci)*K+ky)*K+kx] : 0.f;
  wb[i] = bf16r(v);
}
// MFMA-ready bf16 B-frags for convT (torch [in][out][4][4] source), 16 taps
__global__ void k_rmfma4(const float* __restrict__ w, ushort_t* __restrict__ wb){
  int i = blockIdx.x*256 + threadIdx.x;
  if (i >= 16384) return;
  int j = i & 7, l = (i>>3) & 63, t = (i>>9) & 1, tap = i >> 10;
  int ci = (l>>4)*8 + j, co = t*16 + (l&15);
  int ky = tap >> 2, kx = tap & 3;
  float v = (ci<24 && co<24) ? w[((ci*24+co)*4+ky)*4+kx] : 0.f;
  wb[i] = bf16r(v);
}

// ================= compute kernels =================

__global__ void k_lap(const float* __restrict__ x, float* __restrict__ xl, int H, int W){
  int idx = blockIdx.x*256 + threadIdx.x;
  int HW = H*W;
  if (idx >= HW) return;
  const float* xb = x + (size_t)blockIdx.z*3*HW;
  float* xo = xl + (size_t)blockIdx.z*HW;
  int px = idx % W, py = idx / W;
#define MEANV(yy,xx) (((yy)>=0&&(yy)<H&&(xx)>=0&&(xx)<W) ? (xb[(yy)*W+(xx)]+xb[HW+(yy)*W+(xx)]+xb[2*HW+(yy)*W+(xx)])*(1.f/3.f) : 0.f)
  float v = 4.f*MEANV(py,px) - MEANV(py-1,px) - MEANV(py+1,px) - MEANV(py,px-1) - MEANV(py,px+1);
#undef MEANV
  xo[idx] = v;
}

// ---------- MFMA KxK conv 24->24 (pad K/2) FUSED with 1x1 pw conv + mean/max maps ----------
template<int K, bool EXPAND>
__launch_bounds__(512)
__global__ void k_conv_mfma(const float* __restrict__ in, const ushort_t* __restrict__ wb,
                            const ushort_t* __restrict__ wbpw, const float* __restrict__ wexp,
                            float* __restrict__ out, float* __restrict__ mm,
                            int H, int W, int istrIn, int istrOut, int istrMM){
  constexpr int SW_T = 32 + K - 1;
  constexpr int SH = 16 + K - 1;
  constexpr int NPX = SH*SW_T;
  __shared__ ushort_t lds[NPX*32];
  __shared__ uint_t sc[8][16*20];
  int tid = threadIdx.x;
  const float* inb = in + (size_t)blockIdx.z*istrIn;
  int x0g = blockIdx.x*32 - K/2, y0g = blockIdx.y*16 - K/2;
  int HW = H*W;
  for (int i = tid; i < NPX*16; i += 512){
    int cpair = i / NPX;
    int pp = i - cpair*NPX;
    int c0 = cpair*2;
    int row = pp / SW_T, col = pp - row*SW_T;
    int gy = y0g + row, gx = x0g + col;
    float v0 = 0.f, v1 = 0.f;
    if (gy >= 0 && gy < H && gx >= 0 && gx < W){
      if (EXPAND){
        float val = inb[(size_t)gy*W + gx];
        v0 = val * wexp[c0];
        v1 = val * wexp[c0+1];
      } else {
        size_t base = (size_t)gy*W + gx;
        v0 = inb[(size_t)c0*HW + base];
        v1 = inb[(size_t)(c0+1)*HW + base];
      }
    }
    uint_t packed = (uint_t)bf16r(v0) | ((uint_t)bf16r(v1) << 16);
    int slot = pp*32 + (c0 ^ (((pp>>1)&3)<<3));
    *(uint_t*)(lds + slot) = packed;
  }
  __syncthreads();
  int l = tid & 63, wid = tid >> 6;
  int kg = l >> 4, li = l & 15;
  f32x4 zero = {0.f,0.f,0.f,0.f};
  f32x4 acc[4][2];
  #pragma unroll
  for (int i=0;i<4;i++){ acc[i][0]=zero; acc[i][1]=zero; }

  for (int ky=0; ky<K; ky++){
    for (int kx=0; kx<K; kx++){
      int tap = ky*K + kx;
      const ushort_t* wp = wb + (size_t)tap*1024;
      short8v b0 = *(const short8v*)(wp + l*8);
      short8v b1 = *(const short8v*)(wp + 512 + l*8);
      #pragma unroll
      for (int i=0;i<4;i++){
        int pp = (wid + (i&1)*8 + ky)*SW_T + (i>>1)*16 + kx + li;
        short8v a = *(const short8v*)(lds + pp*32 + ((kg*8) ^ (((pp>>1)&3)<<3)));
        acc[i][0] = __builtin_amdgcn_mfma_f32_16x16x32_bf16(a, b0, acc[i][0], 0, 0, 0);
        acc[i][1] = __builtin_amdgcn_mfma_f32_16x16x32_bf16(a, b1, acc[i][1], 0, 0, 0);
      }
    }
  }
  // ---- stage 2: pw 1x1 via second MFMA, + mean/max ----
  short8v bpw0 = *(const short8v*)(wbpw + l*8);
  short8v bpw1 = *(const short8v*)(wbpw + 512 + l*8);
  uint_t* s = sc[wid];
  float* outb = out + (size_t)blockIdx.z*istrOut;
  float* mmb = mm + (size_t)blockIdx.z*istrMM;
  #pragma unroll 1
  for (int i=0;i<4;i++){
    __asm__ volatile("s_waitcnt lgkmcnt(0)" ::: "memory");
    __builtin_amdgcn_sched_barrier(0);
    #pragma unroll
    for (int reg=0; reg<4; reg++){
      float v0 = acc[i][0][reg], v1 = acc[i][1][reg];
      float v0n = __shfl_xor(v0, 1, 64);
      float v1n = __shfl_xor(v1, 1, 64);
      int pxr = kg*4 + reg;
      uint_t packed; int uidx;
      if ((li & 1) == 0){
        packed = (uint_t)bf16r(v0) | ((uint_t)bf16r(v0n) << 16);
        uidx = li >> 1;
      } else {
        packed = (uint_t)bf16r(v1n) | ((uint_t)bf16r(v1) << 16);
        uidx = 8 + (li >> 1);
      }
      s[pxr*20 + uidx] = packed;
    }
    __asm__ volatile("s_waitcnt lgkmcnt(0)" ::: "memory");
    __builtin_amdgcn_sched_barrier(0);
    short8v a2 = *(const short8v*)((const ushort_t*)s + li*40 + kg*8);
    f32x4 d0 = __builtin_amdgcn_mfma_f32_16x16x32_bf16(a2, bpw0, zero, 0, 0, 0);
    f32x4 d1 = __builtin_amdgcn_mfma_f32_16x16x32_bf16(a2, bpw1, zero, 0, 0, 0);
    int gy = blockIdx.y*16 + wid + (i&1)*8;
    int gx = blockIdx.x*32 + (i>>1)*16 + kg*4;
    float* o0 = outb + (size_t)li*HW + (size_t)gy*W + gx;
    *(f32x4*)o0 = d0;
    if (li < 8){
      float* o1 = outb + (size_t)(16+li)*HW + (size_t)gy*W + gx;
      *(f32x4*)o1 = d1;
    }
    f32x4 sm, mx;
    #pragma unroll
    for (int reg=0; reg<4; reg++){
      sm[reg] = d0[reg] + d1[reg];
      mx[reg] = fmaxf(d0[reg], (li<8) ? d1[reg] : -3.4e38f);
    }
    #pragma unroll
    for (int m=1; m<16; m<<=1){
      #pragma unroll
      for (int reg=0; reg<4; reg++){
        sm[reg] += __shfl_xor(sm[reg], m, 64);
        mx[reg] = fmaxf(mx[reg], __shfl_xor(mx[reg], m, 64));
      }
    }
    if (li == 0){
      f32x4 me; me[0]=sm[0]*(1.f/24.f); me[1]=sm[1]*(1.f/24.f); me[2]=sm[2]*(1.f/24.f); me[3]=sm[3]*(1.f/24.f);
      *(f32x4*)(mmb + (size_t)gy*W + gx) = me;
      *(f32x4*)(mmb + (size_t)HW + (size_t)gy*W + gx) = mx;
    }
  }
}

// ---------- MFMA ConvTranspose2d(k=4,s=2,p=1), 32x16 output tile, 8 waves ----------
__launch_bounds__(512)
__global__ void k_convT_mfma(const float* __restrict__ in, const ushort_t* __restrict__ wb,
                             float* __restrict__ out, int Ho, int Wo, int istrIn, int istrOut){
  const int Hi = Ho>>1, Wi = Wo>>1;
  constexpr int SW_T = 18, NPX = 180;   // 10 rows x 18 cols input halo
  __shared__ ushort_t lds[NPX*32];
  int tid = threadIdx.x;
  const float* inb = in + (size_t)blockIdx.z*istrIn;
  int X0 = blockIdx.x*32, Y0 = blockIdx.y*16;
  int ix0 = (X0>>1) - 1, iy0 = (Y0>>1) - 1;
  int HWi = Hi*Wi;
  for (int i = tid; i < NPX*16; i += 512){
    int cpair = i / NPX;
    int pp = i - cpair*NPX;
    int c0 = cpair*2;
    int row = pp / SW_T, col = pp - row*SW_T;
    int gy = iy0 + row, gx = ix0 + col;
    float v0=0.f, v1=0.f;
    if (gy>=0 && gy<Hi && gx>=0 && gx<Wi){
      size_t base = (size_t)gy*Wi + gx;
      v0 = inb[(size_t)c0*HWi + base];
      v1 = inb[(size_t)(c0+1)*HWi + base];
    }
    uint_t packed = (uint_t)bf16r(v0) | ((uint_t)bf16r(v1)<<16);
    int slot = pp*32 + (c0 ^ (((pp>>1)&3)<<3));
    *(uint_t*)(lds + slot) = packed;
  }
  __syncthreads();
  int l = tid & 63, wid = tid >> 6;
  int kg = l >> 4, li = l & 15;
  f32x4 zero = {0.f,0.f,0.f,0.f};
  f32x4 acc[4][2];
  #pragma unroll
  for (int i=0;i<4;i++){ acc[i][0]=zero; acc[i][1]=zero; }

  // group g = wid + 8*i : output row r = g&15 (y = Y0+r), x-parity q = g>>4
  #pragma unroll
  for (int i=0;i<4;i++){
    int g = wid + 8*i;
    int r = g & 15, q = g >> 4;
    int ky0 = (r+1)&1;
    #pragma unroll
    for (int t2=0;t2<2;t2++){
      int ky = ky0 + 2*t2;
      int liy = ((r+1-ky)>>1) + 1;
      #pragma unroll
      for (int u=0;u<2;u++){
        int kx = (q ? 0 : 1) + 2*u;
        int lixb = ((q+1-kx)>>1) + 1;
        int tap = ky*4 + kx;
        const ushort_t* wp = wb + (size_t)tap*1024;
        short8v b0 = *(const short8v*)(wp + l*8);
        short8v b1 = *(const short8v*)(wp + 512 + l*8);
        int pp = liy*SW_T + lixb + li;
        short8v a = *(const short8v*)(lds + pp*32 + ((kg*8) ^ (((pp>>1)&3)<<3)));
        acc[i][0] = __builtin_amdgcn_mfma_f32_16x16x32_bf16(a, b0, acc[i][0], 0, 0, 0);
        acc[i][1] = __builtin_amdgcn_mfma_f32_16x16x32_bf16(a, b1, acc[i][1], 0, 0, 0);
      }
    }
  }
  float* outb = out + (size_t)blockIdx.z*istrOut;
  int HWo = Ho*Wo;
  #pragma unroll
  for (int i=0;i<4;i++){
    int g = wid + 8*i;
    int r = g & 15, q = g >> 4;
    int oy = Y0 + r;
    #pragma unroll
    for (int reg=0; reg<4; reg++){
      int ox = X0 + 2*(kg*4 + reg) + q;
      outb[(size_t)li*HWo + (size_t)oy*Wo + ox] = acc[i][0][reg];
      if (li < 8)
        outb[(size_t)(16+li)*HWo + (size_t)oy*Wo + ox] = acc[i][1][reg];
    }
  }
}

// KxK conv fp32 (K=3 @128). wT=[ky][kx][ci][co]. Tile 32 x TH.
template<int K, int TH>
__launch_bounds__(256)
__global__ void k_conv(const float* __restrict__ in, const float* __restrict__ wT,
                       float* __restrict__ out, int H, int W, int istrIn, int istrOut){
  constexpr int TW = 32;
  constexpr int PX = (TW*TH)/256;
  constexpr int XT = TW/PX;
  constexpr int SW = TW + K - 1;
  constexpr int SWP = SW | 1;
  constexpr int SH = TH + K - 1;
  constexpr int CC = 8;
  __shared__ float tile[CC*SH*SWP];
  int tx = threadIdx.x % XT, ty = threadIdx.x / XT;
  int x0 = blockIdx.x*TW - K/2, y0 = blockIdx.y*TH - K/2;
  const float* inb = in + (size_t)blockIdx.z*istrIn;
  float acc[CH][PX];
  #pragma unroll
  for (int co=0;co<CH;co++)
    #pragma unroll
    for (int px=0;px<PX;px++) acc[co][px] = 0.f;

  #pragma unroll 1
  for (int c0=0;c0<CH;c0+=CC){
    __syncthreads();
    for (int i=threadIdx.x; i<CC*SH*SW; i+=256){
      int col = i % SW; int rr = i / SW; int row = rr % SH; int c = rr / SH;
      int gy = y0+row, gx = x0+col;
      tile[(c*SH+row)*SWP+col] = (gy>=0 && gy<H && gx>=0 && gx<W)
          ? inb[(size_t)(c0+c)*H*W + (size_t)gy*W + gx] : 0.f;
    }
    __syncthreads();
    #pragma unroll 1
    for (int ci=0;ci<CC;ci++){
      #pragma unroll 1
      for (int ky=0;ky<K;ky++){
        const float* trow = &tile[(ci*SH + ty+ky)*SWP + tx*PX];
        #pragma unroll
        for (int kx=0;kx<K;kx++){
          float v[PX];
          #pragma unroll
          for (int px=0;px<PX;px++) v[px] = trow[kx+px];
          const float* wp = wT + ((ky*K+kx)*24 + c0+ci)*24;
          #pragma unroll
          for (int co=0;co<CH;co++){
            float wv = wp[co];
            #pragma unroll
            for (int px=0;px<PX;px++) acc[co][px] = fmaf(v[px], wv, acc[co][px]);
          }
        }
      }
    }
  }
  int oy = blockIdx.y*TH+ty, ox = blockIdx.x*TW+tx*PX;
  float* ob = out + (size_t)blockIdx.z*istrOut + (size_t)oy*W + ox;
  #pragma unroll
  for (int co=0;co<CH;co++){
    if (PX == 2){
      float2 o; o.x=acc[co][0]; o.y=acc[co][1];
      *(float2*)(ob + (size_t)co*H*W) = o;
    } else {
      ob[(size_t)co*H*W] = acc[co][0];
    }
  }
}

__global__ void k_pw(const float* in, const float* __restrict__ wT,
                     float* out, float* __restrict__ mm, int HW, int istr, int istrMM){
  int p = (blockIdx.x*256 + threadIdx.x)*4;
  if (p >= HW) return;
  const float* ib = in + (size_t)blockIdx.z*istr;
  float acc[CH][4];
  #pragma unroll
  for (int co=0;co<CH;co++){ acc[co][0]=0;acc[co][1]=0;acc[co][2]=0;acc[co][3]=0; }
  #pragma unroll 1
  for (int ci=0;ci<CH;ci++){
    float4 v = *(const float4*)(ib + (size_t)ci*HW + p);
    const float* wp = wT + ci*24;
    #pragma unroll
    for (int co=0;co<CH;co++){
      float wv = wp[co];
      acc[co][0] = fmaf(v.x, wv, acc[co][0]);
      acc[co][1] = fmaf(v.y, wv, acc[co][1]);
      acc[co][2] = fmaf(v.z, wv, acc[co][2]);
      acc[co][3] = fmaf(v.w, wv, acc[co][3]);
    }
  }
  float mean[4]={0,0,0,0}, mx[4]={-3.4e38f,-3.4e38f,-3.4e38f,-3.4e38f};
  #pragma unroll
  for (int co=0;co<CH;co++)
    #pragma unroll
    for (int j=0;j<4;j++){ mean[j]+=acc[co][j]; mx[j]=fmaxf(mx[j],acc[co][j]); }
  float* ob = out + (size_t)blockIdx.z*istr;
  #pragma unroll
  for (int co=0;co<CH;co++){
    float4 o; o.x=acc[co][0]; o.y=acc[co][1]; o.z=acc[co][2]; o.w=acc[co][3];
    *(float4*)(ob + (size_t)co*HW + p) = o;
  }
  float* mb = mm + (size_t)blockIdx.z*istrMM;
  float4 me; me.x=mean[0]*(1.f/24.f); me.y=mean[1]*(1.f/24.f); me.z=mean[2]*(1.f/24.f); me.w=mean[3]*(1.f/24.f);
  float4 mxo; mxo.x=mx[0]; mxo.y=mx[1]; mxo.z=mx[2]; mxo.w=mx[3];
  *(float4*)(mb + p) = me;
  *(float4*)(mb + HW + p) = mxo;
}

__global__ void k_attn_res(const float* __restrict__ R, const float* __restrict__ M,
                           const float* X, const float* __restrict__ wsa,
                           float* out, int H, int W, int istr, int istrMM){
  int p = (blockIdx.x*256 + threadIdx.x)*4;
  int HW = H*W;
  if (p >= HW) return;
  int py = p / W, px0 = p % W;
  const float* Mb = M + (size_t)blockIdx.z*istrMM;
  float s[4]={0,0,0,0};
  #pragma unroll
  for (int cc=0;cc<2;cc++){
    const float* Mc = Mb + (size_t)cc*HW;
    #pragma unroll 1
    for (int ky=0;ky<7;ky++){
      int gy = py+ky-3;
      if (gy<0||gy>=H) continue;
      const float* mr = Mc + (size_t)gy*W;
      float mv[10];
      #pragma unroll
      for (int j=0;j<10;j++){
        int gx = px0-3+j;
        mv[j] = (gx>=0 && gx<W) ? mr[gx] : 0.f;
      }
      const float* wr = wsa + (cc*7+ky)*7;
      #pragma unroll
      for (int kx=0;kx<7;kx++){
        float wv = wr[kx];
        #pragma unroll
        for (int px=0;px<4;px++) s[px] = fmaf(mv[kx+px], wv, s[px]);
      }
    }
  }
  float g[4];
  #pragma unroll
  for (int px=0;px<4;px++) g[px] = 1.f/(1.f+expf(-s[px]));
  const float* Rb = R + (size_t)blockIdx.z*istr;
  const float* Xb = X + (size_t)blockIdx.z*istr;
  float* Ob = out + (size_t)blockIdx.z*istr;
  #pragma unroll
  for (int c=0;c<CH;c++){
    float4 r = *(const float4*)(Rb + (size_t)c*HW + p);
    float4 xv = *(const float4*)(Xb + (size_t)c*HW + p);
    float4 o;
    o.x = xv.x + fmaxf(r.x*g[0], 0.f);
    o.y = xv.y + fmaxf(r.y*g[1], 0.f);
    o.z = xv.z + fmaxf(r.z*g[2], 0.f);
    o.w = xv.w + fmaxf(r.w*g[3], 0.f);
    *(float4*)(Ob + (size_t)c*HW + p) = o;
  }
}

__global__ void k_attn_res_x(const float* __restrict__ R, const float* __restrict__ M,
                             const float* __restrict__ XL, const float* __restrict__ wsa,
                             const float* __restrict__ wexp,
                             float* __restrict__ out, int H, int W, int istr, int istrMM){
  int p = (blockIdx.x*256 + threadIdx.x)*4;
  int HW = H*W;
  if (p >= HW) return;
  int py = p / W, px0 = p % W;
  const float* Mb = M + (size_t)blockIdx.z*istrMM;
  float s[4]={0,0,0,0};
  #pragma unroll
  for (int cc=0;cc<2;cc++){
    const float* Mc = Mb + (size_t)cc*HW;
    #pragma unroll 1
    for (int ky=0;ky<7;ky++){
      int gy = py+ky-3;
      if (gy<0||gy>=H) continue;
      const float* mr = Mc + (size_t)gy*W;
      float mv[10];
      #pragma unroll
      for (int j=0;j<10;j++){
        int gx = px0-3+j;
        mv[j] = (gx>=0 && gx<W) ? mr[gx] : 0.f;
      }
      const float* wr = wsa + (cc*7+ky)*7;
      #pragma unroll
      for (int kx=0;kx<7;kx++){
        float wv = wr[kx];
        #pragma unroll
        for (int px=0;px<4;px++) s[px] = fmaf(mv[kx+px], wv, s[px]);
      }
    }
  }
  float g[4];
  #pragma unroll
  for (int px=0;px<4;px++) g[px] = 1.f/(1.f+expf(-s[px]));
  float4 xl4 = *(const float4*)(XL + (size_t)blockIdx.z*HW + p);
  const float* Rb = R + (size_t)blockIdx.z*istr;
  float* Ob = out + (size_t)blockIdx.z*istr;
  #pragma unroll
  for (int c=0;c<CH;c++){
    float wc = wexp[c];
    float4 r = *(const float4*)(Rb + (size_t)c*HW + p);
    float4 o;
    o.x = xl4.x*wc + fmaxf(r.x*g[0], 0.f);
    o.y = xl4.y*wc + fmaxf(r.y*g[1], 0.f);
    o.z = xl4.z*wc + fmaxf(r.z*g[2], 0.f);
    o.w = xl4.w*wc + fmaxf(r.w*g[3], 0.f);
    *(float4*)(Ob + (size_t)c*HW + p) = o;
  }
}

__global__ void k_down(const float* __restrict__ in, const float* __restrict__ wT,
                       float* __restrict__ out, int Ho, int Wo, int istrIn, int istrOut){
  int tx = threadIdx.x % 16, ty = threadIdx.x / 16;
  int ox0 = blockIdx.x*32 + tx*2, oy = blockIdx.y*16 + ty;
  int Hi = Ho*2, Wi = Wo*2;
  const float* inb = in + (size_t)blockIdx.z*istrIn;
  float acc[CH][2];
  #pragma unroll
  for (int c=0;c<CH;c++){ acc[c][0]=0; acc[c][1]=0; }
  #pragma unroll 1
  for (int ci=0;ci<CH;ci++){
    const float* ip = inb + (size_t)ci*Hi*Wi;
    #pragma unroll
    for (int ky=0;ky<4;ky++){
      int iy = 2*oy + ky - 1;
      if (iy < 0 || iy >= Hi) continue;
      #pragma unroll
      for (int kx=0;kx<4;kx++){
        int ix0 = 2*ox0 + kx - 1;
        float v0 = (ix0>=0 && ix0<Wi) ? ip[(size_t)iy*Wi + ix0] : 0.f;
        int ix1 = ix0 + 2;
        float v1 = (ix1 < Wi) ? ip[(size_t)iy*Wi + ix1] : 0.f;
        const float* wp = wT + ((ky*4+kx)*24+ci)*24;
        #pragma unroll
        for (int co=0;co<CH;co++){
          float wv = wp[co];
          acc[co][0] = fmaf(v0, wv, acc[co][0]);
          acc[co][1] = fmaf(v1, wv, acc[co][1]);
        }
      }
    }
  }
  float* ob = out + (size_t)blockIdx.z*istrOut + (size_t)oy*Wo + ox0;
  #pragma unroll
  for (int co=0;co<CH;co++){
    float2 o; o.x=acc[co][0]; o.y=acc[co][1];
    *(float2*)(ob + (size_t)co*Ho*Wo) = o;
  }
}

__global__ void k_squeeze(const float* __restrict__ inA, const float* inB,
                          const float* __restrict__ wT, float* out, int HW, int istr){
  int p = (blockIdx.x*256 + threadIdx.x)*4;
  if (p >= HW) return;
  const float* Ab = inA + (size_t)blockIdx.z*istr;
  const float* Bb = inB + (size_t)blockIdx.z*istr;
  float acc[CH][4];
  #pragma unroll
  for (int co=0;co<CH;co++){ acc[co][0]=0;acc[co][1]=0;acc[co][2]=0;acc[co][3]=0; }
  #pragma unroll 1
  for (int ci=0;ci<48;ci++){
    const float* src = (ci<24) ? (Ab + (size_t)ci*HW) : (Bb + (size_t)(ci-24)*HW);
    float4 v = *(const float4*)(src + p);
    const float* wp = wT + ci*24;
    #pragma unroll
    for (int co=0;co<CH;co++){
      float wv = wp[co];
      acc[co][0] = fmaf(v.x, wv, acc[co][0]);
      acc[co][1] = fmaf(v.y, wv, acc[co][1]);
      acc[co][2] = fmaf(v.z, wv, acc[co][2]);
      acc[co][3] = fmaf(v.w, wv, acc[co][3]);
    }
  }
  float* ob = out + (size_t)blockIdx.z*istr;
  #pragma unroll
  for (int co=0;co<CH;co++){
    float4 o; o.x=acc[co][0]; o.y=acc[co][1]; o.z=acc[co][2]; o.w=acc[co][3];
    *(float4*)(ob + (size_t)co*HW + p) = o;
  }
}

__global__ void k_quant(const float* __restrict__ enc, const float* __restrict__ embed,
                        float* __restrict__ qt, float* __restrict__ diffAcc, int HW, int istr){
  __shared__ float em[256*28];
  __shared__ float red[4];
  {
    int j = threadIdx.x;
    float s = 0.f;
    #pragma unroll
    for (int c=0;c<CH;c++){
      float e = embed[c*256+j];
      em[j*28+c] = -2.0f*e;
      s = fmaf(e,e,s);
    }
    em[j*28+24] = s; em[j*28+25]=0.f; em[j*28+26]=0.f; em[j*28+27]=0.f;
  }
  __syncthreads();
  int p = blockIdx.x*256 + threadIdx.x;
  const float* eb = enc + (size_t)blockIdx.z*istr;
  float f[CH];
  #pragma unroll
  for (int c=0;c<CH;c++) f[c] = eb[(size_t)c*HW + p];
  float best = 3.4e38f; int bj = 0;
  #pragma unroll 1
  for (int j=0;j<256;j++){
    const float4* row = (const float4*)&em[j*28];
    float s = em[j*28+24];
    #pragma unroll
    for (int q4=0;q4<6;q4++){
      float4 r = row[q4];
      s = fmaf(f[q4*4+0], r.x, s);
      s = fmaf(f[q4*4+1], r.y, s);
      s = fmaf(f[q4*4+2], r.z, s);
      s = fmaf(f[q4*4+3], r.w, s);
    }
    if (s < best){ best = s; bj = j; }
  }
  float* qb = qt + (size_t)blockIdx.z*istr;
  float d = 0.f;
  #pragma unroll
  for (int c=0;c<CH;c++){
    float q = embed[c*256+bj];
    qb[(size_t)c*HW + p] = q;
    float e = q - f[c];
    d = fmaf(e,e,d);
  }
  #pragma unroll
  for (int off=32; off>0; off>>=1) d += __shfl_down(d, off, 64);
  int lane = threadIdx.x & 63, wv = threadIdx.x >> 6;
  if (lane==0) red[wv] = d;
  __syncthreads();
  if (threadIdx.x==0) atomicAdd(diffAcc, red[0]+red[1]+red[2]+red[3]);
}

__global__ void k_final(const float* __restrict__ dec1, const float* __restrict__ w,
                        const float* __restrict__ xl, float* __restrict__ outMask,
                        float* __restrict__ outClean, int HW, int dstr){
  int p = (blockIdx.x*256 + threadIdx.x)*4;
  if (p >= HW) return;
  const float* db = dec1 + (size_t)blockIdx.z*dstr;
  float m[4]={0,0,0,0};
  #pragma unroll
  for (int c=0;c<CH;c++){
    float4 d = *(const float4*)(db + (size_t)c*HW + p);
    float wc = w[c];
    m[0]=fmaf(d.x,wc,m[0]); m[1]=fmaf(d.y,wc,m[1]); m[2]=fmaf(d.z,wc,m[2]); m[3]=fmaf(d.w,wc,m[3]);
  }
  float4 xv = *(const float4*)(xl + (size_t)blockIdx.z*HW + p);
  float4 mo; mo.x=m[0]; mo.y=m[1]; mo.z=m[2]; mo.w=m[3];
  float4 co; co.x=xv.x-m[0]; co.y=xv.y-m[1]; co.z=xv.z-m[2]; co.w=xv.w-m[3];
  *(float4*)(outMask + (size_t)blockIdx.z*HW + p) = mo;
  *(float4*)(outClean + (size_t)blockIdx.z*HW + p) = co;
}

__global__ void k_diff(const float* __restrict__ acc, float* __restrict__ out){
  out[0] = acc[0]*(1.f/3145728.f) + acc[1]*(1.f/786432.f);
}

// =======================================================================
extern "C" void kernel_launch(void* const* d_in, const int* in_sizes, int n_in,
                              void* d_out, int out_size, void* d_ws, size_t ws_size,
                              hipStream_t stream) {
  const float* x        = (const float*)d_in[0];
  const float* embed2   = (const float*)d_in[1];
  const float* embed3   = (const float*)d_in[2];
  const float* w_img_in = (const float*)d_in[3];
  const float* w_img_out= (const float*)d_in[4];
  const float* w_out_dd = (const float*)d_in[5];
  const float* w_out_dm = (const float*)d_in[6];
  const float* w_out_dt = (const float*)d_in[7];
  const float* w_out_ed = (const float*)d_in[8];
  const float* w_out_em = (const float*)d_in[9];
  const float* w_out_et = (const float*)d_in[10];
  const float* w_pw_dd  = (const float*)d_in[11];
  const float* w_pw_dm  = (const float*)d_in[12];
  const float* w_pw_dt  = (const float*)d_in[13];
  const float* w_pw_ed  = (const float*)d_in[14];
  const float* w_pw_em  = (const float*)d_in[15];
  const float* w_pw_et  = (const float*)d_in[16];
  const float* w_res_dd = (const float*)d_in[17];
  const float* w_res_dm = (const float*)d_in[18];
  const float* w_res_dt = (const float*)d_in[19];
  const float* w_res_ed = (const float*)d_in[20];
  const float* w_res_em = (const float*)d_in[21];
  const float* w_res_et = (const float*)d_in[22];
  const float* w_sa_dd  = (const float*)d_in[23];
  const float* w_sa_dm  = (const float*)d_in[24];
  const float* w_sa_dt  = (const float*)d_in[25];
  const float* w_sa_ed  = (const float*)d_in[26];
  const float* w_sa_em  = (const float*)d_in[27];
  const float* w_sa_et  = (const float*)d_in[28];
  const float* w_squ1   = (const float*)d_in[29];
  const float* w_squ2   = (const float*)d_in[30];
  (void)in_sizes; (void)n_in; (void)out_size;

  const int HW512 = 512*512, HW256 = 256*256, HW128 = 128*128, HW64 = 64*64;
  const int S512 = 24*HW512, S256 = 24*HW256, S128 = 24*HW128, S64 = 24*HW64;

  float* ws = (float*)d_ws;
  float* OUT = (float*)d_out;
  size_t F = ws_size / sizeof(float);

  // fp32-reordered weights
  float* WT      = ws;
  float* wt_ed3  = WT + 85248;
  float* wt_dd3  = WT + 90432;
  float* wt_d_et = WT + 95616;
  float* wt_d_em = WT + 104832;
  float* wt_d_ed = WT + 114048;
  float* wt_pw_ed= WT + 152064;
  float* wt_pw_dd= WT + 152640;
  float* wt_squ1 = WT + 154368;
  float* wt_squ2 = WT + 155520;

  // MFMA bf16 B-frag weights
  ushort_t* WB = (ushort_t*)(ws + 160000);
  ushort_t* wb_et7   = WB;
  ushort_t* wb_dt7   = WB + 50176;
  ushort_t* wb_em5   = WB + 100352;
  ushort_t* wb_dm5   = WB + 125952;
  ushort_t* wb_pw_et = WB + 151552;
  ushort_t* wb_pw_em = WB + 152576;
  ushort_t* wb_pw_dm = WB + 153600;
  ushort_t* wb_pw_dt = WB + 154624;
  ushort_t* wb4_dd   = WB + 155648;
  ushort_t* wb4_dm   = WB + 172032;
  ushort_t* wb4_dt   = WB + 188416;   // ends 204800 ushorts = 102400 floats

  const size_t ABASE = 264000;

  auto needBatched = [&](size_t CB)->size_t{
    size_t u = (CB*(size_t)S512 > (size_t)8*S256) ? CB*(size_t)S512 : (size_t)8*S256;
    return ABASE + 2097152 + 12582912 + 3145728 + 786432 + CB*524288 + 2*u + 2;
  };
  int CB = 0;
  if (F >= needBatched(8)) CB = 8;
  else if (F >= needBatched(4)) CB = 4;
  else if (F >= needBatched(2)) CB = 2;
  const size_t NEED_B = ABASE + 15925250;
  if (CB == 0 && F < NEED_B) return;

  float *XL, *E1, *E2, *Q2, *E3, *Q3, *MM, *DIFF, *U1, *U2;
  if (CB > 0){
    size_t off = ABASE;
    size_t u = (CB*(size_t)S512 > (size_t)8*S256) ? CB*(size_t)S512 : (size_t)8*S256;
    XL = ws + off; off += 2097152;
    E1 = ws + off; off += 12582912;
    Q2 = ws + off; off += 3145728;
    Q3 = ws + off; off += 786432;
    MM = ws + off; off += CB*524288;
    U1 = ws + off; off += u;
    U2 = ws + off; off += u;
    DIFF = ws + off;
    E2 = OUT;
    E3 = OUT + 3145728;
  } else {
    size_t off = ABASE;
    XL = ws + off; off += 262144;
    U1 = ws + off; off += 6291456;
    U2 = ws + off; off += 6291456;
    E1 = ws + off; off += 1572864;
    E2 = ws + off; off += 393216;
    Q2 = ws + off; off += 393216;
    E3 = ws + off; off += 98304;
    Q3 = ws + off; off += 98304;
    MM = ws + off; off += 524288;
    DIFF = ws + off;
  }

  // ---- weight reorders ----
  k_rmfma<<<dim3(196), 256, 0, stream>>>(w_res_et, wb_et7, 7);
  k_rmfma<<<dim3(196), 256, 0, stream>>>(w_res_dt, wb_dt7, 7);
  k_rmfma<<<dim3(100), 256, 0, stream>>>(w_res_em, wb_em5, 5);
  k_rmfma<<<dim3(100), 256, 0, stream>>>(w_res_dm, wb_dm5, 5);
  k_rmfma<<<dim3(4), 256, 0, stream>>>(w_pw_et, wb_pw_et, 1);
  k_rmfma<<<dim3(4), 256, 0, stream>>>(w_pw_em, wb_pw_em, 1);
  k_rmfma<<<dim3(4), 256, 0, stream>>>(w_pw_dm, wb_pw_dm, 1);
  k_rmfma<<<dim3(4), 256, 0, stream>>>(w_pw_dt, wb_pw_dt, 1);
  k_rmfma4<<<dim3(64), 256, 0, stream>>>(w_out_dd, wb4_dd);
  k_rmfma4<<<dim3(64), 256, 0, stream>>>(w_out_dm, wb4_dm);
  k_rmfma4<<<dim3(64), 256, 0, stream>>>(w_out_dt, wb4_dt);
  k_r_res<<<dim3((576*9+255)/256), 256, 0, stream>>>(w_res_ed, wt_ed3, 3);
  k_r_res<<<dim3((576*9+255)/256), 256, 0, stream>>>(w_res_dd, wt_dd3, 3);
  k_r4<<<dim3(36), 256, 0, stream>>>(w_out_et, wt_d_et, 0);
  k_r4<<<dim3(36), 256, 0, stream>>>(w_out_em, wt_d_em, 0);
  k_r4<<<dim3(36), 256, 0, stream>>>(w_out_ed, wt_d_ed, 0);
  k_r_pw<<<dim3(3), 256, 0, stream>>>(w_pw_ed, wt_pw_ed, 24);
  k_r_pw<<<dim3(3), 256, 0, stream>>>(w_pw_dd, wt_pw_dd, 24);
  k_r_pw<<<dim3(5), 256, 0, stream>>>(w_squ1, wt_squ1, 48);
  k_r_pw<<<dim3(5), 256, 0, stream>>>(w_squ2, wt_squ2, 48);

  hipMemsetAsync(DIFF, 0, 2*sizeof(float), stream);

  // ---- phase 1: input -> enc1 ----
  auto phase1 = [&](int c0, int nz, float* XLp, float* E1p){
    k_lap<<<dim3(HW512/256,1,nz), 256, 0, stream>>>(x + (size_t)c0*3*HW512, XLp, 512, 512);
    k_conv_mfma<7,true><<<dim3(16,32,nz), 512, 0, stream>>>(XLp, wb_et7, wb_pw_et, w_img_in,
                                                            U2, MM, 512, 512, HW512, S512, 2*HW512);
    k_attn_res_x<<<dim3(HW512/1024,1,nz), 256, 0, stream>>>(U2, MM, XLp, w_sa_et, w_img_in,
                                                            U1, 512, 512, S512, 2*HW512);
    k_down<<<dim3(8,16,nz), 256, 0, stream>>>(U1, wt_d_et, E1p, 256, 256, S512, S256);
  };

  // ---- deep: enc1 -> squ1 output ----
  auto deep = [&](int nb, float* E1p, float* SAp, float* SBp, float* E2p, float* Q2p,
                  float* E3p, float* Q3p, float* MMp, float* D1p){
    int mm256 = 2*HW256, mm128 = 2*HW128;
    k_conv_mfma<5,false><<<dim3(8,16,nb), 512, 0, stream>>>(E1p, wb_em5, wb_pw_em, nullptr,
                                                            SAp, MMp, 256, 256, S256, S256, mm256);
    k_attn_res<<<dim3(HW256/1024,1,nb), 256, 0, stream>>>(SAp, MMp, E1p, w_sa_em, SBp, 256, 256, S256, mm256);
    k_down<<<dim3(4,8,nb), 256, 0, stream>>>(SBp, wt_d_em, E2p, 128, 128, S256, S128);
    k_conv<3,8><<<dim3(4,16,nb), 256, 0, stream>>>(E2p, wt_ed3, SAp, 128, 128, S128, S128);
    k_pw<<<dim3(HW128/1024,1,nb), 256, 0, stream>>>(SAp, wt_pw_ed, SAp, MMp, HW128, S128, mm128);
    k_attn_res<<<dim3(HW128/1024,1,nb), 256, 0, stream>>>(SAp, MMp, E2p, w_sa_ed, SBp, 128, 128, S128, mm128);
    k_down<<<dim3(2,4,nb), 256, 0, stream>>>(SBp, wt_d_ed, E3p, 64, 64, S128, S64);
    k_quant<<<dim3(HW128/256,1,nb), 256, 0, stream>>>(E2p, embed2, Q2p, DIFF+0, HW128, S128);
    k_quant<<<dim3(HW64/256,1,nb), 256, 0, stream>>>(E3p, embed3, Q3p, DIFF+1, HW64, S64);
    k_convT_mfma<<<dim3(4,8,nb), 512, 0, stream>>>(Q3p, wb4_dd, SAp, 128, 128, S64, S128);
    k_conv<3,8><<<dim3(4,16,nb), 256, 0, stream>>>(SAp, wt_dd3, SBp, 128, 128, S128, S128);
    k_pw<<<dim3(HW128/1024,1,nb), 256, 0, stream>>>(SBp, wt_pw_dd, SBp, MMp, HW128, S128, mm128);
    k_attn_res<<<dim3(HW128/1024,1,nb), 256, 0, stream>>>(SBp, MMp, SAp, w_sa_dd, SAp, 128, 128, S128, mm128);
    k_squeeze<<<dim3(HW128/1024,1,nb), 256, 0, stream>>>(SAp, Q2p, wt_squ2, SBp, HW128, S128);
    k_convT_mfma<<<dim3(8,16,nb), 512, 0, stream>>>(SBp, wb4_dm, SAp, 256, 256, S128, S256);
    k_conv_mfma<5,false><<<dim3(8,16,nb), 512, 0, stream>>>(SAp, wb_dm5, wb_pw_dm, nullptr,
                                                            SBp, MMp, 256, 256, S256, S256, mm256);
    k_attn_res<<<dim3(HW256/1024,1,nb), 256, 0, stream>>>(SBp, MMp, SAp, w_sa_dm, SAp, 256, 256, S256, mm256);
    k_squeeze<<<dim3(HW256/1024,1,nb), 256, 0, stream>>>(SAp, E1p, wt_squ1, D1p, HW256, S256);
  };

  // ---- phase 3: D1 -> outputs ----
  auto phase3 = [&](int c0, int nz, const float* D1p, const float* XLp){
    k_convT_mfma<<<dim3(16,32,nz), 512, 0, stream>>>(D1p, wb4_dt, U1, 512, 512, S256, S512);
    k_conv_mfma<7,false><<<dim3(16,32,nz), 512, 0, stream>>>(U1, wb_dt7, wb_pw_dt, nullptr,
                                                             U2, MM, 512, 512, S512, S512, 2*HW512);
    k_attn_res<<<dim3(HW512/1024,1,nz), 256, 0, stream>>>(U2, MM, U1, w_sa_dt, U1, 512, 512, S512, 2*HW512);
    k_final<<<dim3(HW512/1024,1,nz), 256, 0, stream>>>(U1, w_img_out, XLp,
                                                       OUT + (size_t)c0*HW512,
                                                       OUT + 2097152 + (size_t)c0*HW512,
                                                       HW512, S512);
  };

  if (CB > 0){
    for (int c0=0;c0<8;c0+=CB)
      phase1(c0, CB, XL + (size_t)c0*HW512, E1 + (size_t)c0*S256);
    deep(8, E1, U1, U2, E2, Q2, E3, Q3, MM, E1);
    for (int c0=0;c0<8;c0+=CB)
      phase3(c0, CB, E1 + (size_t)c0*S256, XL + (size_t)c0*HW512);
  } else {
    for (int b=0;b<8;b++){
      phase1(b, 1, XL, E1);
      deep(1, E1, U1, U2, E2, Q2, E3, Q3, MM, U2);
      phase3(b, 1, U2, XL);
    }
  }

  k_diff<<<1, 1, 0, stream>>>(DIFF, OUT + 4194304);
}

// Round 8
// 1804.716 us; speedup vs baseline: 10.9102x; 1.3143x over previous
//
#include <hip/hip_runtime.h>
#include <math.h>

#define CH 24

typedef __attribute__((ext_vector_type(8))) short short8v;
typedef __attribute__((ext_vector_type(4))) float f32x4;
typedef unsigned short ushort_t;
typedef unsigned int uint_t;

__device__ inline ushort_t bf16r(float f){
  uint_t u = __float_as_uint(f);
  u += 0x7FFF + ((u>>16)&1);
  return (ushort_t)(u>>16);
}

// ================= weight reorder kernels =================
__global__ void k_r_res(const float* __restrict__ w, float* __restrict__ wT, int K){
  int i = blockIdx.x*256 + threadIdx.x;
  int n = 576*K*K; if (i >= n) return;
  int co = i % 24, ci = (i/24) % 24, kk = i/576;
  int ky = kk / K, kx = kk % K;
  wT[i] = w[((co*24+ci)*K+ky)*K+kx];
}
__global__ void k_r_pw(const float* __restrict__ w, float* __restrict__ wT, int CIN){
  int i = blockIdx.x*256 + threadIdx.x;
  if (i >= CIN*24) return;
  int co = i % 24, ci = i/24;
  wT[i] = w[co*CIN+ci];
}
// MFMA-ready bf16 B-frags (OIHW source): wb[tap*1024 + t*512 + l*8 + j] = W[ci][co]
__global__ void k_rmfma(const float* __restrict__ w, ushort_t* __restrict__ wb, int K){
  int i = blockIdx.x*256 + threadIdx.x;
  int n = K*K*1024; if (i >= n) return;
  int j = i & 7, l = (i>>3) & 63, t = (i>>9) & 1, tap = i >> 10;
  int ci = (l>>4)*8 + j, co = t*16 + (l&15);
  int ky = tap / K, kx = tap % K;
  float v = (ci<24 && co<24) ? w[((co*24+ci)*K+ky)*K+kx] : 0.f;
  wb[i] = bf16r(v);
}
// MFMA-ready bf16 B-frags for convT (torch [in][out][4][4] source), 16 taps
__global__ void k_rmfma4(const float* __restrict__ w, ushort_t* __restrict__ wb){
  int i = blockIdx.x*256 + threadIdx.x;
  if (i >= 16384) return;
  int j = i & 7, l = (i>>3) & 63, t = (i>>9) & 1, tap = i >> 10;
  int ci = (l>>4)*8 + j, co = t*16 + (l&15);
  int ky = tap >> 2, kx = tap & 3;
  float v = (ci<24 && co<24) ? w[((ci*24+co)*4+ky)*4+kx] : 0.f;
  wb[i] = bf16r(v);
}

// ================= compute kernels =================

__global__ void k_lap(const float* __restrict__ x, float* __restrict__ xl, int H, int W){
  int idx = blockIdx.x*256 + threadIdx.x;
  int HW = H*W;
  if (idx >= HW) return;
  const float* xb = x + (size_t)blockIdx.z*3*HW;
  float* xo = xl + (size_t)blockIdx.z*HW;
  int px = idx % W, py = idx / W;
#define MEANV(yy,xx) (((yy)>=0&&(yy)<H&&(xx)>=0&&(xx)<W) ? (xb[(yy)*W+(xx)]+xb[HW+(yy)*W+(xx)]+xb[2*HW+(yy)*W+(xx)])*(1.f/3.f) : 0.f)
  float v = 4.f*MEANV(py,px) - MEANV(py-1,px) - MEANV(py+1,px) - MEANV(py,px-1) - MEANV(py,px+1);
#undef MEANV
  xo[idx] = v;
}

// ---------- MFMA KxK conv 24->24 (pad K/2) FUSED with 1x1 pw conv + mean/max maps ----------
template<int K, bool EXPAND>
__launch_bounds__(512)
__global__ void k_conv_mfma(const float* __restrict__ in, const ushort_t* __restrict__ wb,
                            const ushort_t* __restrict__ wbpw, const float* __restrict__ wexp,
                            float* __restrict__ out, float* __restrict__ mm,
                            int H, int W, int istrIn, int istrOut, int istrMM){
  constexpr int SW_T = 32 + K - 1;
  constexpr int SH = 16 + K - 1;
  constexpr int NPX = SH*SW_T;
  __shared__ ushort_t lds[NPX*32];
  __shared__ uint_t sc[8][16*20];
  int tid = threadIdx.x;
  const float* inb = in + (size_t)blockIdx.z*istrIn;
  int x0g = blockIdx.x*32 - K/2, y0g = blockIdx.y*16 - K/2;
  int HW = H*W;
  for (int i = tid; i < NPX*16; i += 512){
    int cpair = i / NPX;
    int pp = i - cpair*NPX;
    int c0 = cpair*2;
    int row = pp / SW_T, col = pp - row*SW_T;
    int gy = y0g + row, gx = x0g + col;
    float v0 = 0.f, v1 = 0.f;
    if (gy >= 0 && gy < H && gx >= 0 && gx < W){
      if (EXPAND){
        float val = inb[(size_t)gy*W + gx];
        v0 = val * wexp[c0];
        v1 = val * wexp[c0+1];
      } else {
        size_t base = (size_t)gy*W + gx;
        v0 = inb[(size_t)c0*HW + base];
        v1 = inb[(size_t)(c0+1)*HW + base];
      }
    }
    uint_t packed = (uint_t)bf16r(v0) | ((uint_t)bf16r(v1) << 16);
    int slot = pp*32 + (c0 ^ (((pp>>1)&3)<<3));
    *(uint_t*)(lds + slot) = packed;
  }
  __syncthreads();
  int l = tid & 63, wid = tid >> 6;
  int kg = l >> 4, li = l & 15;
  f32x4 zero = {0.f,0.f,0.f,0.f};
  f32x4 acc[4][2];
  #pragma unroll
  for (int i=0;i<4;i++){ acc[i][0]=zero; acc[i][1]=zero; }

  for (int ky=0; ky<K; ky++){
    for (int kx=0; kx<K; kx++){
      int tap = ky*K + kx;
      const ushort_t* wp = wb + (size_t)tap*1024;
      short8v b0 = *(const short8v*)(wp + l*8);
      short8v b1 = *(const short8v*)(wp + 512 + l*8);
      #pragma unroll
      for (int i=0;i<4;i++){
        int pp = (wid + (i&1)*8 + ky)*SW_T + (i>>1)*16 + kx + li;
        short8v a = *(const short8v*)(lds + pp*32 + ((kg*8) ^ (((pp>>1)&3)<<3)));
        acc[i][0] = __builtin_amdgcn_mfma_f32_16x16x32_bf16(a, b0, acc[i][0], 0, 0, 0);
        acc[i][1] = __builtin_amdgcn_mfma_f32_16x16x32_bf16(a, b1, acc[i][1], 0, 0, 0);
      }
    }
  }
  // ---- stage 2: pw 1x1 via second MFMA, + mean/max ----
  short8v bpw0 = *(const short8v*)(wbpw + l*8);
  short8v bpw1 = *(const short8v*)(wbpw + 512 + l*8);
  uint_t* s = sc[wid];
  float* outb = out + (size_t)blockIdx.z*istrOut;
  float* mmb = mm + (size_t)blockIdx.z*istrMM;
  #pragma unroll 1
  for (int i=0;i<4;i++){
    __asm__ volatile("s_waitcnt lgkmcnt(0)" ::: "memory");
    __builtin_amdgcn_sched_barrier(0);
    #pragma unroll
    for (int reg=0; reg<4; reg++){
      float v0 = acc[i][0][reg], v1 = acc[i][1][reg];
      float v0n = __shfl_xor(v0, 1, 64);
      float v1n = __shfl_xor(v1, 1, 64);
      int pxr = kg*4 + reg;
      uint_t packed; int uidx;
      if ((li & 1) == 0){
        packed = (uint_t)bf16r(v0) | ((uint_t)bf16r(v0n) << 16);
        uidx = li >> 1;
      } else {
        packed = (uint_t)bf16r(v1n) | ((uint_t)bf16r(v1) << 16);
        uidx = 8 + (li >> 1);
      }
      s[pxr*20 + uidx] = packed;
    }
    __asm__ volatile("s_waitcnt lgkmcnt(0)" ::: "memory");
    __builtin_amdgcn_sched_barrier(0);
    short8v a2 = *(const short8v*)((const ushort_t*)s + li*40 + kg*8);
    f32x4 d0 = __builtin_amdgcn_mfma_f32_16x16x32_bf16(a2, bpw0, zero, 0, 0, 0);
    f32x4 d1 = __builtin_amdgcn_mfma_f32_16x16x32_bf16(a2, bpw1, zero, 0, 0, 0);
    int gy = blockIdx.y*16 + wid + (i&1)*8;
    int gx = blockIdx.x*32 + (i>>1)*16 + kg*4;
    float* o0 = outb + (size_t)li*HW + (size_t)gy*W + gx;
    *(f32x4*)o0 = d0;
    if (li < 8){
      float* o1 = outb + (size_t)(16+li)*HW + (size_t)gy*W + gx;
      *(f32x4*)o1 = d1;
    }
    f32x4 sm, mx;
    #pragma unroll
    for (int reg=0; reg<4; reg++){
      sm[reg] = d0[reg] + d1[reg];
      mx[reg] = fmaxf(d0[reg], (li<8) ? d1[reg] : -3.4e38f);
    }
    #pragma unroll
    for (int m=1; m<16; m<<=1){
      #pragma unroll
      for (int reg=0; reg<4; reg++){
        sm[reg] += __shfl_xor(sm[reg], m, 64);
        mx[reg] = fmaxf(mx[reg], __shfl_xor(mx[reg], m, 64));
      }
    }
    if (li == 0){
      f32x4 me; me[0]=sm[0]*(1.f/24.f); me[1]=sm[1]*(1.f/24.f); me[2]=sm[2]*(1.f/24.f); me[3]=sm[3]*(1.f/24.f);
      *(f32x4*)(mmb + (size_t)gy*W + gx) = me;
      *(f32x4*)(mmb + (size_t)HW + (size_t)gy*W + gx) = mx;
    }
  }
}

// ---------- MFMA ConvTranspose2d(k=4,s=2,p=1), 32x16 output tile, 8 waves ----------
__launch_bounds__(512)
__global__ void k_convT_mfma(const float* __restrict__ in, const ushort_t* __restrict__ wb,
                             float* __restrict__ out, int Ho, int Wo, int istrIn, int istrOut){
  const int Hi = Ho>>1, Wi = Wo>>1;
  constexpr int SW_T = 18, NPX = 180;
  __shared__ ushort_t lds[NPX*32];
  int tid = threadIdx.x;
  const float* inb = in + (size_t)blockIdx.z*istrIn;
  int X0 = blockIdx.x*32, Y0 = blockIdx.y*16;
  int ix0 = (X0>>1) - 1, iy0 = (Y0>>1) - 1;
  int HWi = Hi*Wi;
  for (int i = tid; i < NPX*16; i += 512){
    int cpair = i / NPX;
    int pp = i - cpair*NPX;
    int c0 = cpair*2;
    int row = pp / SW_T, col = pp - row*SW_T;
    int gy = iy0 + row, gx = ix0 + col;
    float v0=0.f, v1=0.f;
    if (gy>=0 && gy<Hi && gx>=0 && gx<Wi){
      size_t base = (size_t)gy*Wi + gx;
      v0 = inb[(size_t)c0*HWi + base];
      v1 = inb[(size_t)(c0+1)*HWi + base];
    }
    uint_t packed = (uint_t)bf16r(v0) | ((uint_t)bf16r(v1)<<16);
    int slot = pp*32 + (c0 ^ (((pp>>1)&3)<<3));
    *(uint_t*)(lds + slot) = packed;
  }
  __syncthreads();
  int l = tid & 63, wid = tid >> 6;
  int kg = l >> 4, li = l & 15;
  f32x4 zero = {0.f,0.f,0.f,0.f};
  f32x4 acc[4][2];
  #pragma unroll
  for (int i=0;i<4;i++){ acc[i][0]=zero; acc[i][1]=zero; }

  #pragma unroll
  for (int i=0;i<4;i++){
    int g = wid + 8*i;
    int r = g & 15, q = g >> 4;
    int ky0 = (r+1)&1;
    #pragma unroll
    for (int t2=0;t2<2;t2++){
      int ky = ky0 + 2*t2;
      int liy = ((r+1-ky)>>1) + 1;
      #pragma unroll
      for (int u=0;u<2;u++){
        int kx = (q ? 0 : 1) + 2*u;
        int lixb = ((q+1-kx)>>1) + 1;
        int tap = ky*4 + kx;
        const ushort_t* wp = wb + (size_t)tap*1024;
        short8v b0 = *(const short8v*)(wp + l*8);
        short8v b1 = *(const short8v*)(wp + 512 + l*8);
        int pp = liy*SW_T + lixb + li;
        short8v a = *(const short8v*)(lds + pp*32 + ((kg*8) ^ (((pp>>1)&3)<<3)));
        acc[i][0] = __builtin_amdgcn_mfma_f32_16x16x32_bf16(a, b0, acc[i][0], 0, 0, 0);
        acc[i][1] = __builtin_amdgcn_mfma_f32_16x16x32_bf16(a, b1, acc[i][1], 0, 0, 0);
      }
    }
  }
  float* outb = out + (size_t)blockIdx.z*istrOut;
  int HWo = Ho*Wo;
  #pragma unroll
  for (int i=0;i<4;i++){
    int g = wid + 8*i;
    int r = g & 15, q = g >> 4;
    int oy = Y0 + r;
    #pragma unroll
    for (int reg=0; reg<4; reg++){
      int ox = X0 + 2*(kg*4 + reg) + q;
      outb[(size_t)li*HWo + (size_t)oy*Wo + ox] = acc[i][0][reg];
      if (li < 8)
        outb[(size_t)(16+li)*HWo + (size_t)oy*Wo + ox] = acc[i][1][reg];
    }
  }
}

// ---------- MFMA 4x4 s2 p1 downsample, 16x8 output tile, parity-deinterleaved halo ----------
__launch_bounds__(512)
__global__ void k_down_mfma(const float* __restrict__ in, const ushort_t* __restrict__ wb,
                            float* __restrict__ out, int Ho, int Wo, int istrIn, int istrOut){
  const int Hi = Ho*2, Wi = Wo*2;
  constexpr int NPX = 18*34;    // 612 px halo, cols deinterleaved by parity
  __shared__ ushort_t lds[NPX*32];
  int tid = threadIdx.x;
  const float* inb = in + (size_t)blockIdx.z*istrIn;
  int X0 = blockIdx.x*16, Y0 = blockIdx.y*8;
  int ix0 = 2*X0 - 1, iy0 = 2*Y0 - 1;
  int HWi = Hi*Wi;
  for (int i = tid; i < NPX*16; i += 512){
    int cpair = i / NPX;
    int pp = i - cpair*NPX;
    int c0 = cpair*2;
    int row = pp / 34;
    int rem = pp - row*34;
    int par = (rem >= 17) ? 1 : 0;
    int sub = rem - par*17;
    int gx = ix0 + 2*sub + par;
    int gy = iy0 + row;
    float v0=0.f, v1=0.f;
    if (gy>=0 && gy<Hi && gx>=0 && gx<Wi){
      size_t base = (size_t)gy*Wi + gx;
      v0 = inb[(size_t)c0*HWi + base];
      v1 = inb[(size_t)(c0+1)*HWi + base];
    }
    uint_t packed = (uint_t)bf16r(v0) | ((uint_t)bf16r(v1)<<16);
    int slot = pp*32 + (c0 ^ (((pp>>1)&3)<<3));
    *(uint_t*)(lds + slot) = packed;
  }
  __syncthreads();
  int l = tid & 63, wid = tid >> 6;
  int kg = l >> 4, li = l & 15;
  f32x4 zero = {0.f,0.f,0.f,0.f};
  f32x4 acc0 = zero, acc1 = zero;
  // wave wid handles output row r = wid; tap (ky,kx): pixel A-row = li
  #pragma unroll
  for (int ky=0; ky<4; ky++){
    int rowb = (2*wid + ky)*34;
    #pragma unroll
    for (int kx=0; kx<4; kx++){
      int tap = ky*4 + kx;
      const ushort_t* wp = wb + (size_t)tap*1024;
      short8v b0 = *(const short8v*)(wp + l*8);
      short8v b1 = *(const short8v*)(wp + 512 + l*8);
      int pp = rowb + (kx&1)*17 + (kx>>1) + li;
      short8v a = *(const short8v*)(lds + pp*32 + ((kg*8) ^ (((pp>>1)&3)<<3)));
      acc0 = __builtin_amdgcn_mfma_f32_16x16x32_bf16(a, b0, acc0, 0, 0, 0);
      acc1 = __builtin_amdgcn_mfma_f32_16x16x32_bf16(a, b1, acc1, 0, 0, 0);
    }
  }
  int HWo = Ho*Wo;
  float* outb = out + (size_t)blockIdx.z*istrOut;
  int oy = Y0 + wid, ox = X0 + kg*4;
  float* o0 = outb + (size_t)li*HWo + (size_t)oy*Wo + ox;
  *(f32x4*)o0 = acc0;
  if (li < 8){
    float* o1 = outb + (size_t)(16+li)*HWo + (size_t)oy*Wo + ox;
    *(f32x4*)o1 = acc1;
  }
}

// KxK conv fp32 (K=3 @128). wT=[ky][kx][ci][co]. Tile 32 x TH.
template<int K, int TH>
__launch_bounds__(256)
__global__ void k_conv(const float* __restrict__ in, const float* __restrict__ wT,
                       float* __restrict__ out, int H, int W, int istrIn, int istrOut){
  constexpr int TW = 32;
  constexpr int PX = (TW*TH)/256;
  constexpr int XT = TW/PX;
  constexpr int SW = TW + K - 1;
  constexpr int SWP = SW | 1;
  constexpr int SH = TH + K - 1;
  constexpr int CC = 8;
  __shared__ float tile[CC*SH*SWP];
  int tx = threadIdx.x % XT, ty = threadIdx.x / XT;
  int x0 = blockIdx.x*TW - K/2, y0 = blockIdx.y*TH - K/2;
  const float* inb = in + (size_t)blockIdx.z*istrIn;
  float acc[CH][PX];
  #pragma unroll
  for (int co=0;co<CH;co++)
    #pragma unroll
    for (int px=0;px<PX;px++) acc[co][px] = 0.f;

  #pragma unroll 1
  for (int c0=0;c0<CH;c0+=CC){
    __syncthreads();
    for (int i=threadIdx.x; i<CC*SH*SW; i+=256){
      int col = i % SW; int rr = i / SW; int row = rr % SH; int c = rr / SH;
      int gy = y0+row, gx = x0+col;
      tile[(c*SH+row)*SWP+col] = (gy>=0 && gy<H && gx>=0 && gx<W)
          ? inb[(size_t)(c0+c)*H*W + (size_t)gy*W + gx] : 0.f;
    }
    __syncthreads();
    #pragma unroll 1
    for (int ci=0;ci<CC;ci++){
      #pragma unroll 1
      for (int ky=0;ky<K;ky++){
        const float* trow = &tile[(ci*SH + ty+ky)*SWP + tx*PX];
        #pragma unroll
        for (int kx=0;kx<K;kx++){
          float v[PX];
          #pragma unroll
          for (int px=0;px<PX;px++) v[px] = trow[kx+px];
          const float* wp = wT + ((ky*K+kx)*24 + c0+ci)*24;
          #pragma unroll
          for (int co=0;co<CH;co++){
            float wv = wp[co];
            #pragma unroll
            for (int px=0;px<PX;px++) acc[co][px] = fmaf(v[px], wv, acc[co][px]);
          }
        }
      }
    }
  }
  int oy = blockIdx.y*TH+ty, ox = blockIdx.x*TW+tx*PX;
  float* ob = out + (size_t)blockIdx.z*istrOut + (size_t)oy*W + ox;
  #pragma unroll
  for (int co=0;co<CH;co++){
    if (PX == 2){
      float2 o; o.x=acc[co][0]; o.y=acc[co][1];
      *(float2*)(ob + (size_t)co*H*W) = o;
    } else {
      ob[(size_t)co*H*W] = acc[co][0];
    }
  }
}

__global__ void k_pw(const float* in, const float* __restrict__ wT,
                     float* out, float* __restrict__ mm, int HW, int istr, int istrMM){
  int p = (blockIdx.x*256 + threadIdx.x)*4;
  if (p >= HW) return;
  const float* ib = in + (size_t)blockIdx.z*istr;
  float acc[CH][4];
  #pragma unroll
  for (int co=0;co<CH;co++){ acc[co][0]=0;acc[co][1]=0;acc[co][2]=0;acc[co][3]=0; }
  #pragma unroll 1
  for (int ci=0;ci<CH;ci++){
    float4 v = *(const float4*)(ib + (size_t)ci*HW + p);
    const float* wp = wT + ci*24;
    #pragma unroll
    for (int co=0;co<CH;co++){
      float wv = wp[co];
      acc[co][0] = fmaf(v.x, wv, acc[co][0]);
      acc[co][1] = fmaf(v.y, wv, acc[co][1]);
      acc[co][2] = fmaf(v.z, wv, acc[co][2]);
      acc[co][3] = fmaf(v.w, wv, acc[co][3]);
    }
  }
  float mean[4]={0,0,0,0}, mx[4]={-3.4e38f,-3.4e38f,-3.4e38f,-3.4e38f};
  #pragma unroll
  for (int co=0;co<CH;co++)
    #pragma unroll
    for (int j=0;j<4;j++){ mean[j]+=acc[co][j]; mx[j]=fmaxf(mx[j],acc[co][j]); }
  float* ob = out + (size_t)blockIdx.z*istr;
  #pragma unroll
  for (int co=0;co<CH;co++){
    float4 o; o.x=acc[co][0]; o.y=acc[co][1]; o.z=acc[co][2]; o.w=acc[co][3];
    *(float4*)(ob + (size_t)co*HW + p) = o;
  }
  float* mb = mm + (size_t)blockIdx.z*istrMM;
  float4 me; me.x=mean[0]*(1.f/24.f); me.y=mean[1]*(1.f/24.f); me.z=mean[2]*(1.f/24.f); me.w=mean[3]*(1.f/24.f);
  float4 mxo; mxo.x=mx[0]; mxo.y=mx[1]; mxo.z=mx[2]; mxo.w=mx[3];
  *(float4*)(mb + p) = me;
  *(float4*)(mb + HW + p) = mxo;
}

__global__ void k_attn_res(const float* __restrict__ R, const float* __restrict__ M,
                           const float* X, const float* __restrict__ wsa,
                           float* out, int H, int W, int istr, int istrMM){
  int p = (blockIdx.x*256 + threadIdx.x)*4;
  int HW = H*W;
  if (p >= HW) return;
  int py = p / W, px0 = p % W;
  const float* Mb = M + (size_t)blockIdx.z*istrMM;
  float s[4]={0,0,0,0};
  #pragma unroll
  for (int cc=0;cc<2;cc++){
    const float* Mc = Mb + (size_t)cc*HW;
    #pragma unroll 1
    for (int ky=0;ky<7;ky++){
      int gy = py+ky-3;
      if (gy<0||gy>=H) continue;
      const float* mr = Mc + (size_t)gy*W;
      float mv[10];
      #pragma unroll
      for (int j=0;j<10;j++){
        int gx = px0-3+j;
        mv[j] = (gx>=0 && gx<W) ? mr[gx] : 0.f;
      }
      const float* wr = wsa + (cc*7+ky)*7;
      #pragma unroll
      for (int kx=0;kx<7;kx++){
        float wv = wr[kx];
        #pragma unroll
        for (int px=0;px<4;px++) s[px] = fmaf(mv[kx+px], wv, s[px]);
      }
    }
  }
  float g[4];
  #pragma unroll
  for (int px=0;px<4;px++) g[px] = 1.f/(1.f+expf(-s[px]));
  const float* Rb = R + (size_t)blockIdx.z*istr;
  const float* Xb = X + (size_t)blockIdx.z*istr;
  float* Ob = out + (size_t)blockIdx.z*istr;
  #pragma unroll
  for (int c=0;c<CH;c++){
    float4 r = *(const float4*)(Rb + (size_t)c*HW + p);
    float4 xv = *(const float4*)(Xb + (size_t)c*HW + p);
    float4 o;
    o.x = xv.x + fmaxf(r.x*g[0], 0.f);
    o.y = xv.y + fmaxf(r.y*g[1], 0.f);
    o.z = xv.z + fmaxf(r.z*g[2], 0.f);
    o.w = xv.w + fmaxf(r.w*g[3], 0.f);
    *(float4*)(Ob + (size_t)c*HW + p) = o;
  }
}

__global__ void k_attn_res_x(const float* __restrict__ R, const float* __restrict__ M,
                             const float* __restrict__ XL, const float* __restrict__ wsa,
                             const float* __restrict__ wexp,
                             float* __restrict__ out, int H, int W, int istr, int istrMM){
  int p = (blockIdx.x*256 + threadIdx.x)*4;
  int HW = H*W;
  if (p >= HW) return;
  int py = p / W, px0 = p % W;
  const float* Mb = M + (size_t)blockIdx.z*istrMM;
  float s[4]={0,0,0,0};
  #pragma unroll
  for (int cc=0;cc<2;cc++){
    const float* Mc = Mb + (size_t)cc*HW;
    #pragma unroll 1
    for (int ky=0;ky<7;ky++){
      int gy = py+ky-3;
      if (gy<0||gy>=H) continue;
      const float* mr = Mc + (size_t)gy*W;
      float mv[10];
      #pragma unroll
      for (int j=0;j<10;j++){
        int gx = px0-3+j;
        mv[j] = (gx>=0 && gx<W) ? mr[gx] : 0.f;
      }
      const float* wr = wsa + (cc*7+ky)*7;
      #pragma unroll
      for (int kx=0;kx<7;kx++){
        float wv = wr[kx];
        #pragma unroll
        for (int px=0;px<4;px++) s[px] = fmaf(mv[kx+px], wv, s[px]);
      }
    }
  }
  float g[4];
  #pragma unroll
  for (int px=0;px<4;px++) g[px] = 1.f/(1.f+expf(-s[px]));
  float4 xl4 = *(const float4*)(XL + (size_t)blockIdx.z*HW + p);
  const float* Rb = R + (size_t)blockIdx.z*istr;
  float* Ob = out + (size_t)blockIdx.z*istr;
  #pragma unroll
  for (int c=0;c<CH;c++){
    float wc = wexp[c];
    float4 r = *(const float4*)(Rb + (size_t)c*HW + p);
    float4 o;
    o.x = xl4.x*wc + fmaxf(r.x*g[0], 0.f);
    o.y = xl4.y*wc + fmaxf(r.y*g[1], 0.f);
    o.z = xl4.z*wc + fmaxf(r.z*g[2], 0.f);
    o.w = xl4.w*wc + fmaxf(r.w*g[3], 0.f);
    *(float4*)(Ob + (size_t)c*HW + p) = o;
  }
}

__global__ void k_squeeze(const float* __restrict__ inA, const float* inB,
                          const float* __restrict__ wT, float* out, int HW, int istr){
  int p = (blockIdx.x*256 + threadIdx.x)*4;
  if (p >= HW) return;
  const float* Ab = inA + (size_t)blockIdx.z*istr;
  const float* Bb = inB + (size_t)blockIdx.z*istr;
  float acc[CH][4];
  #pragma unroll
  for (int co=0;co<CH;co++){ acc[co][0]=0;acc[co][1]=0;acc[co][2]=0;acc[co][3]=0; }
  #pragma unroll 1
  for (int ci=0;ci<48;ci++){
    const float* src = (ci<24) ? (Ab + (size_t)ci*HW) : (Bb + (size_t)(ci-24)*HW);
    float4 v = *(const float4*)(src + p);
    const float* wp = wT + ci*24;
    #pragma unroll
    for (int co=0;co<CH;co++){
      float wv = wp[co];
      acc[co][0] = fmaf(v.x, wv, acc[co][0]);
      acc[co][1] = fmaf(v.y, wv, acc[co][1]);
      acc[co][2] = fmaf(v.z, wv, acc[co][2]);
      acc[co][3] = fmaf(v.w, wv, acc[co][3]);
    }
  }
  float* ob = out + (size_t)blockIdx.z*istr;
  #pragma unroll
  for (int co=0;co<CH;co++){
    float4 o; o.x=acc[co][0]; o.y=acc[co][1]; o.z=acc[co][2]; o.w=acc[co][3];
    *(float4*)(ob + (size_t)co*HW + p) = o;
  }
}

__global__ void k_quant(const float* __restrict__ enc, const float* __restrict__ embed,
                        float* __restrict__ qt, float* __restrict__ diffAcc, int HW, int istr){
  __shared__ float em[256*28];
  __shared__ float red[4];
  {
    int j = threadIdx.x;
    float s = 0.f;
    #pragma unroll
    for (int c=0;c<CH;c++){
      float e = embed[c*256+j];
      em[j*28+c] = -2.0f*e;
      s = fmaf(e,e,s);
    }
    em[j*28+24] = s; em[j*28+25]=0.f; em[j*28+26]=0.f; em[j*28+27]=0.f;
  }
  __syncthreads();
  int p = blockIdx.x*256 + threadIdx.x;
  const float* eb = enc + (size_t)blockIdx.z*istr;
  float f[CH];
  #pragma unroll
  for (int c=0;c<CH;c++) f[c] = eb[(size_t)c*HW + p];
  float best = 3.4e38f; int bj = 0;
  #pragma unroll 1
  for (int j=0;j<256;j++){
    const float4* row = (const float4*)&em[j*28];
    float s = em[j*28+24];
    #pragma unroll
    for (int q4=0;q4<6;q4++){
      float4 r = row[q4];
      s = fmaf(f[q4*4+0], r.x, s);
      s = fmaf(f[q4*4+1], r.y, s);
      s = fmaf(f[q4*4+2], r.z, s);
      s = fmaf(f[q4*4+3], r.w, s);
    }
    if (s < best){ best = s; bj = j; }
  }
  float* qb = qt + (size_t)blockIdx.z*istr;
  float d = 0.f;
  #pragma unroll
  for (int c=0;c<CH;c++){
    float q = embed[c*256+bj];
    qb[(size_t)c*HW + p] = q;
    float e = q - f[c];
    d = fmaf(e,e,d);
  }
  #pragma unroll
  for (int off=32; off>0; off>>=1) d += __shfl_down(d, off, 64);
  int lane = threadIdx.x & 63, wv = threadIdx.x >> 6;
  if (lane==0) red[wv] = d;
  __syncthreads();
  if (threadIdx.x==0) atomicAdd(diffAcc, red[0]+red[1]+red[2]+red[3]);
}

__global__ void k_final(const float* __restrict__ dec1, const float* __restrict__ w,
                        const float* __restrict__ xl, float* __restrict__ outMask,
                        float* __restrict__ outClean, int HW, int dstr){
  int p = (blockIdx.x*256 + threadIdx.x)*4;
  if (p >= HW) return;
  const float* db = dec1 + (size_t)blockIdx.z*dstr;
  float m[4]={0,0,0,0};
  #pragma unroll
  for (int c=0;c<CH;c++){
    float4 d = *(const float4*)(db + (size_t)c*HW + p);
    float wc = w[c];
    m[0]=fmaf(d.x,wc,m[0]); m[1]=fmaf(d.y,wc,m[1]); m[2]=fmaf(d.z,wc,m[2]); m[3]=fmaf(d.w,wc,m[3]);
  }
  float4 xv = *(const float4*)(xl + (size_t)blockIdx.z*HW + p);
  float4 mo; mo.x=m[0]; mo.y=m[1]; mo.z=m[2]; mo.w=m[3];
  float4 co; co.x=xv.x-m[0]; co.y=xv.y-m[1]; co.z=xv.z-m[2]; co.w=xv.w-m[3];
  *(float4*)(outMask + (size_t)blockIdx.z*HW + p) = mo;
  *(float4*)(outClean + (size_t)blockIdx.z*HW + p) = co;
}

__global__ void k_diff(const float* __restrict__ acc, float* __restrict__ out){
  out[0] = acc[0]*(1.f/3145728.f) + acc[1]*(1.f/786432.f);
}

// =======================================================================
extern "C" void kernel_launch(void* const* d_in, const int* in_sizes, int n_in,
                              void* d_out, int out_size, void* d_ws, size_t ws_size,
                              hipStream_t stream) {
  const float* x        = (const float*)d_in[0];
  const float* embed2   = (const float*)d_in[1];
  const float* embed3   = (const float*)d_in[2];
  const float* w_img_in = (const float*)d_in[3];
  const float* w_img_out= (const float*)d_in[4];
  const float* w_out_dd = (const float*)d_in[5];
  const float* w_out_dm = (const float*)d_in[6];
  const float* w_out_dt = (const float*)d_in[7];
  const float* w_out_ed = (const float*)d_in[8];
  const float* w_out_em = (const float*)d_in[9];
  const float* w_out_et = (const float*)d_in[10];
  const float* w_pw_dd  = (const float*)d_in[11];
  const float* w_pw_dm  = (const float*)d_in[12];
  const float* w_pw_dt  = (const float*)d_in[13];
  const float* w_pw_ed  = (const float*)d_in[14];
  const float* w_pw_em  = (const float*)d_in[15];
  const float* w_pw_et  = (const float*)d_in[16];
  const float* w_res_dd = (const float*)d_in[17];
  const float* w_res_dm = (const float*)d_in[18];
  const float* w_res_dt = (const float*)d_in[19];
  const float* w_res_ed = (const float*)d_in[20];
  const float* w_res_em = (const float*)d_in[21];
  const float* w_res_et = (const float*)d_in[22];
  const float* w_sa_dd  = (const float*)d_in[23];
  const float* w_sa_dm  = (const float*)d_in[24];
  const float* w_sa_dt  = (const float*)d_in[25];
  const float* w_sa_ed  = (const float*)d_in[26];
  const float* w_sa_em  = (const float*)d_in[27];
  const float* w_sa_et  = (const float*)d_in[28];
  const float* w_squ1   = (const float*)d_in[29];
  const float* w_squ2   = (const float*)d_in[30];
  (void)in_sizes; (void)n_in; (void)out_size;

  const int HW512 = 512*512, HW256 = 256*256, HW128 = 128*128, HW64 = 64*64;
  const int S512 = 24*HW512, S256 = 24*HW256, S128 = 24*HW128, S64 = 24*HW64;

  float* ws = (float*)d_ws;
  float* OUT = (float*)d_out;
  size_t F = ws_size / sizeof(float);

  // fp32-reordered weights
  float* WT      = ws;
  float* wt_ed3  = WT + 85248;
  float* wt_dd3  = WT + 90432;
  float* wt_pw_ed= WT + 152064;
  float* wt_pw_dd= WT + 152640;
  float* wt_squ1 = WT + 154368;
  float* wt_squ2 = WT + 155520;

  // MFMA bf16 B-frag weights
  ushort_t* WB = (ushort_t*)(ws + 160000);
  ushort_t* wb_et7   = WB;
  ushort_t* wb_dt7   = WB + 50176;
  ushort_t* wb_em5   = WB + 100352;
  ushort_t* wb_dm5   = WB + 125952;
  ushort_t* wb_pw_et = WB + 151552;
  ushort_t* wb_pw_em = WB + 152576;
  ushort_t* wb_pw_dm = WB + 153600;
  ushort_t* wb_pw_dt = WB + 154624;
  ushort_t* wb4_dd   = WB + 155648;
  ushort_t* wb4_dm   = WB + 172032;
  ushort_t* wb4_dt   = WB + 188416;
  ushort_t* wb4d_et  = WB + 204800;
  ushort_t* wb4d_em  = WB + 221184;
  ushort_t* wb4d_ed  = WB + 237568;   // ends 253952 ushorts = 126976 floats

  const size_t ABASE = 290000;

  auto needBatched = [&](size_t CB)->size_t{
    size_t u = (CB*(size_t)S512 > (size_t)8*S256) ? CB*(size_t)S512 : (size_t)8*S256;
    return ABASE + 2097152 + 12582912 + 3145728 + 786432 + CB*524288 + 2*u + 2;
  };
  int CB = 0;
  if (F >= needBatched(8)) CB = 8;
  else if (F >= needBatched(4)) CB = 4;
  else if (F >= needBatched(2)) CB = 2;
  const size_t NEED_B = ABASE + 15925250;
  if (CB == 0 && F < NEED_B) return;

  float *XL, *E1, *E2, *Q2, *E3, *Q3, *MM, *DIFF, *U1, *U2;
  if (CB > 0){
    size_t off = ABASE;
    size_t u = (CB*(size_t)S512 > (size_t)8*S256) ? CB*(size_t)S512 : (size_t)8*S256;
    XL = ws + off; off += 2097152;
    E1 = ws + off; off += 12582912;
    Q2 = ws + off; off += 3145728;
    Q3 = ws + off; off += 786432;
    MM = ws + off; off += CB*524288;
    U1 = ws + off; off += u;
    U2 = ws + off; off += u;
    DIFF = ws + off;
    E2 = OUT;
    E3 = OUT + 3145728;
  } else {
    size_t off = ABASE;
    XL = ws + off; off += 262144;
    U1 = ws + off; off += 6291456;
    U2 = ws + off; off += 6291456;
    E1 = ws + off; off += 1572864;
    E2 = ws + off; off += 393216;
    Q2 = ws + off; off += 393216;
    E3 = ws + off; off += 98304;
    Q3 = ws + off; off += 98304;
    MM = ws + off; off += 524288;
    DIFF = ws + off;
  }

  // ---- weight reorders ----
  k_rmfma<<<dim3(196), 256, 0, stream>>>(w_res_et, wb_et7, 7);
  k_rmfma<<<dim3(196), 256, 0, stream>>>(w_res_dt, wb_dt7, 7);
  k_rmfma<<<dim3(100), 256, 0, stream>>>(w_res_em, wb_em5, 5);
  k_rmfma<<<dim3(100), 256, 0, stream>>>(w_res_dm, wb_dm5, 5);
  k_rmfma<<<dim3(4), 256, 0, stream>>>(w_pw_et, wb_pw_et, 1);
  k_rmfma<<<dim3(4), 256, 0, stream>>>(w_pw_em, wb_pw_em, 1);
  k_rmfma<<<dim3(4), 256, 0, stream>>>(w_pw_dm, wb_pw_dm, 1);
  k_rmfma<<<dim3(4), 256, 0, stream>>>(w_pw_dt, wb_pw_dt, 1);
  k_rmfma4<<<dim3(64), 256, 0, stream>>>(w_out_dd, wb4_dd);
  k_rmfma4<<<dim3(64), 256, 0, stream>>>(w_out_dm, wb4_dm);
  k_rmfma4<<<dim3(64), 256, 0, stream>>>(w_out_dt, wb4_dt);
  k_rmfma<<<dim3(64), 256, 0, stream>>>(w_out_et, wb4d_et, 4);
  k_rmfma<<<dim3(64), 256, 0, stream>>>(w_out_em, wb4d_em, 4);
  k_rmfma<<<dim3(64), 256, 0, stream>>>(w_out_ed, wb4d_ed, 4);
  k_r_res<<<dim3((576*9+255)/256), 256, 0, stream>>>(w_res_ed, wt_ed3, 3);
  k_r_res<<<dim3((576*9+255)/256), 256, 0, stream>>>(w_res_dd, wt_dd3, 3);
  k_r_pw<<<dim3(3), 256, 0, stream>>>(w_pw_ed, wt_pw_ed, 24);
  k_r_pw<<<dim3(3), 256, 0, stream>>>(w_pw_dd, wt_pw_dd, 24);
  k_r_pw<<<dim3(5), 256, 0, stream>>>(w_squ1, wt_squ1, 48);
  k_r_pw<<<dim3(5), 256, 0, stream>>>(w_squ2, wt_squ2, 48);

  hipMemsetAsync(DIFF, 0, 2*sizeof(float), stream);

  // ---- phase 1: input -> enc1 ----
  auto phase1 = [&](int c0, int nz, float* XLp, float* E1p){
    k_lap<<<dim3(HW512/256,1,nz), 256, 0, stream>>>(x + (size_t)c0*3*HW512, XLp, 512, 512);
    k_conv_mfma<7,true><<<dim3(16,32,nz), 512, 0, stream>>>(XLp, wb_et7, wb_pw_et, w_img_in,
                                                            U2, MM, 512, 512, HW512, S512, 2*HW512);
    k_attn_res_x<<<dim3(HW512/1024,1,nz), 256, 0, stream>>>(U2, MM, XLp, w_sa_et, w_img_in,
                                                            U1, 512, 512, S512, 2*HW512);
    k_down_mfma<<<dim3(16,32,nz), 512, 0, stream>>>(U1, wb4d_et, E1p, 256, 256, S512, S256);
  };

  // ---- deep: enc1 -> squ1 output ----
  auto deep = [&](int nb, float* E1p, float* SAp, float* SBp, float* E2p, float* Q2p,
                  float* E3p, float* Q3p, float* MMp, float* D1p){
    int mm256 = 2*HW256, mm128 = 2*HW128;
    k_conv_mfma<5,false><<<dim3(8,16,nb), 512, 0, stream>>>(E1p, wb_em5, wb_pw_em, nullptr,
                                                            SAp, MMp, 256, 256, S256, S256, mm256);
    k_attn_res<<<dim3(HW256/1024,1,nb), 256, 0, stream>>>(SAp, MMp, E1p, w_sa_em, SBp, 256, 256, S256, mm256);
    k_down_mfma<<<dim3(8,16,nb), 512, 0, stream>>>(SBp, wb4d_em, E2p, 128, 128, S256, S128);
    k_conv<3,8><<<dim3(4,16,nb), 256, 0, stream>>>(E2p, wt_ed3, SAp, 128, 128, S128, S128);
    k_pw<<<dim3(HW128/1024,1,nb), 256, 0, stream>>>(SAp, wt_pw_ed, SAp, MMp, HW128, S128, mm128);
    k_attn_res<<<dim3(HW128/1024,1,nb), 256, 0, stream>>>(SAp, MMp, E2p, w_sa_ed, SBp, 128, 128, S128, mm128);
    k_down_mfma<<<dim3(4,8,nb), 512, 0, stream>>>(SBp, wb4d_ed, E3p, 64, 64, S128, S64);
    k_quant<<<dim3(HW128/256,1,nb), 256, 0, stream>>>(E2p, embed2, Q2p, DIFF+0, HW128, S128);
    k_quant<<<dim3(HW64/256,1,nb), 256, 0, stream>>>(E3p, embed3, Q3p, DIFF+1, HW64, S64);
    k_convT_mfma<<<dim3(4,8,nb), 512, 0, stream>>>(Q3p, wb4_dd, SAp, 128, 128, S64, S128);
    k_conv<3,8><<<dim3(4,16,nb), 256, 0, stream>>>(SAp, wt_dd3, SBp, 128, 128, S128, S128);
    k_pw<<<dim3(HW128/1024,1,nb), 256, 0, stream>>>(SBp, wt_pw_dd, SBp, MMp, HW128, S128, mm128);
    k_attn_res<<<dim3(HW128/1024,1,nb), 256, 0, stream>>>(SBp, MMp, SAp, w_sa_dd, SAp, 128, 128, S128, mm128);
    k_squeeze<<<dim3(HW128/1024,1,nb), 256, 0, stream>>>(SAp, Q2p, wt_squ2, SBp, HW128, S128);
    k_convT_mfma<<<dim3(8,16,nb), 512, 0, stream>>>(SBp, wb4_dm, SAp, 256, 256, S128, S256);
    k_conv_mfma<5,false><<<dim3(8,16,nb), 512, 0, stream>>>(SAp, wb_dm5, wb_pw_dm, nullptr,
                                                            SBp, MMp, 256, 256, S256, S256, mm256);
    k_attn_res<<<dim3(HW256/1024,1,nb), 256, 0, stream>>>(SBp, MMp, SAp, w_sa_dm, SAp, 256, 256, S256, mm256);
    k_squeeze<<<dim3(HW256/1024,1,nb), 256, 0, stream>>>(SAp, E1p, wt_squ1, D1p, HW256, S256);
  };

  // ---- phase 3: D1 -> outputs ----
  auto phase3 = [&](int c0, int nz, const float* D1p, const float* XLp){
    k_convT_mfma<<<dim3(16,32,nz), 512, 0, stream>>>(D1p, wb4_dt, U1, 512, 512, S256, S512);
    k_conv_mfma<7,false><<<dim3(16,32,nz), 512, 0, stream>>>(U1, wb_dt7, wb_pw_dt, nullptr,
                                                             U2, MM, 512, 512, S512, S512, 2*HW512);
    k_attn_res<<<dim3(HW512/1024,1,nz), 256, 0, stream>>>(U2, MM, U1, w_sa_dt, U1, 512, 512, S512, 2*HW512);
    k_final<<<dim3(HW512/1024,1,nz), 256, 0, stream>>>(U1, w_img_out, XLp,
                                                       OUT + (size_t)c0*HW512,
                                                       OUT + 2097152 + (size_t)c0*HW512,
                                                       HW512, S512);
  };

  if (CB > 0){
    for (int c0=0;c0<8;c0+=CB)
      phase1(c0, CB, XL + (size_t)c0*HW512, E1 + (size_t)c0*S256);
    deep(8, E1, U1, U2, E2, Q2, E3, Q3, MM, E1);
    for (int c0=0;c0<8;c0+=CB)
      phase3(c0, CB, E1 + (size_t)c0*S256, XL + (size_t)c0*HW512);
  } else {
    for (int b=0;b<8;b++){
      phase1(b, 1, XL, E1);
      deep(1, E1, U1, U2, E2, Q2, E3, Q3, MM, U2);
      phase3(b, 1, U2, XL);
    }
  }

  k_diff<<<1, 1, 0, stream>>>(DIFF, OUT + 4194304);
}